// Round 1
// baseline (6458.784 us; speedup 1.0000x reference)
//
#include <hip/hip_runtime.h>
#include <stdint.h>

#define N_NODES 50000
#define N_EDGES 400000

typedef short s8v __attribute__((ext_vector_type(8)));
typedef float f4v __attribute__((ext_vector_type(4)));

static __device__ __forceinline__ unsigned short f2bf(float f) {
  union { float f; uint32_t u; } v; v.f = f;
  return (unsigned short)((v.u + 0x7FFFu + ((v.u >> 16) & 1u)) >> 16);
}
static __device__ __forceinline__ ushort4 f2bf4(float4 v) {
  ushort4 o; o.x = f2bf(v.x); o.y = f2bf(v.y); o.z = f2bf(v.z); o.w = f2bf(v.w);
  return o;
}
static __device__ __forceinline__ f4v mfma16(s8v a, s8v b, f4v c) {
  return __builtin_amdgcn_mfma_f32_16x16x32_bf16(a, b, c, 0, 0, 0);
}

// Per-wave fused 2-layer MLP core.
// BUF initially holds A as bf16 rows of stride (KST1*32+8); after the internal
// barrier BUF is reused as H1 [64][264] bf16. Each wave owns rows [wr0, wr0+16).
// Layer1: [16,KST1*32] @ W1t -> 256 cols, relu -> H1. Layer2: @ W2t -> 128 cols.
template <int KST1>
static __device__ __forceinline__ void mlp_core(
    unsigned short* __restrict__ BUF,
    const unsigned short* __restrict__ W1t, const float* __restrict__ b1,
    const unsigned short* __restrict__ W2t,
    int l15, int kg, int wr0, f4v* __restrict__ acc2)
{
  const int ldA = KST1 * 32 + 8;
  const f4v vzero = {0.f, 0.f, 0.f, 0.f};
  const unsigned short* Arow = BUF + (size_t)(wr0 + l15) * ldA;
  s8v af1[KST1];
#pragma unroll
  for (int k = 0; k < KST1; ++k) af1[k] = *(const s8v*)(Arow + k * 32 + kg * 8);
  __syncthreads();  // all A reads done; BUF may now be overwritten as H1
  f4v acc1[16];
#pragma unroll
  for (int t = 0; t < 16; ++t) acc1[t] = vzero;
#pragma unroll
  for (int k = 0; k < KST1; ++k) {
#pragma unroll
    for (int t = 0; t < 16; ++t) {
      s8v b = *(const s8v*)(W1t + (size_t)(t * 16 + l15) * (KST1 * 32) + k * 32 + kg * 8);
      acc1[t] = mfma16(af1[k], b, acc1[t]);
    }
  }
  // bias + relu -> H1 (stride 264, per-wave disjoint rows)
#pragma unroll
  for (int t = 0; t < 16; ++t) {
    int c = t * 16 + l15;
    float bb = b1[c];
#pragma unroll
    for (int j = 0; j < 4; ++j) {
      BUF[(size_t)(wr0 + kg * 4 + j) * 264 + c] = f2bf(fmaxf(acc1[t][j] + bb, 0.f));
    }
  }
  const unsigned short* Hrow = BUF + (size_t)(wr0 + l15) * 264;
  s8v af2[8];
#pragma unroll
  for (int k = 0; k < 8; ++k) af2[k] = *(const s8v*)(Hrow + k * 32 + kg * 8);
#pragma unroll
  for (int t = 0; t < 8; ++t) acc2[t] = vzero;
#pragma unroll
  for (int k = 0; k < 8; ++k) {
#pragma unroll
    for (int t = 0; t < 8; ++t) {
      s8v b = *(const s8v*)(W2t + (size_t)(t * 16 + l15) * 256 + k * 32 + kg * 8);
      acc2[t] = mfma16(af2[k], b, acc2[t]);
    }
  }
}

// ---------------- edge message MLP (p or c direction) ----------------
// A-row(e) = [ hidden[g0[e]] | hidden[g1[e]] | efeat[e] ]  (3*128 bf16)
// out(e) = relu(mlp(A)) * rcp[g1[e]]  atomically added into Sacc[g1[e]]
__global__ __launch_bounds__(256, 2) void edge_mlp_kernel(
    const float* __restrict__ hidden,
    const int* __restrict__ g0idx, const int* __restrict__ g1idx,
    const unsigned short* __restrict__ efeat,
    const unsigned short* __restrict__ W1t, const float* __restrict__ b1,
    const unsigned short* __restrict__ W2t, const float* __restrict__ b2,
    float* __restrict__ Sacc, const float* __restrict__ rcpv)
{
  __shared__ unsigned short BUF[64 * 392];
  __shared__ int g0s[64];
  __shared__ int g1s[64];
  __shared__ float tsc[64];
  const int tid = threadIdx.x;
  const int base = blockIdx.x * 64;  // E % 64 == 0, no row guards needed
  if (tid < 64) {
    int e = base + tid;
    int a0 = g0idx[e], a1 = g1idx[e];
    g0s[tid] = a0; g1s[tid] = a1; tsc[tid] = rcpv[a1];
  }
  __syncthreads();
  // seg0 + seg1: gather two hidden rows per edge (f32 -> bf16)
#pragma unroll
  for (int it = 0; it < 16; ++it) {
    int i = tid + it * 256;
    int r = i >> 6, ch = i & 63, seg = ch >> 5, c4 = ch & 31;
    int node = seg ? g1s[r] : g0s[r];
    float4 v = *(const float4*)(hidden + (size_t)node * 128 + c4 * 4);
    *(ushort4*)(BUF + r * 392 + seg * 128 + c4 * 4) = f2bf4(v);
  }
  // seg2: copy edge features (already bf16)
#pragma unroll
  for (int it = 0; it < 4; ++it) {
    int i = tid + it * 256;
    int r = i >> 4, c8 = i & 15;
    *(uint4*)(BUF + r * 392 + 256 + c8 * 8) =
        *(const uint4*)(efeat + (size_t)(base + r) * 128 + c8 * 8);
  }
  __syncthreads();
  const int lane = tid & 63, wv = tid >> 6;
  const int l15 = lane & 15, kg = lane >> 4, wr0 = wv * 16;
  f4v acc2[8];
  mlp_core<12>(BUF, W1t, b1, W2t, l15, kg, wr0, acc2);
#pragma unroll
  for (int t = 0; t < 8; ++t) {
    int c = t * 16 + l15;
    float bb = b2[c];
#pragma unroll
    for (int j = 0; j < 4; ++j) {
      int r = wr0 + kg * 4 + j;
      float v = fmaxf(acc2[t][j] + bb, 0.f) * tsc[r];
      atomicAdd(Sacc + (size_t)g1s[r] * 128 + c, v);
    }
  }
}

// ---------------- node aggregation MLP ----------------
// A-row(n) = [ hidden[n] | Sp[n]+p_mask[n]*stok | Sc[n]+c_mask[n]*etok ]
// hidden[n] += relu(mlp(A))
__global__ __launch_bounds__(256, 2) void node_aggr_kernel(
    float* __restrict__ hid,
    const float* __restrict__ Sp, const float* __restrict__ Sc,
    const float* __restrict__ p_mask, const float* __restrict__ c_mask,
    const float* __restrict__ stok, const float* __restrict__ etok,
    const unsigned short* __restrict__ W1t, const float* __restrict__ b1,
    const unsigned short* __restrict__ W2t, const float* __restrict__ b2)
{
  __shared__ unsigned short BUF[64 * 392];
  const int tid = threadIdx.x;
  const int base = blockIdx.x * 64;
#pragma unroll
  for (int it = 0; it < 8; ++it) {
    int i = tid + it * 256;
    int r = i >> 5, c4 = i & 31, n = base + r;
    float4 v = {0.f, 0.f, 0.f, 0.f};
    if (n < N_NODES) v = *(const float4*)(hid + (size_t)n * 128 + c4 * 4);
    *(ushort4*)(BUF + r * 392 + c4 * 4) = f2bf4(v);
  }
#pragma unroll
  for (int it = 0; it < 8; ++it) {
    int i = tid + it * 256;
    int r = i >> 5, c4 = i & 31, n = base + r;
    float4 v = {0.f, 0.f, 0.f, 0.f};
    if (n < N_NODES) {
      v = *(const float4*)(Sp + (size_t)n * 128 + c4 * 4);
      float pm = p_mask[n];
      const float4 st = *(const float4*)(stok + c4 * 4);
      v.x = fmaf(pm, st.x, v.x); v.y = fmaf(pm, st.y, v.y);
      v.z = fmaf(pm, st.z, v.z); v.w = fmaf(pm, st.w, v.w);
    }
    *(ushort4*)(BUF + r * 392 + 128 + c4 * 4) = f2bf4(v);
  }
#pragma unroll
  for (int it = 0; it < 8; ++it) {
    int i = tid + it * 256;
    int r = i >> 5, c4 = i & 31, n = base + r;
    float4 v = {0.f, 0.f, 0.f, 0.f};
    if (n < N_NODES) {
      v = *(const float4*)(Sc + (size_t)n * 128 + c4 * 4);
      float cm = c_mask[n];
      const float4 et = *(const float4*)(etok + c4 * 4);
      v.x = fmaf(cm, et.x, v.x); v.y = fmaf(cm, et.y, v.y);
      v.z = fmaf(cm, et.z, v.z); v.w = fmaf(cm, et.w, v.w);
    }
    *(ushort4*)(BUF + r * 392 + 256 + c4 * 4) = f2bf4(v);
  }
  __syncthreads();
  const int lane = tid & 63, wv = tid >> 6;
  const int l15 = lane & 15, kg = lane >> 4, wr0 = wv * 16;
  f4v acc2[8];
  mlp_core<12>(BUF, W1t, b1, W2t, l15, kg, wr0, acc2);
#pragma unroll
  for (int t = 0; t < 8; ++t) {
    int c = t * 16 + l15;
    float bb = b2[c];
#pragma unroll
    for (int j = 0; j < 4; ++j) {
      int n = base + wr0 + kg * 4 + j;
      if (n < N_NODES) {
        hid[(size_t)n * 128 + c] += fmaxf(acc2[t][j] + bb, 0.f);
      }
    }
  }
}

// ---------------- initial node MLP: hidden = mlp_v(batch_token) ----------------
__global__ __launch_bounds__(256, 2) void v_mlp_kernel(
    const float* __restrict__ x,
    const unsigned short* __restrict__ W1t, const float* __restrict__ b1,
    const unsigned short* __restrict__ W2t, const float* __restrict__ b2,
    float* __restrict__ hid)
{
  __shared__ unsigned short BUF[64 * 264];
  const int tid = threadIdx.x;
  const int base = blockIdx.x * 64;
#pragma unroll
  for (int it = 0; it < 8; ++it) {
    int i = tid + it * 256;
    int r = i >> 5, c4 = i & 31, n = base + r;
    float4 v = {0.f, 0.f, 0.f, 0.f};
    if (n < N_NODES) v = *(const float4*)(x + (size_t)n * 128 + c4 * 4);
    *(ushort4*)(BUF + r * 136 + c4 * 4) = f2bf4(v);
  }
  __syncthreads();
  const int lane = tid & 63, wv = tid >> 6;
  const int l15 = lane & 15, kg = lane >> 4, wr0 = wv * 16;
  f4v acc2[8];
  mlp_core<4>(BUF, W1t, b1, W2t, l15, kg, wr0, acc2);
#pragma unroll
  for (int t = 0; t < 8; ++t) {
    int c = t * 16 + l15;
    float bb = b2[c];
#pragma unroll
    for (int j = 0; j < 4; ++j) {
      int n = base + wr0 + kg * 4 + j;
      if (n < N_NODES) {
        hid[(size_t)n * 128 + c] = fmaxf(acc2[t][j] + bb, 0.f);
      }
    }
  }
}

// ---------------- edge-scalar MLP: feat = mlp_e(indicator) as bf16 ----------------
__global__ __launch_bounds__(256, 2) void edge_feat_kernel(
    const float* __restrict__ ind, const float* __restrict__ W1, const float* __restrict__ b1,
    const unsigned short* __restrict__ W2t, const float* __restrict__ b2,
    unsigned short* __restrict__ feat)
{
  __shared__ unsigned short H1[64 * 264];
  __shared__ float xs[64];
  const int tid = threadIdx.x;
  const int base = blockIdx.x * 64;  // E % 64 == 0
  if (tid < 64) xs[tid] = ind[base + tid];
  __syncthreads();
  const float w = W1[tid];  // [1,256] row
  const float bb = b1[tid];
  for (int r = 0; r < 64; ++r) {
    H1[r * 264 + tid] = f2bf(fmaxf(fmaf(xs[r], w, bb), 0.f));
  }
  __syncthreads();
  const int lane = tid & 63, wv = tid >> 6;
  const int l15 = lane & 15, kg = lane >> 4, wr0 = wv * 16;
  const unsigned short* Hrow = H1 + (size_t)(wr0 + l15) * 264;
  const f4v vzero = {0.f, 0.f, 0.f, 0.f};
  s8v af2[8];
#pragma unroll
  for (int k = 0; k < 8; ++k) af2[k] = *(const s8v*)(Hrow + k * 32 + kg * 8);
  f4v acc2[8];
#pragma unroll
  for (int t = 0; t < 8; ++t) acc2[t] = vzero;
#pragma unroll
  for (int k = 0; k < 8; ++k) {
#pragma unroll
    for (int t = 0; t < 8; ++t) {
      s8v b = *(const s8v*)(W2t + (size_t)(t * 16 + l15) * 256 + k * 32 + kg * 8);
      acc2[t] = mfma16(af2[k], b, acc2[t]);
    }
  }
#pragma unroll
  for (int t = 0; t < 8; ++t) {
    int c = t * 16 + l15;
    float b2c = b2[c];
#pragma unroll
    for (int j = 0; j < 4; ++j) {
      int e = base + wr0 + kg * 4 + j;
      feat[(size_t)e * 128 + c] = f2bf(fmaxf(acc2[t][j] + b2c, 0.f));
    }
  }
}

// ---------------- small helper kernels ----------------
__global__ void transpose_w(const float* __restrict__ W, unsigned short* __restrict__ Wt,
                            int K, int NH) {
  int i = blockIdx.x * 256 + threadIdx.x;
  if (i < K * NH) {
    int k = i / NH, n = i - k * NH;
    Wt[(size_t)n * K + k] = f2bf(W[i]);
  }
}

__global__ void count_kernel(const int* __restrict__ pn, const int* __restrict__ cn,
                             float* __restrict__ cp, float* __restrict__ cc) {
  int i = blockIdx.x * 256 + threadIdx.x;
  if (i < N_EDGES) {
    atomicAdd(cp + pn[i], 1.f);
    atomicAdd(cc + cn[i], 1.f);
  }
}

__global__ void rcp_kernel(float* __restrict__ cp, float* __restrict__ cc) {
  int i = blockIdx.x * 256 + threadIdx.x;
  if (i < N_NODES) {
    cp[i] = 1.f / fmaxf(cp[i], 1.f);
    cc[i] = 1.f / fmaxf(cc[i], 1.f);
  }
}

extern "C" void kernel_launch(void* const* d_in, const int* in_sizes, int n_in,
                              void* d_out, int out_size, void* d_ws, size_t ws_size,
                              hipStream_t stream) {
  const float* batch_token = (const float*)d_in[0];
  const int*   pn          = (const int*)d_in[1];
  const int*   cn          = (const int*)d_in[2];
  const float* indP        = (const float*)d_in[3];
  const float* indC        = (const float*)d_in[4];
  const float* p_mask      = (const float*)d_in[5];
  const float* c_mask      = (const float*)d_in[6];
  const float* stok        = (const float*)d_in[7];
  const float* etok        = (const float*)d_in[8];
  const float* vW1 = (const float*)d_in[9],  *vb1 = (const float*)d_in[10];
  const float* vW2 = (const float*)d_in[11], *vb2 = (const float*)d_in[12];
  const float* eW1 = (const float*)d_in[13], *eb1 = (const float*)d_in[14];
  const float* eW2 = (const float*)d_in[15], *eb2 = (const float*)d_in[16];
  const float* pW1 = (const float*)d_in[17], *pb1 = (const float*)d_in[18];
  const float* pW2 = (const float*)d_in[19], *pb2 = (const float*)d_in[20];
  const float* cW1 = (const float*)d_in[21], *cb1 = (const float*)d_in[22];
  const float* cW2 = (const float*)d_in[23], *cb2 = (const float*)d_in[24];
  const float* aW1 = (const float*)d_in[25], *ab1 = (const float*)d_in[26];
  const float* aW2 = (const float*)d_in[27], *ab2 = (const float*)d_in[28];

  char* w = (char*)d_ws;
  auto alloc = [&](size_t bytes) -> char* {
    char* p = w;
    w += (bytes + 255) & ~(size_t)255;
    return p;
  };
  float* Sp    = (float*)alloc((size_t)N_NODES * 128 * 4);
  float* Sc    = (float*)alloc((size_t)N_NODES * 128 * 4);
  float* rcp_p = (float*)alloc((size_t)N_NODES * 4);  // counts, then 1/cnt in place
  float* rcp_c = (float*)alloc((size_t)N_NODES * 4);
  unsigned short* featP = (unsigned short*)alloc((size_t)N_EDGES * 128 * 2);
  unsigned short* featC = (unsigned short*)alloc((size_t)N_EDGES * 128 * 2);
  unsigned short* W1t_p = (unsigned short*)alloc(256 * 384 * 2);
  unsigned short* W1t_c = (unsigned short*)alloc(256 * 384 * 2);
  unsigned short* W1t_a = (unsigned short*)alloc(256 * 384 * 2);
  unsigned short* W1t_v = (unsigned short*)alloc(256 * 128 * 2);
  unsigned short* W2t_p = (unsigned short*)alloc(128 * 256 * 2);
  unsigned short* W2t_c = (unsigned short*)alloc(128 * 256 * 2);
  unsigned short* W2t_a = (unsigned short*)alloc(128 * 256 * 2);
  unsigned short* W2t_v = (unsigned short*)alloc(128 * 256 * 2);
  unsigned short* W2t_e = (unsigned short*)alloc(128 * 256 * 2);

  float* hidden = (float*)d_out;

  const int EB = N_EDGES / 64;            // 6250, exact
  const int NB = (N_NODES + 63) / 64;     // 782

  // counts
  hipMemsetAsync(rcp_p, 0, (size_t)N_NODES * 4, stream);
  hipMemsetAsync(rcp_c, 0, (size_t)N_NODES * 4, stream);
  count_kernel<<<(N_EDGES + 255) / 256, 256, 0, stream>>>(pn, cn, rcp_p, rcp_c);
  rcp_kernel<<<(N_NODES + 255) / 256, 256, 0, stream>>>(rcp_p, rcp_c);

  // weight prep (f32 [K][NH] -> bf16 [NH][K])
  auto T = [&](const float* Wsrc, unsigned short* Wdst, int K, int NH) {
    int tot = K * NH;
    transpose_w<<<(tot + 255) / 256, 256, 0, stream>>>(Wsrc, Wdst, K, NH);
  };
  T(pW1, W1t_p, 384, 256);
  T(cW1, W1t_c, 384, 256);
  T(aW1, W1t_a, 384, 256);
  T(vW1, W1t_v, 128, 256);
  T(pW2, W2t_p, 256, 128);
  T(cW2, W2t_c, 256, 128);
  T(aW2, W2t_a, 256, 128);
  T(vW2, W2t_v, 256, 128);
  T(eW2, W2t_e, 256, 128);

  // one-time edge feature MLPs and initial hidden
  edge_feat_kernel<<<EB, 256, 0, stream>>>(indP, eW1, eb1, W2t_e, eb2, featP);
  edge_feat_kernel<<<EB, 256, 0, stream>>>(indC, eW1, eb1, W2t_e, eb2, featC);
  v_mlp_kernel<<<NB, 256, 0, stream>>>(batch_token, W1t_v, vb1, W2t_v, vb2, hidden);

  for (int hop = 0; hop < 3; ++hop) {
    hipMemsetAsync(Sp, 0, (size_t)N_NODES * 128 * 4, stream);
    hipMemsetAsync(Sc, 0, (size_t)N_NODES * 128 * 4, stream);
    // S_p = scatter_mean(mlp_p([hc, hp, ep]), pn):  g0 = cn, g1 = pn (target)
    edge_mlp_kernel<<<EB, 256, 0, stream>>>(hidden, cn, pn, featP,
                                            W1t_p, pb1, W2t_p, pb2, Sp, rcp_p);
    // S_c = scatter_mean(mlp_c([hp, hc, ec]), cn):  g0 = pn, g1 = cn (target)
    edge_mlp_kernel<<<EB, 256, 0, stream>>>(hidden, pn, cn, featC,
                                            W1t_c, cb1, W2t_c, cb2, Sc, rcp_c);
    node_aggr_kernel<<<NB, 256, 0, stream>>>(hidden, Sp, Sc, p_mask, c_mask,
                                             stok, etok, W1t_a, ab1, W2t_a, ab2);
  }
  (void)in_sizes; (void)n_in; (void)out_size; (void)ws_size;
}

// Round 4
// 3143.410 us; speedup vs baseline: 2.0547x; 2.0547x over previous
//
#include <hip/hip_runtime.h>
#include <stdint.h>

#define N_NODES 50000
#define N_EDGES 400000

typedef short s8v __attribute__((ext_vector_type(8)));
typedef float f4v __attribute__((ext_vector_type(4)));

static __device__ __forceinline__ unsigned short f2bf(float f) {
  union { float f; uint32_t u; } v; v.f = f;
  return (unsigned short)((v.u + 0x7FFFu + ((v.u >> 16) & 1u)) >> 16);
}
static __device__ __forceinline__ ushort4 f2bf4(float4 v) {
  ushort4 o; o.x = f2bf(v.x); o.y = f2bf(v.y); o.z = f2bf(v.z); o.w = f2bf(v.w);
  return o;
}
static __device__ __forceinline__ f4v mfma16(s8v a, s8v b, f4v c) {
  return __builtin_amdgcn_mfma_f32_16x16x32_bf16(a, b, c, 0, 0, 0);
}
// async global->LDS, 16B/lane; LDS dest = wave-uniform base + lane*16
static __device__ __forceinline__ void gload_lds16(const void* g, void* l) {
  __builtin_amdgcn_global_load_lds(
      (const __attribute__((address_space(1))) uint32_t*)g,
      (__attribute__((address_space(3))) uint32_t*)l, 16, 0, 0);
}

// Staged weight layouts (prebuilt):
//   W1stg: [12 slices][4 kc][256 out][8]  bf16,  element = W1[s*32+kc*8+j][out]
//   W2stg: [ 8 slices][4 kc][128 out][8]  bf16,  element = W2[s*32+kc*8+j][out]
// Staging into LDS is fully linear (16B/lane), reads are 2-way-conflict max.

// =====================================================================
// Edge-message MLP (v1 dataflow, staged weights):
//   A = [hid[n0] | hid[n1] | feat[e]]  (64x384 bf16, XOR-swizzled in LDS)
//   H1 = relu(A @ W1 + b1); out = relu(H1 @ W2 + b2) * rcp[n1]
//   atomicAdd into Sacc[n1]
// =====================================================================
__global__ __launch_bounds__(256, 2) void edge_mlp_kernel(
    const float* __restrict__ hid,
    const int* __restrict__ n0idx, const int* __restrict__ n1idx,
    const unsigned short* __restrict__ feat,
    const unsigned short* __restrict__ W1stg, const float* __restrict__ b1,
    const unsigned short* __restrict__ W2stg, const float* __restrict__ b2,
    float* __restrict__ Sacc, const float* __restrict__ rcpv)
{
  __shared__ __align__(16) unsigned short ABUF[64 * 384];  // 48KB
  __shared__ __align__(16) unsigned short Wb[2][8192];     // 32KB
  const int tid = threadIdx.x, lane = tid & 63, wv = tid >> 6;
  const int l15 = lane & 15, kg = lane >> 4;
  const int base = blockIdx.x * 64;  // E % 64 == 0
  // idx arrays alias Wb[1] (dead once gather completes; Wb[1] first staged at s=0)
  int* n0s = (int*)(&Wb[1][0]);
  int* n1s = n0s + 64;
  if (tid < 64) {
    n0s[tid] = n0idx[base + tid];
    n1s[tid] = n1idx[base + tid];
  }
  // stage W1 slice 0 -> Wb[0]
#pragma unroll
  for (int i = 0; i < 4; ++i) {
    int q = wv * 4 + i;
    gload_lds16(W1stg + (size_t)q * 512 + lane * 8, &Wb[0][q * 512]);
  }
  __syncthreads();  // idx visible (also drains slice-0 staging)
  // gather A: seg0 = hid[n0], seg1 = hid[n1]  (f32 -> bf16)
#pragma unroll
  for (int it = 0; it < 16; ++it) {
    int i = tid + it * 256;
    int r = i >> 6, ch = i & 63, seg = ch >> 5, c4 = ch & 31;
    int node = seg ? n1s[r] : n0s[r];
    float4 v = *(const float4*)(hid + (size_t)node * 128 + c4 * 4);
    int unit = seg * 16 + (c4 >> 1);
    *(ushort4*)(ABUF + r * 384 + ((unit ^ (r & 7)) * 8) + (c4 & 1) * 4) = f2bf4(v);
  }
  // seg2 = feat[e] (already bf16, 16B copies)
#pragma unroll
  for (int it = 0; it < 4; ++it) {
    int i = tid + it * 256;
    int r = i >> 4, c8 = i & 15;
    uint4 f = *(const uint4*)(feat + (size_t)(base + r) * 128 + c8 * 8);
    int unit = 32 + c8;
    *(uint4*)(ABUF + r * 384 + ((unit ^ (r & 7)) * 8)) = f;
  }
  __syncthreads();  // A complete; idx reads done (Wb[1] now reusable)
  const int rr = wv * 16 + l15;
  s8v af1[12];
#pragma unroll
  for (int k = 0; k < 12; ++k)
    af1[k] = *(const s8v*)(ABUF + rr * 384 + (((k * 4 + kg) ^ (rr & 7)) * 8));
  const f4v vz = {0.f, 0.f, 0.f, 0.f};
  f4v acc1[16];
#pragma unroll
  for (int t = 0; t < 16; ++t) acc1[t] = vz;
  // ---- layer 1: 12 K-phases, double-buffered staged W ----
#pragma unroll
  for (int s = 0; s < 12; ++s) {
    if (s < 11) {
#pragma unroll
      for (int i = 0; i < 4; ++i) {
        int q = wv * 4 + i;
        gload_lds16(W1stg + (size_t)(s + 1) * 8192 + q * 512 + lane * 8,
                    &Wb[(s + 1) & 1][q * 512]);
      }
    } else {  // prefetch W2 slice 0 -> Wb[0]  ((11+1)&1 == 0)
#pragma unroll
      for (int i = 0; i < 2; ++i) {
        int q = wv * 2 + i;
        gload_lds16(W2stg + (size_t)q * 512 + lane * 8, &Wb[0][q * 512]);
      }
    }
#pragma unroll
    for (int t = 0; t < 16; ++t) {
      s8v b = *(const s8v*)(&Wb[s & 1][kg * 2048 + (t * 16 + l15) * 8]);
      acc1[t] = mfma16(af1[s], b, acc1[t]);
    }
    __syncthreads();
  }
  // H1 = relu(acc1 + b1) -> ABUF as [64][256] (XOR-swizzled)
#pragma unroll
  for (int t = 0; t < 16; ++t) {
    int c = t * 16 + l15;
    float bb = b1[c];
#pragma unroll
    for (int j = 0; j < 4; ++j) {
      int r = wv * 16 + kg * 4 + j;
      ABUF[r * 256 + (((c >> 3) ^ (r & 7)) * 8) + (c & 7)] =
          f2bf(fmaxf(acc1[t][j] + bb, 0.f));
    }
  }
  __syncthreads();
  s8v af2[8];
#pragma unroll
  for (int k = 0; k < 8; ++k)
    af2[k] = *(const s8v*)(ABUF + rr * 256 + (((k * 4 + kg) ^ (l15 & 7)) * 8));
  f4v acc2[8];
#pragma unroll
  for (int t = 0; t < 8; ++t) acc2[t] = vz;
  // ---- layer 2: 8 K-phases ----
#pragma unroll
  for (int s = 0; s < 8; ++s) {
    if (s < 7) {
#pragma unroll
      for (int i = 0; i < 2; ++i) {
        int q = wv * 2 + i;
        gload_lds16(W2stg + (size_t)(s + 1) * 4096 + q * 512 + lane * 8,
                    &Wb[(s + 1) & 1][q * 512]);
      }
    }
#pragma unroll
    for (int t = 0; t < 8; ++t) {
      s8v b = *(const s8v*)(&Wb[s & 1][kg * 1024 + (t * 16 + l15) * 8]);
      acc2[t] = mfma16(af2[s], b, acc2[t]);
    }
    __syncthreads();
  }
  // epilogue: reload idx from global (L2-hot), scale, atomic scatter
  int n1r[4]; float tscr[4];
#pragma unroll
  for (int j = 0; j < 4; ++j) {
    int r = wv * 16 + kg * 4 + j;
    int n1 = n1idx[base + r];
    n1r[j] = n1; tscr[j] = rcpv[n1];
  }
#pragma unroll
  for (int t = 0; t < 8; ++t) {
    int c = t * 16 + l15;
    float bb = b2[c];
#pragma unroll
    for (int j = 0; j < 4; ++j) {
      float v = fmaxf(acc2[t][j] + bb, 0.f) * tscr[j];
      atomicAdd(Sacc + (size_t)n1r[j] * 128 + c, v);
    }
  }
}

// =====================================================================
// Aggr MLP (fused A-build, staged weights):
//   A = [hid | Sp+pm*st | Sc+cm*et]; hid += relu(mlp_a(A))
// =====================================================================
__global__ __launch_bounds__(256, 2) void aggr_kernel(
    float* __restrict__ hid,
    const float* __restrict__ Sp, const float* __restrict__ Sc,
    const float* __restrict__ pm, const float* __restrict__ cm,
    const float* __restrict__ st, const float* __restrict__ et,
    const unsigned short* __restrict__ W1stg, const float* __restrict__ b1,
    const unsigned short* __restrict__ W2stg, const float* __restrict__ b2)
{
  __shared__ __align__(16) unsigned short ABUF[64 * 384];  // 48KB
  __shared__ __align__(16) unsigned short Wb[2][8192];     // 32KB
  const int tid = threadIdx.x, lane = tid & 63, wv = tid >> 6;
  const int l15 = lane & 15, kg = lane >> 4;
  const int base = blockIdx.x * 64;
  // stage W1 slice 0
#pragma unroll
  for (int i = 0; i < 4; ++i) {
    int q = wv * 4 + i;
    gload_lds16(W1stg + (size_t)q * 512 + lane * 8, &Wb[0][q * 512]);
  }
  // build A tile
#pragma unroll
  for (int it = 0; it < 24; ++it) {
    int i = tid + it * 256;
    int r = i / 96, q = i - r * 96;
    int seg = q >> 5, c4 = q & 31;
    int n = base + r;
    float4 v = {0.f, 0.f, 0.f, 0.f};
    if (n < N_NODES) {
      if (seg == 0) {
        v = *(const float4*)(hid + (size_t)n * 128 + c4 * 4);
      } else if (seg == 1) {
        v = *(const float4*)(Sp + (size_t)n * 128 + c4 * 4);
        float m = pm[n]; const float4 t = *(const float4*)(st + c4 * 4);
        v.x = fmaf(m, t.x, v.x); v.y = fmaf(m, t.y, v.y);
        v.z = fmaf(m, t.z, v.z); v.w = fmaf(m, t.w, v.w);
      } else {
        v = *(const float4*)(Sc + (size_t)n * 128 + c4 * 4);
        float m = cm[n]; const float4 t = *(const float4*)(et + c4 * 4);
        v.x = fmaf(m, t.x, v.x); v.y = fmaf(m, t.y, v.y);
        v.z = fmaf(m, t.z, v.z); v.w = fmaf(m, t.w, v.w);
      }
    }
    int unit = seg * 16 + (c4 >> 1);
    *(ushort4*)(ABUF + r * 384 + ((unit ^ (r & 7)) * 8) + (c4 & 1) * 4) = f2bf4(v);
  }
  __syncthreads();
  const int rr = wv * 16 + l15;
  s8v af1[12];
#pragma unroll
  for (int k = 0; k < 12; ++k)
    af1[k] = *(const s8v*)(ABUF + rr * 384 + (((k * 4 + kg) ^ (rr & 7)) * 8));
  const f4v vz = {0.f, 0.f, 0.f, 0.f};
  f4v acc1[16];
#pragma unroll
  for (int t = 0; t < 16; ++t) acc1[t] = vz;
#pragma unroll
  for (int s = 0; s < 12; ++s) {
    if (s < 11) {
#pragma unroll
      for (int i = 0; i < 4; ++i) {
        int q = wv * 4 + i;
        gload_lds16(W1stg + (size_t)(s + 1) * 8192 + q * 512 + lane * 8,
                    &Wb[(s + 1) & 1][q * 512]);
      }
    } else {
#pragma unroll
      for (int i = 0; i < 2; ++i) {
        int q = wv * 2 + i;
        gload_lds16(W2stg + (size_t)q * 512 + lane * 8, &Wb[0][q * 512]);
      }
    }
#pragma unroll
    for (int t = 0; t < 16; ++t) {
      s8v b = *(const s8v*)(&Wb[s & 1][kg * 2048 + (t * 16 + l15) * 8]);
      acc1[t] = mfma16(af1[s], b, acc1[t]);
    }
    __syncthreads();
  }
#pragma unroll
  for (int t = 0; t < 16; ++t) {
    int c = t * 16 + l15;
    float bb = b1[c];
#pragma unroll
    for (int j = 0; j < 4; ++j) {
      int r = wv * 16 + kg * 4 + j;
      ABUF[r * 256 + (((c >> 3) ^ (r & 7)) * 8) + (c & 7)] =
          f2bf(fmaxf(acc1[t][j] + bb, 0.f));
    }
  }
  __syncthreads();
  s8v af2[8];
#pragma unroll
  for (int k = 0; k < 8; ++k)
    af2[k] = *(const s8v*)(ABUF + rr * 256 + (((k * 4 + kg) ^ (l15 & 7)) * 8));
  f4v acc2[8];
#pragma unroll
  for (int t = 0; t < 8; ++t) acc2[t] = vz;
#pragma unroll
  for (int s = 0; s < 8; ++s) {
    if (s < 7) {
#pragma unroll
      for (int i = 0; i < 2; ++i) {
        int q = wv * 2 + i;
        gload_lds16(W2stg + (size_t)(s + 1) * 4096 + q * 512 + lane * 8,
                    &Wb[(s + 1) & 1][q * 512]);
      }
    }
#pragma unroll
    for (int t = 0; t < 8; ++t) {
      s8v b = *(const s8v*)(&Wb[s & 1][kg * 1024 + (t * 16 + l15) * 8]);
      acc2[t] = mfma16(af2[s], b, acc2[t]);
    }
    __syncthreads();
  }
#pragma unroll
  for (int t = 0; t < 8; ++t) {
    int c = t * 16 + l15;
    float bb = b2[c];
#pragma unroll
    for (int j = 0; j < 4; ++j) {
      int ro = base + wv * 16 + kg * 4 + j;
      if (ro < N_NODES) hid[(size_t)ro * 128 + c] += fmaxf(acc2[t][j] + bb, 0.f);
    }
  }
}

// =====================================================================
// one-time kernels: v1-proven paths
// =====================================================================
template <int KST1>
static __device__ __forceinline__ void mlp_core(
    unsigned short* __restrict__ BUF,
    const unsigned short* __restrict__ W1t, const float* __restrict__ b1,
    const unsigned short* __restrict__ W2t,
    int l15, int kg, int wr0, f4v* __restrict__ acc2)
{
  const int ldA = KST1 * 32 + 8;
  const f4v vzero = {0.f, 0.f, 0.f, 0.f};
  const unsigned short* Arow = BUF + (size_t)(wr0 + l15) * ldA;
  s8v af1[KST1];
#pragma unroll
  for (int k = 0; k < KST1; ++k) af1[k] = *(const s8v*)(Arow + k * 32 + kg * 8);
  __syncthreads();
  f4v acc1[16];
#pragma unroll
  for (int t = 0; t < 16; ++t) acc1[t] = vzero;
#pragma unroll
  for (int k = 0; k < KST1; ++k) {
#pragma unroll
    for (int t = 0; t < 16; ++t) {
      s8v b = *(const s8v*)(W1t + (size_t)(t * 16 + l15) * (KST1 * 32) + k * 32 + kg * 8);
      acc1[t] = mfma16(af1[k], b, acc1[t]);
    }
  }
#pragma unroll
  for (int t = 0; t < 16; ++t) {
    int c = t * 16 + l15;
    float bb = b1[c];
#pragma unroll
    for (int j = 0; j < 4; ++j) {
      BUF[(size_t)(wr0 + kg * 4 + j) * 264 + c] = f2bf(fmaxf(acc1[t][j] + bb, 0.f));
    }
  }
  const unsigned short* Hrow = BUF + (size_t)(wr0 + l15) * 264;
  s8v af2[8];
#pragma unroll
  for (int k = 0; k < 8; ++k) af2[k] = *(const s8v*)(Hrow + k * 32 + kg * 8);
#pragma unroll
  for (int t = 0; t < 8; ++t) acc2[t] = vzero;
#pragma unroll
  for (int k = 0; k < 8; ++k) {
#pragma unroll
    for (int t = 0; t < 8; ++t) {
      s8v b = *(const s8v*)(W2t + (size_t)(t * 16 + l15) * 256 + k * 32 + kg * 8);
      acc2[t] = mfma16(af2[k], b, acc2[t]);
    }
  }
}

__global__ __launch_bounds__(256, 2) void v_mlp_kernel(
    const float* __restrict__ x,
    const unsigned short* __restrict__ W1t, const float* __restrict__ b1,
    const unsigned short* __restrict__ W2t, const float* __restrict__ b2,
    float* __restrict__ hid)
{
  __shared__ unsigned short BUF[64 * 264];
  const int tid = threadIdx.x;
  const int base = blockIdx.x * 64;
#pragma unroll
  for (int it = 0; it < 8; ++it) {
    int i = tid + it * 256;
    int r = i >> 5, c4 = i & 31, n = base + r;
    float4 v = {0.f, 0.f, 0.f, 0.f};
    if (n < N_NODES) v = *(const float4*)(x + (size_t)n * 128 + c4 * 4);
    *(ushort4*)(BUF + r * 136 + c4 * 4) = f2bf4(v);
  }
  __syncthreads();
  const int lane = tid & 63, wv = tid >> 6;
  const int l15 = lane & 15, kg = lane >> 4, wr0 = wv * 16;
  f4v acc2[8];
  mlp_core<4>(BUF, W1t, b1, W2t, l15, kg, wr0, acc2);
#pragma unroll
  for (int t = 0; t < 8; ++t) {
    int c = t * 16 + l15;
    float bb = b2[c];
#pragma unroll
    for (int j = 0; j < 4; ++j) {
      int n = base + wr0 + kg * 4 + j;
      if (n < N_NODES) hid[(size_t)n * 128 + c] = fmaxf(acc2[t][j] + bb, 0.f);
    }
  }
}

__global__ __launch_bounds__(256, 2) void edge_feat_kernel(
    const float* __restrict__ ind, const float* __restrict__ W1, const float* __restrict__ b1,
    const unsigned short* __restrict__ W2t, const float* __restrict__ b2,
    unsigned short* __restrict__ feat)
{
  __shared__ unsigned short H1[64 * 264];
  __shared__ float xs[64];
  const int tid = threadIdx.x;
  const int base = blockIdx.x * 64;
  if (tid < 64) xs[tid] = ind[base + tid];
  __syncthreads();
  const float w = W1[tid];
  const float bb = b1[tid];
  for (int r = 0; r < 64; ++r) {
    H1[r * 264 + tid] = f2bf(fmaxf(fmaf(xs[r], w, bb), 0.f));
  }
  __syncthreads();
  const int lane = tid & 63, wv = tid >> 6;
  const int l15 = lane & 15, kg = lane >> 4, wr0 = wv * 16;
  const unsigned short* Hrow = H1 + (size_t)(wr0 + l15) * 264;
  const f4v vzero = {0.f, 0.f, 0.f, 0.f};
  s8v af2[8];
#pragma unroll
  for (int k = 0; k < 8; ++k) af2[k] = *(const s8v*)(Hrow + k * 32 + kg * 8);
  f4v acc2[8];
#pragma unroll
  for (int t = 0; t < 8; ++t) acc2[t] = vzero;
#pragma unroll
  for (int k = 0; k < 8; ++k) {
#pragma unroll
    for (int t = 0; t < 8; ++t) {
      s8v b = *(const s8v*)(W2t + (size_t)(t * 16 + l15) * 256 + k * 32 + kg * 8);
      acc2[t] = mfma16(af2[k], b, acc2[t]);
    }
  }
#pragma unroll
  for (int t = 0; t < 8; ++t) {
    int c = t * 16 + l15;
    float b2c = b2[c];
#pragma unroll
    for (int j = 0; j < 4; ++j) {
      int e = base + wr0 + kg * 4 + j;
      feat[(size_t)e * 128 + c] = f2bf(fmaxf(acc2[t][j] + b2c, 0.f));
    }
  }
}

// ---------------- prep kernels ----------------
__global__ void transpose_w(const float* __restrict__ W, unsigned short* __restrict__ Wt,
                            int K, int NH) {
  int i = blockIdx.x * 256 + threadIdx.x;
  if (i < K * NH) {
    int k = i / NH, n = i - k * NH;
    Wt[(size_t)n * K + k] = f2bf(W[i]);
  }
}

// W [384][256] f32 -> stg [12][4][256][8] bf16
__global__ void build_w1stg(const float* __restrict__ W, unsigned short* __restrict__ stg) {
  int i = blockIdx.x * 256 + threadIdx.x;
  if (i < 384 * 256) {
    int k = i >> 8, out = i & 255;
    int s = k >> 5, kc = (k >> 3) & 3, j = k & 7;
    stg[(size_t)s * 8192 + kc * 2048 + out * 8 + j] = f2bf(W[i]);
  }
}

// W [256][128] f32 -> stg [8][4][128][8] bf16
__global__ void build_w2stg(const float* __restrict__ W, unsigned short* __restrict__ stg) {
  int i = blockIdx.x * 256 + threadIdx.x;
  if (i < 256 * 128) {
    int k = i >> 7, out = i & 127;
    int s = k >> 5, kc = (k >> 3) & 3, j = k & 7;
    stg[(size_t)s * 4096 + kc * 1024 + out * 8 + j] = f2bf(W[i]);
  }
}

__global__ void count_kernel(const int* __restrict__ pn, const int* __restrict__ cn,
                             float* __restrict__ cp, float* __restrict__ cc) {
  int i = blockIdx.x * 256 + threadIdx.x;
  if (i < N_EDGES) {
    atomicAdd(cp + pn[i], 1.f);
    atomicAdd(cc + cn[i], 1.f);
  }
}

__global__ void rcp_kernel(float* __restrict__ cp, float* __restrict__ cc) {
  int i = blockIdx.x * 256 + threadIdx.x;
  if (i < N_NODES) {
    cp[i] = 1.f / fmaxf(cp[i], 1.f);
    cc[i] = 1.f / fmaxf(cc[i], 1.f);
  }
}

extern "C" void kernel_launch(void* const* d_in, const int* in_sizes, int n_in,
                              void* d_out, int out_size, void* d_ws, size_t ws_size,
                              hipStream_t stream) {
  const float* batch_token = (const float*)d_in[0];
  const int*   pn          = (const int*)d_in[1];
  const int*   cn          = (const int*)d_in[2];
  const float* indP        = (const float*)d_in[3];
  const float* indC        = (const float*)d_in[4];
  const float* p_mask      = (const float*)d_in[5];
  const float* c_mask      = (const float*)d_in[6];
  const float* stok        = (const float*)d_in[7];
  const float* etok        = (const float*)d_in[8];
  const float* vW1 = (const float*)d_in[9],  *vb1 = (const float*)d_in[10];
  const float* vW2 = (const float*)d_in[11], *vb2 = (const float*)d_in[12];
  const float* eW1 = (const float*)d_in[13], *eb1 = (const float*)d_in[14];
  const float* eW2 = (const float*)d_in[15], *eb2 = (const float*)d_in[16];
  const float* pW1 = (const float*)d_in[17], *pb1 = (const float*)d_in[18];
  const float* pW2 = (const float*)d_in[19], *pb2 = (const float*)d_in[20];
  const float* cW1 = (const float*)d_in[21], *cb1 = (const float*)d_in[22];
  const float* cW2 = (const float*)d_in[23], *cb2 = (const float*)d_in[24];
  const float* aW1 = (const float*)d_in[25], *ab1 = (const float*)d_in[26];
  const float* aW2 = (const float*)d_in[27], *ab2 = (const float*)d_in[28];

  // ws budget deliberately matches v1's proven ~258MB footprint.
  char* w = (char*)d_ws;
  auto alloc = [&](size_t bytes) -> char* {
    char* p = w;
    w += (bytes + 255) & ~(size_t)255;
    return p;
  };
  float* Sp    = (float*)alloc((size_t)N_NODES * 128 * 4);   // 25.6MB
  float* Sc    = (float*)alloc((size_t)N_NODES * 128 * 4);   // 25.6MB
  float* rcp_p = (float*)alloc((size_t)N_NODES * 4);
  float* rcp_c = (float*)alloc((size_t)N_NODES * 4);
  unsigned short* featP = (unsigned short*)alloc((size_t)N_EDGES * 128 * 2);  // 102.4MB
  unsigned short* featC = (unsigned short*)alloc((size_t)N_EDGES * 128 * 2);  // 102.4MB
  unsigned short* W1stg_p = (unsigned short*)alloc(12 * 8192 * 2);
  unsigned short* W1stg_c = (unsigned short*)alloc(12 * 8192 * 2);
  unsigned short* W1stg_a = (unsigned short*)alloc(12 * 8192 * 2);
  unsigned short* W2stg_p = (unsigned short*)alloc(8 * 4096 * 2);
  unsigned short* W2stg_c = (unsigned short*)alloc(8 * 4096 * 2);
  unsigned short* W2stg_a = (unsigned short*)alloc(8 * 4096 * 2);
  unsigned short* W1t_v   = (unsigned short*)alloc(256 * 128 * 2);
  unsigned short* W2t_v   = (unsigned short*)alloc(128 * 256 * 2);
  unsigned short* W2t_e   = (unsigned short*)alloc(128 * 256 * 2);

  float* hidden = (float*)d_out;

  const int EB = N_EDGES / 64;          // 6250
  const int NB = (N_NODES + 63) / 64;   // 782

  // counts -> reciprocals
  hipMemsetAsync(rcp_p, 0, (size_t)N_NODES * 4, stream);
  hipMemsetAsync(rcp_c, 0, (size_t)N_NODES * 4, stream);
  count_kernel<<<(N_EDGES + 255) / 256, 256, 0, stream>>>(pn, cn, rcp_p, rcp_c);
  rcp_kernel<<<(N_NODES + 255) / 256, 256, 0, stream>>>(rcp_p, rcp_c);

  // weight prep
  transpose_w<<<(128 * 256 + 255) / 256, 256, 0, stream>>>(vW1, W1t_v, 128, 256);
  transpose_w<<<(256 * 128 + 255) / 256, 256, 0, stream>>>(vW2, W2t_v, 256, 128);
  transpose_w<<<(256 * 128 + 255) / 256, 256, 0, stream>>>(eW2, W2t_e, 256, 128);
  build_w1stg<<<(384 * 256 + 255) / 256, 256, 0, stream>>>(pW1, W1stg_p);
  build_w1stg<<<(384 * 256 + 255) / 256, 256, 0, stream>>>(cW1, W1stg_c);
  build_w1stg<<<(384 * 256 + 255) / 256, 256, 0, stream>>>(aW1, W1stg_a);
  build_w2stg<<<(256 * 128 + 255) / 256, 256, 0, stream>>>(pW2, W2stg_p);
  build_w2stg<<<(256 * 128 + 255) / 256, 256, 0, stream>>>(cW2, W2stg_c);
  build_w2stg<<<(256 * 128 + 255) / 256, 256, 0, stream>>>(aW2, W2stg_a);

  // one-time: edge features + initial hidden
  edge_feat_kernel<<<EB, 256, 0, stream>>>(indP, eW1, eb1, W2t_e, eb2, featP);
  edge_feat_kernel<<<EB, 256, 0, stream>>>(indC, eW1, eb1, W2t_e, eb2, featC);
  v_mlp_kernel<<<NB, 256, 0, stream>>>(batch_token, W1t_v, vb1, W2t_v, vb2, hidden);

  for (int hop = 0; hop < 3; ++hop) {
    hipMemsetAsync(Sp, 0, (size_t)N_NODES * 128 * 4, stream);
    hipMemsetAsync(Sc, 0, (size_t)N_NODES * 128 * 4, stream);
    // S_p: A=[hc|hp|ep], target pn
    edge_mlp_kernel<<<EB, 256, 0, stream>>>(hidden, cn, pn, featP,
                                            W1stg_p, pb1, W2stg_p, pb2, Sp, rcp_p);
    // S_c: A=[hp|hc|ec], target cn
    edge_mlp_kernel<<<EB, 256, 0, stream>>>(hidden, pn, cn, featC,
                                            W1stg_c, cb1, W2stg_c, cb2, Sc, rcp_c);
    aggr_kernel<<<NB, 256, 0, stream>>>(hidden, Sp, Sc, p_mask, c_mask,
                                        stok, etok, W1stg_a, ab1, W2stg_a, ab2);
  }
  (void)in_sizes; (void)n_in; (void)out_size; (void)ws_size;
}

// Round 5
// 2923.593 us; speedup vs baseline: 2.2092x; 1.0752x over previous
//
#include <hip/hip_runtime.h>
#include <stdint.h>

#define N_NODES 50000
#define N_EDGES 400000

typedef short s8v __attribute__((ext_vector_type(8)));
typedef float f4v __attribute__((ext_vector_type(4)));

static __device__ __forceinline__ unsigned short f2bf(float f) {
  union { float f; uint32_t u; } v; v.f = f;
  return (unsigned short)((v.u + 0x7FFFu + ((v.u >> 16) & 1u)) >> 16);
}
static __device__ __forceinline__ ushort4 f2bf4(float4 v) {
  ushort4 o; o.x = f2bf(v.x); o.y = f2bf(v.y); o.z = f2bf(v.z); o.w = f2bf(v.w);
  return o;
}
static __device__ __forceinline__ void bf2(uint32_t u, float& a, float& b) {
  union { uint32_t x; float f; } lo, hi;
  lo.x = u << 16; hi.x = u & 0xffff0000u;
  a = lo.f; b = hi.f;
}
static __device__ __forceinline__ f4v mfma16(s8v a, s8v b, f4v c) {
  return __builtin_amdgcn_mfma_f32_16x16x32_bf16(a, b, c, 0, 0, 0);
}
// async global->LDS, 16B/lane; LDS dest = wave-uniform base + lane*16
static __device__ __forceinline__ void gload_lds16(const void* g, void* l) {
  __builtin_amdgcn_global_load_lds(
      (const __attribute__((address_space(1))) uint32_t*)g,
      (__attribute__((address_space(3))) uint32_t*)l, 16, 0, 0);
}

// Staged weight layouts (prebuilt):
//   W1stg : [12][4 kc][256 out][8] bf16  (K=384 -> 256)
//   W1cstg: [ 4][4 kc][256 out][8] bf16  (K=128 -> 256, W1 rows 256..383)
//   W2stg : [ 8][4 kc][128 out][8] bf16  (K=256 -> 128)

// =====================================================================
// Z-GEMM: Z[n][g*256+c] = sum_k bf16(hid[n][k]) * Wg[k][c]   (bf16 out)
// B group (64KB, XOR-swizzled, prebuilt) resident in LDS. Z stride 512.
// =====================================================================
__global__ __launch_bounds__(256) void z_gemm_kernel(
    const float* __restrict__ hid, const unsigned short* __restrict__ Wsw,
    unsigned short* __restrict__ Z)
{
  __shared__ __align__(16) unsigned short B[256 * 128];
  const int tid = threadIdx.x, lane = tid & 63, wv = tid >> 6;
  const int g = blockIdx.y;
  const unsigned short* src = Wsw + (size_t)g * 256 * 128;
#pragma unroll
  for (int it = 0; it < 16; ++it) {
    int q = it * 4 + wv;
    gload_lds16(src + (size_t)q * 512 + lane * 8, &B[q * 512]);
  }
  __syncthreads();
  const int l15 = lane & 15, kg = lane >> 4;
  const f4v vz = {0.f, 0.f, 0.f, 0.f};
  for (int c0 = blockIdx.x; c0 < (N_NODES + 63) / 64; c0 += gridDim.x) {
    const int base = c0 * 64;
    const int row = base + wv * 16 + l15;
    s8v af[4];
#pragma unroll
    for (int k = 0; k < 4; ++k) {
      float4 u0 = {0.f,0.f,0.f,0.f}, u1 = {0.f,0.f,0.f,0.f};
      if (row < N_NODES) {
        u0 = *(const float4*)(hid + (size_t)row * 128 + k * 32 + kg * 8);
        u1 = *(const float4*)(hid + (size_t)row * 128 + k * 32 + kg * 8 + 4);
      }
      s8v a;
      a[0] = (short)f2bf(u0.x); a[1] = (short)f2bf(u0.y);
      a[2] = (short)f2bf(u0.z); a[3] = (short)f2bf(u0.w);
      a[4] = (short)f2bf(u1.x); a[5] = (short)f2bf(u1.y);
      a[6] = (short)f2bf(u1.z); a[7] = (short)f2bf(u1.w);
      af[k] = a;
    }
    f4v acc[16];
#pragma unroll
    for (int t = 0; t < 16; ++t) acc[t] = vz;
#pragma unroll
    for (int k = 0; k < 4; ++k) {
#pragma unroll
      for (int t = 0; t < 16; ++t) {
        int j = t * 16 + l15;
        s8v b = *(const s8v*)(&B[j * 128 + (((k * 4 + kg) ^ (j & 7)) * 8)]);
        acc[t] = mfma16(af[k], b, acc[t]);
      }
    }
#pragma unroll
    for (int t = 0; t < 16; ++t) {
      int c = t * 16 + l15;
#pragma unroll
      for (int j = 0; j < 4; ++j) {
        int ro = base + wv * 16 + kg * 4 + j;
        if (ro < N_NODES) Z[(size_t)ro * 512 + g * 256 + c] = f2bf(acc[t][j]);
      }
    }
  }
}

// =====================================================================
// Edge message (Z-based):
//   acc1 = feat[e] @ W1c (4 staged phases) + b1
//   H1 = relu(acc1 + Z[n0][0:256] + Z[n1][256:512])
//   out = relu(H1 @ W2 + b2) * rcp[n1] -> atomicAdd Sacc[n1]
// =====================================================================
__global__ __launch_bounds__(256, 2) void edge_msg2_kernel(
    const unsigned short* __restrict__ Z,     // [N][512]
    const unsigned short* __restrict__ feat,  // [E][128]
    const int* __restrict__ n0idx, const int* __restrict__ n1idx,
    const unsigned short* __restrict__ W1cstg, const float* __restrict__ b1,
    const unsigned short* __restrict__ W2stg, const float* __restrict__ b2,
    float* __restrict__ Sacc, const float* __restrict__ rcpv)
{
  __shared__ __align__(16) unsigned short H1[64 * 256];  // 32KB swizzled
  __shared__ __align__(16) unsigned short Wb[2][8192];   // 32KB
  __shared__ int n0s[64], n1s[64];
  const int tid = threadIdx.x, lane = tid & 63, wv = tid >> 6;
  const int l15 = lane & 15, kg = lane >> 4;
  const int base = blockIdx.x * 64;  // E % 64 == 0
  if (tid < 64) {
    n0s[tid] = n0idx[base + tid];
    n1s[tid] = n1idx[base + tid];
  }
  // stage W1c slice 0
#pragma unroll
  for (int i = 0; i < 4; ++i) {
    int q = wv * 4 + i;
    gload_lds16(W1cstg + (size_t)q * 512 + lane * 8, &Wb[0][q * 512]);
  }
  __syncthreads();  // idx visible (drains slice-0 too)
  // issue Z gathers early (consumed after the phase loop)
  uint4 za[8], zb[8];
#pragma unroll
  for (int it = 0; it < 8; ++it) {
    int i = tid + it * 256;
    int r = i >> 5, c8 = i & 31;
    za[it] = *(const uint4*)(Z + (size_t)n0s[r] * 512 + c8 * 8);
    zb[it] = *(const uint4*)(Z + (size_t)n1s[r] * 512 + 256 + c8 * 8);
  }
  const int erow = base + wv * 16 + l15;
  s8v af0[4];
#pragma unroll
  for (int k = 0; k < 4; ++k)
    af0[k] = *(const s8v*)(feat + (size_t)erow * 128 + k * 32 + kg * 8);
  const f4v vz = {0.f, 0.f, 0.f, 0.f};
  f4v acc1[16];
#pragma unroll
  for (int t = 0; t < 16; ++t) acc1[t] = vz;
  // ---- layer-1 edge part: 4 K-phases ----
#pragma unroll
  for (int s = 0; s < 4; ++s) {
    if (s < 3) {
#pragma unroll
      for (int i = 0; i < 4; ++i) {
        int q = wv * 4 + i;
        gload_lds16(W1cstg + (size_t)(s + 1) * 8192 + q * 512 + lane * 8,
                    &Wb[(s + 1) & 1][q * 512]);
      }
    } else {  // prefetch W2 slice 0 -> Wb[0]  ((3+1)&1 == 0)
#pragma unroll
      for (int i = 0; i < 2; ++i) {
        int q = wv * 2 + i;
        gload_lds16(W2stg + (size_t)q * 512 + lane * 8, &Wb[0][q * 512]);
      }
    }
#pragma unroll
    for (int t = 0; t < 16; ++t) {
      s8v b = *(const s8v*)(&Wb[s & 1][kg * 2048 + (t * 16 + l15) * 8]);
      acc1[t] = mfma16(af0[s], b, acc1[t]);
    }
    __syncthreads();
  }
  // ---- H1 = acc1 + b1 (pre-relu, swizzled) ----
#pragma unroll
  for (int t = 0; t < 16; ++t) {
    int c = t * 16 + l15;
    float bb = b1[c];
#pragma unroll
    for (int j = 0; j < 4; ++j) {
      int r = wv * 16 + kg * 4 + j;
      H1[r * 256 + (((c >> 3) ^ (r & 7)) * 8) + (c & 7)] = f2bf(acc1[t][j] + bb);
    }
  }
  __syncthreads();
  // ---- RMW: H1 = relu(H1 + Za + Zb) ----
#pragma unroll
  for (int it = 0; it < 8; ++it) {
    int i = tid + it * 256;
    int r = i >> 5, c8 = i & 31;
    unsigned short* hp = H1 + r * 256 + ((c8 ^ (r & 7)) * 8);
    uint4 h = *(const uint4*)hp;
    uint32_t uh[4] = {h.x, h.y, h.z, h.w};
    uint32_t ua[4] = {za[it].x, za[it].y, za[it].z, za[it].w};
    uint32_t ub[4] = {zb[it].x, zb[it].y, zb[it].z, zb[it].w};
    uint32_t uo[4];
#pragma unroll
    for (int q = 0; q < 4; ++q) {
      float h0, h1f, a0, a1f, b0, b1f;
      bf2(uh[q], h0, h1f); bf2(ua[q], a0, a1f); bf2(ub[q], b0, b1f);
      float s0 = fmaxf(h0 + a0 + b0, 0.f);
      float s1 = fmaxf(h1f + a1f + b1f, 0.f);
      uo[q] = (uint32_t)f2bf(s0) | ((uint32_t)f2bf(s1) << 16);
    }
    uint4 pk; pk.x = uo[0]; pk.y = uo[1]; pk.z = uo[2]; pk.w = uo[3];
    *(uint4*)hp = pk;
  }
  __syncthreads();
  // ---- layer 2: 8 K-phases ----
  const int rr = wv * 16 + l15;
  s8v af2[8];
#pragma unroll
  for (int k = 0; k < 8; ++k)
    af2[k] = *(const s8v*)(H1 + rr * 256 + (((k * 4 + kg) ^ (l15 & 7)) * 8));
  f4v acc2[8];
#pragma unroll
  for (int t = 0; t < 8; ++t) acc2[t] = vz;
#pragma unroll
  for (int s = 0; s < 8; ++s) {
    if (s < 7) {
#pragma unroll
      for (int i = 0; i < 2; ++i) {
        int q = wv * 2 + i;
        gload_lds16(W2stg + (size_t)(s + 1) * 4096 + q * 512 + lane * 8,
                    &Wb[(s + 1) & 1][q * 512]);
      }
    }
#pragma unroll
    for (int t = 0; t < 8; ++t) {
      s8v b = *(const s8v*)(&Wb[s & 1][kg * 1024 + (t * 16 + l15) * 8]);
      acc2[t] = mfma16(af2[s], b, acc2[t]);
    }
    __syncthreads();
  }
  // epilogue: reload idx from global (L2-hot), scale, atomic scatter
  int n1r[4]; float tscr[4];
#pragma unroll
  for (int j = 0; j < 4; ++j) {
    int r = wv * 16 + kg * 4 + j;
    int n1 = n1idx[base + r];
    n1r[j] = n1; tscr[j] = rcpv[n1];
  }
#pragma unroll
  for (int t = 0; t < 8; ++t) {
    int c = t * 16 + l15;
    float bb = b2[c];
#pragma unroll
    for (int j = 0; j < 4; ++j) {
      float v = fmaxf(acc2[t][j] + bb, 0.f) * tscr[j];
      atomicAdd(Sacc + (size_t)n1r[j] * 128 + c, v);
    }
  }
}

// =====================================================================
// v4 fallback: full per-edge MLP with staged weights (proven)
// =====================================================================
__global__ __launch_bounds__(256, 2) void edge_mlp_kernel(
    const float* __restrict__ hid,
    const int* __restrict__ n0idx, const int* __restrict__ n1idx,
    const unsigned short* __restrict__ feat,
    const unsigned short* __restrict__ W1stg, const float* __restrict__ b1,
    const unsigned short* __restrict__ W2stg, const float* __restrict__ b2,
    float* __restrict__ Sacc, const float* __restrict__ rcpv)
{
  __shared__ __align__(16) unsigned short ABUF[64 * 384];  // 48KB
  __shared__ __align__(16) unsigned short Wb[2][8192];     // 32KB
  const int tid = threadIdx.x, lane = tid & 63, wv = tid >> 6;
  const int l15 = lane & 15, kg = lane >> 4;
  const int base = blockIdx.x * 64;  // E % 64 == 0
  int* n0s = (int*)(&Wb[1][0]);
  int* n1s = n0s + 64;
  if (tid < 64) {
    n0s[tid] = n0idx[base + tid];
    n1s[tid] = n1idx[base + tid];
  }
#pragma unroll
  for (int i = 0; i < 4; ++i) {
    int q = wv * 4 + i;
    gload_lds16(W1stg + (size_t)q * 512 + lane * 8, &Wb[0][q * 512]);
  }
  __syncthreads();
#pragma unroll
  for (int it = 0; it < 16; ++it) {
    int i = tid + it * 256;
    int r = i >> 6, ch = i & 63, seg = ch >> 5, c4 = ch & 31;
    int node = seg ? n1s[r] : n0s[r];
    float4 v = *(const float4*)(hid + (size_t)node * 128 + c4 * 4);
    int unit = seg * 16 + (c4 >> 1);
    *(ushort4*)(ABUF + r * 384 + ((unit ^ (r & 7)) * 8) + (c4 & 1) * 4) = f2bf4(v);
  }
#pragma unroll
  for (int it = 0; it < 4; ++it) {
    int i = tid + it * 256;
    int r = i >> 4, c8 = i & 15;
    uint4 f = *(const uint4*)(feat + (size_t)(base + r) * 128 + c8 * 8);
    int unit = 32 + c8;
    *(uint4*)(ABUF + r * 384 + ((unit ^ (r & 7)) * 8)) = f;
  }
  __syncthreads();
  const int rr = wv * 16 + l15;
  s8v af1[12];
#pragma unroll
  for (int k = 0; k < 12; ++k)
    af1[k] = *(const s8v*)(ABUF + rr * 384 + (((k * 4 + kg) ^ (rr & 7)) * 8));
  const f4v vz = {0.f, 0.f, 0.f, 0.f};
  f4v acc1[16];
#pragma unroll
  for (int t = 0; t < 16; ++t) acc1[t] = vz;
#pragma unroll
  for (int s = 0; s < 12; ++s) {
    if (s < 11) {
#pragma unroll
      for (int i = 0; i < 4; ++i) {
        int q = wv * 4 + i;
        gload_lds16(W1stg + (size_t)(s + 1) * 8192 + q * 512 + lane * 8,
                    &Wb[(s + 1) & 1][q * 512]);
      }
    } else {
#pragma unroll
      for (int i = 0; i < 2; ++i) {
        int q = wv * 2 + i;
        gload_lds16(W2stg + (size_t)q * 512 + lane * 8, &Wb[0][q * 512]);
      }
    }
#pragma unroll
    for (int t = 0; t < 16; ++t) {
      s8v b = *(const s8v*)(&Wb[s & 1][kg * 2048 + (t * 16 + l15) * 8]);
      acc1[t] = mfma16(af1[s], b, acc1[t]);
    }
    __syncthreads();
  }
#pragma unroll
  for (int t = 0; t < 16; ++t) {
    int c = t * 16 + l15;
    float bb = b1[c];
#pragma unroll
    for (int j = 0; j < 4; ++j) {
      int r = wv * 16 + kg * 4 + j;
      ABUF[r * 256 + (((c >> 3) ^ (r & 7)) * 8) + (c & 7)] =
          f2bf(fmaxf(acc1[t][j] + bb, 0.f));
    }
  }
  __syncthreads();
  s8v af2[8];
#pragma unroll
  for (int k = 0; k < 8; ++k)
    af2[k] = *(const s8v*)(ABUF + rr * 256 + (((k * 4 + kg) ^ (l15 & 7)) * 8));
  f4v acc2[8];
#pragma unroll
  for (int t = 0; t < 8; ++t) acc2[t] = vz;
#pragma unroll
  for (int s = 0; s < 8; ++s) {
    if (s < 7) {
#pragma unroll
      for (int i = 0; i < 2; ++i) {
        int q = wv * 2 + i;
        gload_lds16(W2stg + (size_t)(s + 1) * 4096 + q * 512 + lane * 8,
                    &Wb[(s + 1) & 1][q * 512]);
      }
    }
#pragma unroll
    for (int t = 0; t < 8; ++t) {
      s8v b = *(const s8v*)(&Wb[s & 1][kg * 1024 + (t * 16 + l15) * 8]);
      acc2[t] = mfma16(af2[s], b, acc2[t]);
    }
    __syncthreads();
  }
  int n1r[4]; float tscr[4];
#pragma unroll
  for (int j = 0; j < 4; ++j) {
    int r = wv * 16 + kg * 4 + j;
    int n1 = n1idx[base + r];
    n1r[j] = n1; tscr[j] = rcpv[n1];
  }
#pragma unroll
  for (int t = 0; t < 8; ++t) {
    int c = t * 16 + l15;
    float bb = b2[c];
#pragma unroll
    for (int j = 0; j < 4; ++j) {
      float v = fmaxf(acc2[t][j] + bb, 0.f) * tscr[j];
      atomicAdd(Sacc + (size_t)n1r[j] * 128 + c, v);
    }
  }
}

// =====================================================================
// Aggr MLP (proven v4)
// =====================================================================
__global__ __launch_bounds__(256, 2) void aggr_kernel(
    float* __restrict__ hid,
    const float* __restrict__ Sp, const float* __restrict__ Sc,
    const float* __restrict__ pm, const float* __restrict__ cm,
    const float* __restrict__ st, const float* __restrict__ et,
    const unsigned short* __restrict__ W1stg, const float* __restrict__ b1,
    const unsigned short* __restrict__ W2stg, const float* __restrict__ b2)
{
  __shared__ __align__(16) unsigned short ABUF[64 * 384];
  __shared__ __align__(16) unsigned short Wb[2][8192];
  const int tid = threadIdx.x, lane = tid & 63, wv = tid >> 6;
  const int l15 = lane & 15, kg = lane >> 4;
  const int base = blockIdx.x * 64;
#pragma unroll
  for (int i = 0; i < 4; ++i) {
    int q = wv * 4 + i;
    gload_lds16(W1stg + (size_t)q * 512 + lane * 8, &Wb[0][q * 512]);
  }
#pragma unroll
  for (int it = 0; it < 24; ++it) {
    int i = tid + it * 256;
    int r = i / 96, q = i - r * 96;
    int seg = q >> 5, c4 = q & 31;
    int n = base + r;
    float4 v = {0.f, 0.f, 0.f, 0.f};
    if (n < N_NODES) {
      if (seg == 0) {
        v = *(const float4*)(hid + (size_t)n * 128 + c4 * 4);
      } else if (seg == 1) {
        v = *(const float4*)(Sp + (size_t)n * 128 + c4 * 4);
        float m = pm[n]; const float4 t = *(const float4*)(st + c4 * 4);
        v.x = fmaf(m, t.x, v.x); v.y = fmaf(m, t.y, v.y);
        v.z = fmaf(m, t.z, v.z); v.w = fmaf(m, t.w, v.w);
      } else {
        v = *(const float4*)(Sc + (size_t)n * 128 + c4 * 4);
        float m = cm[n]; const float4 t = *(const float4*)(et + c4 * 4);
        v.x = fmaf(m, t.x, v.x); v.y = fmaf(m, t.y, v.y);
        v.z = fmaf(m, t.z, v.z); v.w = fmaf(m, t.w, v.w);
      }
    }
    int unit = seg * 16 + (c4 >> 1);
    *(ushort4*)(ABUF + r * 384 + ((unit ^ (r & 7)) * 8) + (c4 & 1) * 4) = f2bf4(v);
  }
  __syncthreads();
  const int rr = wv * 16 + l15;
  s8v af1[12];
#pragma unroll
  for (int k = 0; k < 12; ++k)
    af1[k] = *(const s8v*)(ABUF + rr * 384 + (((k * 4 + kg) ^ (rr & 7)) * 8));
  const f4v vz = {0.f, 0.f, 0.f, 0.f};
  f4v acc1[16];
#pragma unroll
  for (int t = 0; t < 16; ++t) acc1[t] = vz;
#pragma unroll
  for (int s = 0; s < 12; ++s) {
    if (s < 11) {
#pragma unroll
      for (int i = 0; i < 4; ++i) {
        int q = wv * 4 + i;
        gload_lds16(W1stg + (size_t)(s + 1) * 8192 + q * 512 + lane * 8,
                    &Wb[(s + 1) & 1][q * 512]);
      }
    } else {
#pragma unroll
      for (int i = 0; i < 2; ++i) {
        int q = wv * 2 + i;
        gload_lds16(W2stg + (size_t)q * 512 + lane * 8, &Wb[0][q * 512]);
      }
    }
#pragma unroll
    for (int t = 0; t < 16; ++t) {
      s8v b = *(const s8v*)(&Wb[s & 1][kg * 2048 + (t * 16 + l15) * 8]);
      acc1[t] = mfma16(af1[s], b, acc1[t]);
    }
    __syncthreads();
  }
#pragma unroll
  for (int t = 0; t < 16; ++t) {
    int c = t * 16 + l15;
    float bb = b1[c];
#pragma unroll
    for (int j = 0; j < 4; ++j) {
      int r = wv * 16 + kg * 4 + j;
      ABUF[r * 256 + (((c >> 3) ^ (r & 7)) * 8) + (c & 7)] =
          f2bf(fmaxf(acc1[t][j] + bb, 0.f));
    }
  }
  __syncthreads();
  s8v af2[8];
#pragma unroll
  for (int k = 0; k < 8; ++k)
    af2[k] = *(const s8v*)(ABUF + rr * 256 + (((k * 4 + kg) ^ (l15 & 7)) * 8));
  f4v acc2[8];
#pragma unroll
  for (int t = 0; t < 8; ++t) acc2[t] = vz;
#pragma unroll
  for (int s = 0; s < 8; ++s) {
    if (s < 7) {
#pragma unroll
      for (int i = 0; i < 2; ++i) {
        int q = wv * 2 + i;
        gload_lds16(W2stg + (size_t)(s + 1) * 4096 + q * 512 + lane * 8,
                    &Wb[(s + 1) & 1][q * 512]);
      }
    }
#pragma unroll
    for (int t = 0; t < 8; ++t) {
      s8v b = *(const s8v*)(&Wb[s & 1][kg * 1024 + (t * 16 + l15) * 8]);
      acc2[t] = mfma16(af2[s], b, acc2[t]);
    }
    __syncthreads();
  }
#pragma unroll
  for (int t = 0; t < 8; ++t) {
    int c = t * 16 + l15;
    float bb = b2[c];
#pragma unroll
    for (int j = 0; j < 4; ++j) {
      int ro = base + wv * 16 + kg * 4 + j;
      if (ro < N_NODES) hid[(size_t)ro * 128 + c] += fmaxf(acc2[t][j] + bb, 0.f);
    }
  }
}

// =====================================================================
// edge-scalar MLP with resident W2 (64KB LDS), grid-strided
// =====================================================================
__global__ __launch_bounds__(256) void edge_feat_kernel(
    const float* __restrict__ ind, const float* __restrict__ W1,
    const float* __restrict__ b1,
    const unsigned short* __restrict__ W2sw,  // [128][256] swizzled
    const float* __restrict__ b2, unsigned short* __restrict__ feat)
{
  __shared__ __align__(16) unsigned short B[128 * 256];  // 64KB
  __shared__ unsigned short H1[64 * 264];
  __shared__ float xs[64];
  const int tid = threadIdx.x, lane = tid & 63, wv = tid >> 6;
  const int l15 = lane & 15, kg = lane >> 4;
#pragma unroll
  for (int it = 0; it < 16; ++it) {
    int q = it * 4 + wv;
    gload_lds16(W2sw + (size_t)q * 512 + lane * 8, &B[q * 512]);
  }
  const float w = W1[tid], bb1 = b1[tid];
  const f4v vz = {0.f, 0.f, 0.f, 0.f};
  for (int tile = blockIdx.x; tile < N_EDGES / 64; tile += gridDim.x) {
    const int base = tile * 64;
    if (tid < 64) xs[tid] = ind[base + tid];
    __syncthreads();
    for (int r = 0; r < 64; ++r)
      H1[r * 264 + tid] = f2bf(fmaxf(fmaf(xs[r], w, bb1), 0.f));
    __syncthreads();
    const unsigned short* Hrow = H1 + (size_t)(wv * 16 + l15) * 264;
    s8v af2[8];
#pragma unroll
    for (int k = 0; k < 8; ++k) af2[k] = *(const s8v*)(Hrow + k * 32 + kg * 8);
    f4v acc2[8];
#pragma unroll
    for (int t = 0; t < 8; ++t) acc2[t] = vz;
#pragma unroll
    for (int k = 0; k < 8; ++k) {
#pragma unroll
      for (int t = 0; t < 8; ++t) {
        int j = t * 16 + l15;
        s8v b = *(const s8v*)(&B[j * 256 + (((k * 4 + kg) ^ (j & 7)) * 8)]);
        acc2[t] = mfma16(af2[k], b, acc2[t]);
      }
    }
#pragma unroll
    for (int t = 0; t < 8; ++t) {
      int c = t * 16 + l15;
      float b2c = b2[c];
#pragma unroll
      for (int j = 0; j < 4; ++j) {
        int e = base + wv * 16 + kg * 4 + j;
        feat[(size_t)e * 128 + c] = f2bf(fmaxf(acc2[t][j] + b2c, 0.f));
      }
    }
    __syncthreads();
  }
}

// =====================================================================
// one-time v MLP (proven)
// =====================================================================
template <int KST1>
static __device__ __forceinline__ void mlp_core(
    unsigned short* __restrict__ BUF,
    const unsigned short* __restrict__ W1t, const float* __restrict__ b1,
    const unsigned short* __restrict__ W2t,
    int l15, int kg, int wr0, f4v* __restrict__ acc2)
{
  const int ldA = KST1 * 32 + 8;
  const f4v vzero = {0.f, 0.f, 0.f, 0.f};
  const unsigned short* Arow = BUF + (size_t)(wr0 + l15) * ldA;
  s8v af1[KST1];
#pragma unroll
  for (int k = 0; k < KST1; ++k) af1[k] = *(const s8v*)(Arow + k * 32 + kg * 8);
  __syncthreads();
  f4v acc1[16];
#pragma unroll
  for (int t = 0; t < 16; ++t) acc1[t] = vzero;
#pragma unroll
  for (int k = 0; k < KST1; ++k) {
#pragma unroll
    for (int t = 0; t < 16; ++t) {
      s8v b = *(const s8v*)(W1t + (size_t)(t * 16 + l15) * (KST1 * 32) + k * 32 + kg * 8);
      acc1[t] = mfma16(af1[k], b, acc1[t]);
    }
  }
#pragma unroll
  for (int t = 0; t < 16; ++t) {
    int c = t * 16 + l15;
    float bb = b1[c];
#pragma unroll
    for (int j = 0; j < 4; ++j) {
      BUF[(size_t)(wr0 + kg * 4 + j) * 264 + c] = f2bf(fmaxf(acc1[t][j] + bb, 0.f));
    }
  }
  const unsigned short* Hrow = BUF + (size_t)(wr0 + l15) * 264;
  s8v af2[8];
#pragma unroll
  for (int k = 0; k < 8; ++k) af2[k] = *(const s8v*)(Hrow + k * 32 + kg * 8);
#pragma unroll
  for (int t = 0; t < 8; ++t) acc2[t] = vzero;
#pragma unroll
  for (int k = 0; k < 8; ++k) {
#pragma unroll
    for (int t = 0; t < 8; ++t) {
      s8v b = *(const s8v*)(W2t + (size_t)(t * 16 + l15) * 256 + k * 32 + kg * 8);
      acc2[t] = mfma16(af2[k], b, acc2[t]);
    }
  }
}

__global__ __launch_bounds__(256, 2) void v_mlp_kernel(
    const float* __restrict__ x,
    const unsigned short* __restrict__ W1t, const float* __restrict__ b1,
    const unsigned short* __restrict__ W2t, const float* __restrict__ b2,
    float* __restrict__ hid)
{
  __shared__ unsigned short BUF[64 * 264];
  const int tid = threadIdx.x;
  const int base = blockIdx.x * 64;
#pragma unroll
  for (int it = 0; it < 8; ++it) {
    int i = tid + it * 256;
    int r = i >> 5, c4 = i & 31, n = base + r;
    float4 v = {0.f, 0.f, 0.f, 0.f};
    if (n < N_NODES) v = *(const float4*)(x + (size_t)n * 128 + c4 * 4);
    *(ushort4*)(BUF + r * 136 + c4 * 4) = f2bf4(v);
  }
  __syncthreads();
  const int lane = tid & 63, wv = tid >> 6;
  const int l15 = lane & 15, kg = lane >> 4, wr0 = wv * 16;
  f4v acc2[8];
  mlp_core<4>(BUF, W1t, b1, W2t, l15, kg, wr0, acc2);
#pragma unroll
  for (int t = 0; t < 8; ++t) {
    int c = t * 16 + l15;
    float bb = b2[c];
#pragma unroll
    for (int j = 0; j < 4; ++j) {
      int n = base + wr0 + kg * 4 + j;
      if (n < N_NODES) hid[(size_t)n * 128 + c] = fmaxf(acc2[t][j] + bb, 0.f);
    }
  }
}

// ---------------- prep kernels ----------------
__global__ void transpose_w(const float* __restrict__ W, unsigned short* __restrict__ Wt,
                            int K, int NH) {
  int i = blockIdx.x * 256 + threadIdx.x;
  if (i < K * NH) {
    int k = i / NH, n = i - k * NH;
    Wt[(size_t)n * K + k] = f2bf(W[i]);
  }
}

// W [384][256] f32 -> stg [12][4][256][8] bf16
__global__ void build_w1stg(const float* __restrict__ W, unsigned short* __restrict__ stg) {
  int i = blockIdx.x * 256 + threadIdx.x;
  if (i < 384 * 256) {
    int k = i >> 8, out = i & 255;
    int s = k >> 5, kc = (k >> 3) & 3, j = k & 7;
    stg[(size_t)s * 8192 + kc * 2048 + out * 8 + j] = f2bf(W[i]);
  }
}

// W1 rows 256..383 -> stg [4][4][256][8] bf16
__global__ void build_w1cstg(const float* __restrict__ W, unsigned short* __restrict__ stg) {
  int i = blockIdx.x * 256 + threadIdx.x;
  if (i < 128 * 256) {
    int k = i >> 8, out = i & 255;
    int s = k >> 5, kc = (k >> 3) & 3, j = k & 7;
    stg[(size_t)s * 8192 + kc * 2048 + out * 8 + j] = f2bf(W[(size_t)(256 + k) * 256 + out]);
  }
}

// W [256][128] f32 -> stg [8][4][128][8] bf16
__global__ void build_w2stg(const float* __restrict__ W, unsigned short* __restrict__ stg) {
  int i = blockIdx.x * 256 + threadIdx.x;
  if (i < 256 * 128) {
    int k = i >> 7, out = i & 127;
    int s = k >> 5, kc = (k >> 3) & 3, j = k & 7;
    stg[(size_t)s * 4096 + kc * 1024 + out * 8 + j] = f2bf(W[i]);
  }
}

// dst[256][128] bf16 XOR-swizzled; dst[j][e] = W[(k_off+e)*256 + j]
__global__ void build_w128_sw(const float* __restrict__ W, int k_off,
                              unsigned short* __restrict__ dst) {
  int i = blockIdx.x * 256 + threadIdx.x;
  if (i < 256 * 128) {
    int j = i >> 7, e = i & 127;
    int unit = (e >> 3) ^ (j & 7);
    dst[(size_t)j * 128 + unit * 8 + (e & 7)] = f2bf(W[(size_t)(k_off + e) * 256 + j]);
  }
}

// dst[128][256] bf16 swizzled; dst[j][k] = W[k*128 + j]
__global__ void build_w2sw(const float* __restrict__ W, unsigned short* __restrict__ dst) {
  int i = blockIdx.x * 256 + threadIdx.x;
  if (i < 128 * 256) {
    int j = i >> 8, k = i & 255;
    dst[(size_t)j * 256 + (((k >> 3) ^ (j & 7)) * 8) + (k & 7)] =
        f2bf(W[(size_t)k * 128 + j]);
  }
}

__global__ void count_kernel(const int* __restrict__ pn, const int* __restrict__ cn,
                             float* __restrict__ cp, float* __restrict__ cc) {
  int i = blockIdx.x * 256 + threadIdx.x;
  if (i < N_EDGES) {
    atomicAdd(cp + pn[i], 1.f);
    atomicAdd(cc + cn[i], 1.f);
  }
}

__global__ void rcp_kernel(float* __restrict__ cp, float* __restrict__ cc) {
  int i = blockIdx.x * 256 + threadIdx.x;
  if (i < N_NODES) {
    cp[i] = 1.f / fmaxf(cp[i], 1.f);
    cc[i] = 1.f / fmaxf(cc[i], 1.f);
  }
}

extern "C" void kernel_launch(void* const* d_in, const int* in_sizes, int n_in,
                              void* d_out, int out_size, void* d_ws, size_t ws_size,
                              hipStream_t stream) {
  const float* batch_token = (const float*)d_in[0];
  const int*   pn          = (const int*)d_in[1];
  const int*   cn          = (const int*)d_in[2];
  const float* indP        = (const float*)d_in[3];
  const float* indC        = (const float*)d_in[4];
  const float* p_mask      = (const float*)d_in[5];
  const float* c_mask      = (const float*)d_in[6];
  const float* stok        = (const float*)d_in[7];
  const float* etok        = (const float*)d_in[8];
  const float* vW1 = (const float*)d_in[9],  *vb1 = (const float*)d_in[10];
  const float* vW2 = (const float*)d_in[11], *vb2 = (const float*)d_in[12];
  const float* eW1 = (const float*)d_in[13], *eb1 = (const float*)d_in[14];
  const float* eW2 = (const float*)d_in[15], *eb2 = (const float*)d_in[16];
  const float* pW1 = (const float*)d_in[17], *pb1 = (const float*)d_in[18];
  const float* pW2 = (const float*)d_in[19], *pb2 = (const float*)d_in[20];
  const float* cW1 = (const float*)d_in[21], *cb1 = (const float*)d_in[22];
  const float* cW2 = (const float*)d_in[23], *cb2 = (const float*)d_in[24];
  const float* aW1 = (const float*)d_in[25], *ab1 = (const float*)d_in[26];
  const float* aW2 = (const float*)d_in[27], *ab2 = (const float*)d_in[28];

  char* w0 = (char*)d_ws;
  char* w = w0;
  auto alloc = [&](size_t bytes) -> char* {
    char* p = w;
    w += (bytes + 255) & ~(size_t)255;
    return p;
  };
  // ---- common region (matches v4's proven <258MB footprint) ----
  float* Sp    = (float*)alloc((size_t)N_NODES * 128 * 4);
  float* Sc    = (float*)alloc((size_t)N_NODES * 128 * 4);
  float* rcp_p = (float*)alloc((size_t)N_NODES * 4);
  float* rcp_c = (float*)alloc((size_t)N_NODES * 4);
  unsigned short* featP = (unsigned short*)alloc((size_t)N_EDGES * 128 * 2);
  unsigned short* featC = (unsigned short*)alloc((size_t)N_EDGES * 128 * 2);
  unsigned short* W1stg_p = (unsigned short*)alloc(12 * 8192 * 2);
  unsigned short* W1stg_c = (unsigned short*)alloc(12 * 8192 * 2);
  unsigned short* W1stg_a = (unsigned short*)alloc(12 * 8192 * 2);
  unsigned short* W2stg_p = (unsigned short*)alloc(8 * 4096 * 2);
  unsigned short* W2stg_c = (unsigned short*)alloc(8 * 4096 * 2);
  unsigned short* W2stg_a = (unsigned short*)alloc(8 * 4096 * 2);
  unsigned short* W1t_v   = (unsigned short*)alloc(256 * 128 * 2);
  unsigned short* W2t_v   = (unsigned short*)alloc(128 * 256 * 2);
  unsigned short* W2sw_e  = (unsigned short*)alloc(128 * 256 * 2);
  // ---- big-only region (Z restructure) ----
  unsigned short* Zall      = (unsigned short*)alloc((size_t)N_NODES * 512 * 2);
  unsigned short* Wbig_p    = (unsigned short*)alloc((size_t)2 * 256 * 128 * 2);
  unsigned short* Wbig_c    = (unsigned short*)alloc((size_t)2 * 256 * 128 * 2);
  unsigned short* W1cstg_p  = (unsigned short*)alloc(4 * 8192 * 2);
  unsigned short* W1cstg_c  = (unsigned short*)alloc(4 * 8192 * 2);
  const bool big = (size_t)(w - w0) <= ws_size;

  float* hidden = (float*)d_out;

  const int EB = N_EDGES / 64;          // 6250
  const int NB = (N_NODES + 63) / 64;   // 782

  // counts -> reciprocals
  hipMemsetAsync(rcp_p, 0, (size_t)N_NODES * 4, stream);
  hipMemsetAsync(rcp_c, 0, (size_t)N_NODES * 4, stream);
  count_kernel<<<(N_EDGES + 255) / 256, 256, 0, stream>>>(pn, cn, rcp_p, rcp_c);
  rcp_kernel<<<(N_NODES + 255) / 256, 256, 0, stream>>>(rcp_p, rcp_c);

  // weight prep (common)
  transpose_w<<<(128 * 256 + 255) / 256, 256, 0, stream>>>(vW1, W1t_v, 128, 256);
  transpose_w<<<(256 * 128 + 255) / 256, 256, 0, stream>>>(vW2, W2t_v, 256, 128);
  build_w2sw<<<(128 * 256 + 255) / 256, 256, 0, stream>>>(eW2, W2sw_e);
  build_w1stg<<<(384 * 256 + 255) / 256, 256, 0, stream>>>(aW1, W1stg_a);
  build_w2stg<<<(256 * 128 + 255) / 256, 256, 0, stream>>>(pW2, W2stg_p);
  build_w2stg<<<(256 * 128 + 255) / 256, 256, 0, stream>>>(cW2, W2stg_c);
  build_w2stg<<<(256 * 128 + 255) / 256, 256, 0, stream>>>(aW2, W2stg_a);
  if (big) {
    const int SWB = (256 * 128 + 255) / 256;
    build_w128_sw<<<SWB, 256, 0, stream>>>(pW1, 0,   Wbig_p + 0 * 256 * 128);
    build_w128_sw<<<SWB, 256, 0, stream>>>(pW1, 128, Wbig_p + 1 * 256 * 128);
    build_w128_sw<<<SWB, 256, 0, stream>>>(cW1, 0,   Wbig_c + 0 * 256 * 128);
    build_w128_sw<<<SWB, 256, 0, stream>>>(cW1, 128, Wbig_c + 1 * 256 * 128);
    build_w1cstg<<<(128 * 256 + 255) / 256, 256, 0, stream>>>(pW1, W1cstg_p);
    build_w1cstg<<<(128 * 256 + 255) / 256, 256, 0, stream>>>(cW1, W1cstg_c);
  } else {
    build_w1stg<<<(384 * 256 + 255) / 256, 256, 0, stream>>>(pW1, W1stg_p);
    build_w1stg<<<(384 * 256 + 255) / 256, 256, 0, stream>>>(cW1, W1stg_c);
  }

  // one-time: edge features + initial hidden
  edge_feat_kernel<<<256, 256, 0, stream>>>(indP, eW1, eb1, W2sw_e, eb2, featP);
  edge_feat_kernel<<<256, 256, 0, stream>>>(indC, eW1, eb1, W2sw_e, eb2, featC);
  v_mlp_kernel<<<NB, 256, 0, stream>>>(batch_token, W1t_v, vb1, W2t_v, vb2, hidden);

  for (int hop = 0; hop < 3; ++hop) {
    hipMemsetAsync(Sp, 0, (size_t)N_NODES * 128 * 4, stream);
    hipMemsetAsync(Sc, 0, (size_t)N_NODES * 128 * 4, stream);
    if (big) {
      // p-dir: A=[hc|hp|ep]; Z g0 = hid@pW1[0:128] (hc), g1 = hid@pW1[128:256] (hp)
      z_gemm_kernel<<<dim3(256, 2), 256, 0, stream>>>(hidden, Wbig_p, Zall);
      edge_msg2_kernel<<<EB, 256, 0, stream>>>(Zall, featP, cn, pn,
                                               W1cstg_p, pb1, W2stg_p, pb2, Sp, rcp_p);
      // c-dir: A=[hp|hc|ec]
      z_gemm_kernel<<<dim3(256, 2), 256, 0, stream>>>(hidden, Wbig_c, Zall);
      edge_msg2_kernel<<<EB, 256, 0, stream>>>(Zall, featC, pn, cn,
                                               W1cstg_c, cb1, W2stg_c, cb2, Sc, rcp_c);
    } else {
      edge_mlp_kernel<<<EB, 256, 0, stream>>>(hidden, cn, pn, featP,
                                              W1stg_p, pb1, W2stg_p, pb2, Sp, rcp_p);
      edge_mlp_kernel<<<EB, 256, 0, stream>>>(hidden, pn, cn, featC,
                                              W1stg_c, cb1, W2stg_c, cb2, Sc, rcp_c);
    }
    aggr_kernel<<<NB, 256, 0, stream>>>(hidden, Sp, Sc, p_mask, c_mask,
                                        stok, etok, W1stg_a, ab1, W2stg_a, ab2);
  }
  (void)in_sizes; (void)n_in; (void)out_size;
}

// Round 6
// 1996.565 us; speedup vs baseline: 3.2349x; 1.4643x over previous
//
#include <hip/hip_runtime.h>
#include <stdint.h>

#define N_NODES 50000
#define N_EDGES 400000
#define M_TAB 4096          // lerp intervals; samples 0..4096, alloc 4160 rows

typedef short s8v __attribute__((ext_vector_type(8)));
typedef float f4v __attribute__((ext_vector_type(4)));

static __device__ __forceinline__ unsigned short f2bf(float f) {
  union { float f; uint32_t u; } v; v.f = f;
  return (unsigned short)((v.u + 0x7FFFu + ((v.u >> 16) & 1u)) >> 16);
}
static __device__ __forceinline__ ushort4 f2bf4(float4 v) {
  ushort4 o; o.x = f2bf(v.x); o.y = f2bf(v.y); o.z = f2bf(v.z); o.w = f2bf(v.w);
  return o;
}
static __device__ __forceinline__ void bf2(uint32_t u, float& a, float& b) {
  union { uint32_t x; float f; } lo, hi;
  lo.x = u << 16; hi.x = u & 0xffff0000u;
  a = lo.f; b = hi.f;
}
static __device__ __forceinline__ f4v mfma16(s8v a, s8v b, f4v c) {
  return __builtin_amdgcn_mfma_f32_16x16x32_bf16(a, b, c, 0, 0, 0);
}
// async global->LDS, 16B/lane; LDS dest = wave-uniform base + lane*16
static __device__ __forceinline__ void gload_lds16(const void* g, void* l) {
  __builtin_amdgcn_global_load_lds(
      (const __attribute__((address_space(1))) uint32_t*)g,
      (__attribute__((address_space(3))) uint32_t*)l, 16, 0, 0);
}

// =====================================================================
// Z-GEMM: Z[n][g*256+c] = sum_k bf16(hid[n][k]) * Wg[k][c]   (bf16 out)
// B group (64KB, XOR-swizzled, prebuilt) resident in LDS. Z stride 512.
// =====================================================================
__global__ __launch_bounds__(256) void z_gemm_kernel(
    const float* __restrict__ hid, const unsigned short* __restrict__ Wsw,
    unsigned short* __restrict__ Z)
{
  __shared__ __align__(16) unsigned short B[256 * 128];
  const int tid = threadIdx.x, lane = tid & 63, wv = tid >> 6;
  const int g = blockIdx.y;
  const unsigned short* src = Wsw + (size_t)g * 256 * 128;
#pragma unroll
  for (int it = 0; it < 16; ++it) {
    int q = it * 4 + wv;
    gload_lds16(src + (size_t)q * 512 + lane * 8, &B[q * 512]);
  }
  __syncthreads();
  const int l15 = lane & 15, kg = lane >> 4;
  const f4v vz = {0.f, 0.f, 0.f, 0.f};
  for (int c0 = blockIdx.x; c0 < (N_NODES + 63) / 64; c0 += gridDim.x) {
    const int base = c0 * 64;
    const int row = base + wv * 16 + l15;
    s8v af[4];
#pragma unroll
    for (int k = 0; k < 4; ++k) {
      float4 u0 = {0.f,0.f,0.f,0.f}, u1 = {0.f,0.f,0.f,0.f};
      if (row < N_NODES) {
        u0 = *(const float4*)(hid + (size_t)row * 128 + k * 32 + kg * 8);
        u1 = *(const float4*)(hid + (size_t)row * 128 + k * 32 + kg * 8 + 4);
      }
      s8v a;
      a[0] = (short)f2bf(u0.x); a[1] = (short)f2bf(u0.y);
      a[2] = (short)f2bf(u0.z); a[3] = (short)f2bf(u0.w);
      a[4] = (short)f2bf(u1.x); a[5] = (short)f2bf(u1.y);
      a[6] = (short)f2bf(u1.z); a[7] = (short)f2bf(u1.w);
      af[k] = a;
    }
    f4v acc[16];
#pragma unroll
    for (int t = 0; t < 16; ++t) acc[t] = vz;
#pragma unroll
    for (int k = 0; k < 4; ++k) {
#pragma unroll
      for (int t = 0; t < 16; ++t) {
        int j = t * 16 + l15;
        s8v b = *(const s8v*)(&B[j * 128 + (((k * 4 + kg) ^ (j & 7)) * 8)]);
        acc[t] = mfma16(af[k], b, acc[t]);
      }
    }
#pragma unroll
    for (int t = 0; t < 16; ++t) {
      int c = t * 16 + l15;
#pragma unroll
      for (int j = 0; j < 4; ++j) {
        int ro = base + wv * 16 + kg * 4 + j;
        if (ro < N_NODES) Z[(size_t)ro * 512 + g * 256 + c] = f2bf(acc[t][j]);
      }
    }
  }
}

// =====================================================================
// Table GEMM: T[s][c] = feat_samp[s] @ W1c + b1   (bf16 out, 65 tiles)
// =====================================================================
__global__ __launch_bounds__(256) void tab_gemm_kernel(
    const unsigned short* __restrict__ feat,  // [4160][128]
    const unsigned short* __restrict__ Wsw,   // [256 out][128 k] swizzled
    const float* __restrict__ b1, unsigned short* __restrict__ T)
{
  __shared__ __align__(16) unsigned short B[256 * 128];
  const int tid = threadIdx.x, lane = tid & 63, wv = tid >> 6;
#pragma unroll
  for (int it = 0; it < 16; ++it) {
    int q = it * 4 + wv;
    gload_lds16(Wsw + (size_t)q * 512 + lane * 8, &B[q * 512]);
  }
  __syncthreads();
  const int l15 = lane & 15, kg = lane >> 4;
  const int base = blockIdx.x * 64;
  const int row = base + wv * 16 + l15;
  s8v af[4];
#pragma unroll
  for (int k = 0; k < 4; ++k)
    af[k] = *(const s8v*)(feat + (size_t)row * 128 + k * 32 + kg * 8);
  const f4v vz = {0.f, 0.f, 0.f, 0.f};
  f4v acc[16];
#pragma unroll
  for (int t = 0; t < 16; ++t) acc[t] = vz;
#pragma unroll
  for (int k = 0; k < 4; ++k) {
#pragma unroll
    for (int t = 0; t < 16; ++t) {
      int j = t * 16 + l15;
      s8v b = *(const s8v*)(&B[j * 128 + (((k * 4 + kg) ^ (j & 7)) * 8)]);
      acc[t] = mfma16(af[k], b, acc[t]);
    }
  }
#pragma unroll
  for (int t = 0; t < 16; ++t) {
    int c = t * 16 + l15;
    float bb = b1[c];
#pragma unroll
    for (int j = 0; j < 4; ++j) {
      int ro = base + wv * 16 + kg * 4 + j;
      T[(size_t)ro * 256 + c] = f2bf(acc[t][j] + bb);
    }
  }
}

// =====================================================================
// Edge message (table-based):
//   H1 = relu(Z[n0][0:256] + Z[n1][256:512] + lerp(T, x_e))
//   out = relu(H1 @ W2 + b2) * rcp[n1] -> atomicAdd Sacc[n1]
// =====================================================================
__global__ __launch_bounds__(256) void edge_msg3_kernel(
    const unsigned short* __restrict__ Z,   // [N][512]
    const float* __restrict__ ind,          // [E] scalars
    const int* __restrict__ n0idx, const int* __restrict__ n1idx,
    const unsigned short* __restrict__ T,   // [4097][256] lerp table (b1 baked)
    const unsigned short* __restrict__ W2stg, const float* __restrict__ b2,
    float* __restrict__ Sacc, const float* __restrict__ rcpv)
{
  __shared__ __align__(16) unsigned short H1[64 * 256];  // 32KB swizzled
  __shared__ __align__(16) unsigned short Wb[2][4096];   // 16KB
  __shared__ int n0s[64], n1s[64], tix[64];
  __shared__ float tfr[64];
  const int tid = threadIdx.x, lane = tid & 63, wv = tid >> 6;
  const int l15 = lane & 15, kg = lane >> 4;
  const int base = blockIdx.x * 64;  // E % 64 == 0
  if (tid < 64) {
    n0s[tid] = n0idx[base + tid];
    n1s[tid] = n1idx[base + tid];
    float x = ind[base + tid];
    float xs = x * (float)M_TAB;
    int idx = (int)xs;
    idx = idx < 0 ? 0 : (idx > M_TAB - 1 ? M_TAB - 1 : idx);
    tix[tid] = idx;
    tfr[tid] = xs - (float)idx;
  }
  // stage W2 slice 0
#pragma unroll
  for (int i = 0; i < 2; ++i) {
    int q = wv * 2 + i;
    gload_lds16(W2stg + (size_t)q * 512 + lane * 8, &Wb[0][q * 512]);
  }
  __syncthreads();
  // build H1 = relu(Za + Zb + lerp) directly into LDS (swizzled 16B units)
#pragma unroll
  for (int it = 0; it < 8; ++it) {
    int i = tid + it * 256;
    int r = i >> 5, c8 = i & 31;
    const uint4 za = *(const uint4*)(Z + (size_t)n0s[r] * 512 + c8 * 8);
    const uint4 zb = *(const uint4*)(Z + (size_t)n1s[r] * 512 + 256 + c8 * 8);
    const uint4 t0 = *(const uint4*)(T + (size_t)tix[r] * 256 + c8 * 8);
    const uint4 t1 = *(const uint4*)(T + (size_t)(tix[r] + 1) * 256 + c8 * 8);
    const float f = tfr[r];
    uint32_t ua[4] = {za.x, za.y, za.z, za.w};
    uint32_t ub[4] = {zb.x, zb.y, zb.z, zb.w};
    uint32_t u0[4] = {t0.x, t0.y, t0.z, t0.w};
    uint32_t u1[4] = {t1.x, t1.y, t1.z, t1.w};
    uint32_t uo[4];
#pragma unroll
    for (int q = 0; q < 4; ++q) {
      float a0, a1, b0, b1f, p0, p1, q0, q1;
      bf2(ua[q], a0, a1); bf2(ub[q], b0, b1f);
      bf2(u0[q], p0, p1); bf2(u1[q], q0, q1);
      float s0 = fmaxf(a0 + b0 + p0 + f * (q0 - p0), 0.f);
      float s1 = fmaxf(a1 + b1f + p1 + f * (q1 - p1), 0.f);
      uo[q] = (uint32_t)f2bf(s0) | ((uint32_t)f2bf(s1) << 16);
    }
    uint4 pk; pk.x = uo[0]; pk.y = uo[1]; pk.z = uo[2]; pk.w = uo[3];
    *(uint4*)(H1 + r * 256 + ((c8 ^ (r & 7)) * 8)) = pk;
  }
  __syncthreads();
  // layer 2: [64,256] @ W2 -> [64,128], 8 staged K-phases
  const int rr = wv * 16 + l15;
  s8v af2[8];
#pragma unroll
  for (int k = 0; k < 8; ++k)
    af2[k] = *(const s8v*)(H1 + rr * 256 + (((k * 4 + kg) ^ (l15 & 7)) * 8));
  const f4v vz = {0.f, 0.f, 0.f, 0.f};
  f4v acc2[8];
#pragma unroll
  for (int t = 0; t < 8; ++t) acc2[t] = vz;
#pragma unroll
  for (int s = 0; s < 8; ++s) {
    if (s < 7) {
#pragma unroll
      for (int i = 0; i < 2; ++i) {
        int q = wv * 2 + i;
        gload_lds16(W2stg + (size_t)(s + 1) * 4096 + q * 512 + lane * 8,
                    &Wb[(s + 1) & 1][q * 512]);
      }
    }
#pragma unroll
    for (int t = 0; t < 8; ++t) {
      s8v b = *(const s8v*)(&Wb[s & 1][kg * 1024 + (t * 16 + l15) * 8]);
      acc2[t] = mfma16(af2[s], b, acc2[t]);
    }
    __syncthreads();
  }
  // epilogue: scale by rcp[n1], atomic scatter
  int n1r[4]; float tscr[4];
#pragma unroll
  for (int j = 0; j < 4; ++j) {
    int r = wv * 16 + kg * 4 + j;
    int n1 = n1s[r];
    n1r[j] = n1; tscr[j] = rcpv[n1];
  }
#pragma unroll
  for (int t = 0; t < 8; ++t) {
    int c = t * 16 + l15;
    float bb = b2[c];
#pragma unroll
    for (int j = 0; j < 4; ++j) {
      float v = fmaxf(acc2[t][j] + bb, 0.f) * tscr[j];
      atomicAdd(Sacc + (size_t)n1r[j] * 128 + c, v);
    }
  }
}

// =====================================================================
// Aggr MLP (proven v4/v5)
// =====================================================================
__global__ __launch_bounds__(256, 2) void aggr_kernel(
    float* __restrict__ hid,
    const float* __restrict__ Sp, const float* __restrict__ Sc,
    const float* __restrict__ pm, const float* __restrict__ cm,
    const float* __restrict__ st, const float* __restrict__ et,
    const unsigned short* __restrict__ W1stg, const float* __restrict__ b1,
    const unsigned short* __restrict__ W2stg, const float* __restrict__ b2)
{
  __shared__ __align__(16) unsigned short ABUF[64 * 384];
  __shared__ __align__(16) unsigned short Wb[2][8192];
  const int tid = threadIdx.x, lane = tid & 63, wv = tid >> 6;
  const int l15 = lane & 15, kg = lane >> 4;
  const int base = blockIdx.x * 64;
#pragma unroll
  for (int i = 0; i < 4; ++i) {
    int q = wv * 4 + i;
    gload_lds16(W1stg + (size_t)q * 512 + lane * 8, &Wb[0][q * 512]);
  }
#pragma unroll
  for (int it = 0; it < 24; ++it) {
    int i = tid + it * 256;
    int r = i / 96, q = i - r * 96;
    int seg = q >> 5, c4 = q & 31;
    int n = base + r;
    float4 v = {0.f, 0.f, 0.f, 0.f};
    if (n < N_NODES) {
      if (seg == 0) {
        v = *(const float4*)(hid + (size_t)n * 128 + c4 * 4);
      } else if (seg == 1) {
        v = *(const float4*)(Sp + (size_t)n * 128 + c4 * 4);
        float m = pm[n]; const float4 t = *(const float4*)(st + c4 * 4);
        v.x = fmaf(m, t.x, v.x); v.y = fmaf(m, t.y, v.y);
        v.z = fmaf(m, t.z, v.z); v.w = fmaf(m, t.w, v.w);
      } else {
        v = *(const float4*)(Sc + (size_t)n * 128 + c4 * 4);
        float m = cm[n]; const float4 t = *(const float4*)(et + c4 * 4);
        v.x = fmaf(m, t.x, v.x); v.y = fmaf(m, t.y, v.y);
        v.z = fmaf(m, t.z, v.z); v.w = fmaf(m, t.w, v.w);
      }
    }
    int unit = seg * 16 + (c4 >> 1);
    *(ushort4*)(ABUF + r * 384 + ((unit ^ (r & 7)) * 8) + (c4 & 1) * 4) = f2bf4(v);
  }
  __syncthreads();
  const int rr = wv * 16 + l15;
  s8v af1[12];
#pragma unroll
  for (int k = 0; k < 12; ++k)
    af1[k] = *(const s8v*)(ABUF + rr * 384 + (((k * 4 + kg) ^ (rr & 7)) * 8));
  const f4v vz = {0.f, 0.f, 0.f, 0.f};
  f4v acc1[16];
#pragma unroll
  for (int t = 0; t < 16; ++t) acc1[t] = vz;
#pragma unroll
  for (int s = 0; s < 12; ++s) {
    if (s < 11) {
#pragma unroll
      for (int i = 0; i < 4; ++i) {
        int q = wv * 4 + i;
        gload_lds16(W1stg + (size_t)(s + 1) * 8192 + q * 512 + lane * 8,
                    &Wb[(s + 1) & 1][q * 512]);
      }
    } else {
#pragma unroll
      for (int i = 0; i < 2; ++i) {
        int q = wv * 2 + i;
        gload_lds16(W2stg + (size_t)q * 512 + lane * 8, &Wb[0][q * 512]);
      }
    }
#pragma unroll
    for (int t = 0; t < 16; ++t) {
      s8v b = *(const s8v*)(&Wb[s & 1][kg * 2048 + (t * 16 + l15) * 8]);
      acc1[t] = mfma16(af1[s], b, acc1[t]);
    }
    __syncthreads();
  }
#pragma unroll
  for (int t = 0; t < 16; ++t) {
    int c = t * 16 + l15;
    float bb = b1[c];
#pragma unroll
    for (int j = 0; j < 4; ++j) {
      int r = wv * 16 + kg * 4 + j;
      ABUF[r * 256 + (((c >> 3) ^ (r & 7)) * 8) + (c & 7)] =
          f2bf(fmaxf(acc1[t][j] + bb, 0.f));
    }
  }
  __syncthreads();
  s8v af2[8];
#pragma unroll
  for (int k = 0; k < 8; ++k)
    af2[k] = *(const s8v*)(ABUF + rr * 256 + (((k * 4 + kg) ^ (l15 & 7)) * 8));
  f4v acc2[8];
#pragma unroll
  for (int t = 0; t < 8; ++t) acc2[t] = vz;
#pragma unroll
  for (int s = 0; s < 8; ++s) {
    if (s < 7) {
#pragma unroll
      for (int i = 0; i < 2; ++i) {
        int q = wv * 2 + i;
        gload_lds16(W2stg + (size_t)(s + 1) * 4096 + q * 512 + lane * 8,
                    &Wb[(s + 1) & 1][q * 512]);
      }
    }
#pragma unroll
    for (int t = 0; t < 8; ++t) {
      s8v b = *(const s8v*)(&Wb[s & 1][kg * 1024 + (t * 16 + l15) * 8]);
      acc2[t] = mfma16(af2[s], b, acc2[t]);
    }
    __syncthreads();
  }
#pragma unroll
  for (int t = 0; t < 8; ++t) {
    int c = t * 16 + l15;
    float bb = b2[c];
#pragma unroll
    for (int j = 0; j < 4; ++j) {
      int ro = base + wv * 16 + kg * 4 + j;
      if (ro < N_NODES) hid[(size_t)ro * 128 + c] += fmaxf(acc2[t][j] + bb, 0.f);
    }
  }
}

// =====================================================================
// edge-scalar MLP with resident W2 (64KB LDS), grid-strided over ntiles
// =====================================================================
__global__ __launch_bounds__(256) void edge_feat_kernel(
    const float* __restrict__ ind, const float* __restrict__ W1,
    const float* __restrict__ b1,
    const unsigned short* __restrict__ W2sw,  // [128][256] swizzled
    const float* __restrict__ b2, unsigned short* __restrict__ feat,
    int ntiles)
{
  __shared__ __align__(16) unsigned short B[128 * 256];  // 64KB
  __shared__ unsigned short H1[64 * 264];
  __shared__ float xs[64];
  const int tid = threadIdx.x, lane = tid & 63, wv = tid >> 6;
  const int l15 = lane & 15, kg = lane >> 4;
#pragma unroll
  for (int it = 0; it < 16; ++it) {
    int q = it * 4 + wv;
    gload_lds16(W2sw + (size_t)q * 512 + lane * 8, &B[q * 512]);
  }
  const float w = W1[tid], bb1 = b1[tid];
  const f4v vz = {0.f, 0.f, 0.f, 0.f};
  for (int tile = blockIdx.x; tile < ntiles; tile += gridDim.x) {
    const int base = tile * 64;
    if (tid < 64) xs[tid] = ind[base + tid];
    __syncthreads();
    for (int r = 0; r < 64; ++r)
      H1[r * 264 + tid] = f2bf(fmaxf(fmaf(xs[r], w, bb1), 0.f));
    __syncthreads();
    const unsigned short* Hrow = H1 + (size_t)(wv * 16 + l15) * 264;
    s8v af2[8];
#pragma unroll
    for (int k = 0; k < 8; ++k) af2[k] = *(const s8v*)(Hrow + k * 32 + kg * 8);
    f4v acc2[8];
#pragma unroll
    for (int t = 0; t < 8; ++t) acc2[t] = vz;
#pragma unroll
    for (int k = 0; k < 8; ++k) {
#pragma unroll
      for (int t = 0; t < 8; ++t) {
        int j = t * 16 + l15;
        s8v b = *(const s8v*)(&B[j * 256 + (((k * 4 + kg) ^ (j & 7)) * 8)]);
        acc2[t] = mfma16(af2[k], b, acc2[t]);
      }
    }
#pragma unroll
    for (int t = 0; t < 8; ++t) {
      int c = t * 16 + l15;
      float b2c = b2[c];
#pragma unroll
      for (int j = 0; j < 4; ++j) {
        int e = base + wv * 16 + kg * 4 + j;
        feat[(size_t)e * 128 + c] = f2bf(fmaxf(acc2[t][j] + b2c, 0.f));
      }
    }
    __syncthreads();
  }
}

// =====================================================================
// one-time v MLP (proven)
// =====================================================================
template <int KST1>
static __device__ __forceinline__ void mlp_core(
    unsigned short* __restrict__ BUF,
    const unsigned short* __restrict__ W1t, const float* __restrict__ b1,
    const unsigned short* __restrict__ W2t,
    int l15, int kg, int wr0, f4v* __restrict__ acc2)
{
  const int ldA = KST1 * 32 + 8;
  const f4v vzero = {0.f, 0.f, 0.f, 0.f};
  const unsigned short* Arow = BUF + (size_t)(wr0 + l15) * ldA;
  s8v af1[KST1];
#pragma unroll
  for (int k = 0; k < KST1; ++k) af1[k] = *(const s8v*)(Arow + k * 32 + kg * 8);
  __syncthreads();
  f4v acc1[16];
#pragma unroll
  for (int t = 0; t < 16; ++t) acc1[t] = vzero;
#pragma unroll
  for (int k = 0; k < KST1; ++k) {
#pragma unroll
    for (int t = 0; t < 16; ++t) {
      s8v b = *(const s8v*)(W1t + (size_t)(t * 16 + l15) * (KST1 * 32) + k * 32 + kg * 8);
      acc1[t] = mfma16(af1[k], b, acc1[t]);
    }
  }
#pragma unroll
  for (int t = 0; t < 16; ++t) {
    int c = t * 16 + l15;
    float bb = b1[c];
#pragma unroll
    for (int j = 0; j < 4; ++j) {
      BUF[(size_t)(wr0 + kg * 4 + j) * 264 + c] = f2bf(fmaxf(acc1[t][j] + bb, 0.f));
    }
  }
  const unsigned short* Hrow = BUF + (size_t)(wr0 + l15) * 264;
  s8v af2[8];
#pragma unroll
  for (int k = 0; k < 8; ++k) af2[k] = *(const s8v*)(Hrow + k * 32 + kg * 8);
#pragma unroll
  for (int t = 0; t < 8; ++t) acc2[t] = vzero;
#pragma unroll
  for (int k = 0; k < 8; ++k) {
#pragma unroll
    for (int t = 0; t < 8; ++t) {
      s8v b = *(const s8v*)(W2t + (size_t)(t * 16 + l15) * 256 + k * 32 + kg * 8);
      acc2[t] = mfma16(af2[k], b, acc2[t]);
    }
  }
}

__global__ __launch_bounds__(256, 2) void v_mlp_kernel(
    const float* __restrict__ x,
    const unsigned short* __restrict__ W1t, const float* __restrict__ b1,
    const unsigned short* __restrict__ W2t, const float* __restrict__ b2,
    float* __restrict__ hid)
{
  __shared__ unsigned short BUF[64 * 264];
  const int tid = threadIdx.x;
  const int base = blockIdx.x * 64;
#pragma unroll
  for (int it = 0; it < 8; ++it) {
    int i = tid + it * 256;
    int r = i >> 5, c4 = i & 31, n = base + r;
    float4 v = {0.f, 0.f, 0.f, 0.f};
    if (n < N_NODES) v = *(const float4*)(x + (size_t)n * 128 + c4 * 4);
    *(ushort4*)(BUF + r * 136 + c4 * 4) = f2bf4(v);
  }
  __syncthreads();
  const int lane = tid & 63, wv = tid >> 6;
  const int l15 = lane & 15, kg = lane >> 4, wr0 = wv * 16;
  f4v acc2[8];
  mlp_core<4>(BUF, W1t, b1, W2t, l15, kg, wr0, acc2);
#pragma unroll
  for (int t = 0; t < 8; ++t) {
    int c = t * 16 + l15;
    float bb = b2[c];
#pragma unroll
    for (int j = 0; j < 4; ++j) {
      int n = base + wr0 + kg * 4 + j;
      if (n < N_NODES) hid[(size_t)n * 128 + c] = fmaxf(acc2[t][j] + bb, 0.f);
    }
  }
}

// ---------------- prep kernels ----------------
__global__ void transpose_w(const float* __restrict__ W, unsigned short* __restrict__ Wt,
                            int K, int NH) {
  int i = blockIdx.x * 256 + threadIdx.x;
  if (i < K * NH) {
    int k = i / NH, n = i - k * NH;
    Wt[(size_t)n * K + k] = f2bf(W[i]);
  }
}

// W [384][256] f32 -> stg [12][4][256][8] bf16
__global__ void build_w1stg(const float* __restrict__ W, unsigned short* __restrict__ stg) {
  int i = blockIdx.x * 256 + threadIdx.x;
  if (i < 384 * 256) {
    int k = i >> 8, out = i & 255;
    int s = k >> 5, kc = (k >> 3) & 3, j = k & 7;
    stg[(size_t)s * 8192 + kc * 2048 + out * 8 + j] = f2bf(W[i]);
  }
}

// W [256][128] f32 -> stg [8][4][128][8] bf16
__global__ void build_w2stg(const float* __restrict__ W, unsigned short* __restrict__ stg) {
  int i = blockIdx.x * 256 + threadIdx.x;
  if (i < 256 * 128) {
    int k = i >> 7, out = i & 127;
    int s = k >> 5, kc = (k >> 3) & 3, j = k & 7;
    stg[(size_t)s * 4096 + kc * 1024 + out * 8 + j] = f2bf(W[i]);
  }
}

// dst[256][128] bf16 XOR-swizzled; dst[j][e] = W[(k_off+e)*256 + j]
__global__ void build_w128_sw(const float* __restrict__ W, int k_off,
                              unsigned short* __restrict__ dst) {
  int i = blockIdx.x * 256 + threadIdx.x;
  if (i < 256 * 128) {
    int j = i >> 7, e = i & 127;
    int unit = (e >> 3) ^ (j & 7);
    dst[(size_t)j * 128 + unit * 8 + (e & 7)] = f2bf(W[(size_t)(k_off + e) * 256 + j]);
  }
}

// dst[128][256] bf16 swizzled; dst[j][k] = W[k*128 + j]
__global__ void build_w2sw(const float* __restrict__ W, unsigned short* __restrict__ dst) {
  int i = blockIdx.x * 256 + threadIdx.x;
  if (i < 128 * 256) {
    int j = i >> 8, k = i & 255;
    dst[(size_t)j * 256 + (((k >> 3) ^ (j & 7)) * 8) + (k & 7)] =
        f2bf(W[(size_t)k * 128 + j]);
  }
}

__global__ void make_samples(float* __restrict__ xs) {
  int i = blockIdx.x * 256 + threadIdx.x;
  if (i < 4160) {
    int s = i < M_TAB ? i : M_TAB;
    xs[i] = (float)s * (1.f / (float)M_TAB);
  }
}

__global__ void count_kernel(const int* __restrict__ pn, const int* __restrict__ cn,
                             float* __restrict__ cp, float* __restrict__ cc) {
  int i = blockIdx.x * 256 + threadIdx.x;
  if (i < N_EDGES) {
    atomicAdd(cp + pn[i], 1.f);
    atomicAdd(cc + cn[i], 1.f);
  }
}

__global__ void rcp_kernel(float* __restrict__ cp, float* __restrict__ cc) {
  int i = blockIdx.x * 256 + threadIdx.x;
  if (i < N_NODES) {
    cp[i] = 1.f / fmaxf(cp[i], 1.f);
    cc[i] = 1.f / fmaxf(cc[i], 1.f);
  }
}

extern "C" void kernel_launch(void* const* d_in, const int* in_sizes, int n_in,
                              void* d_out, int out_size, void* d_ws, size_t ws_size,
                              hipStream_t stream) {
  const float* batch_token = (const float*)d_in[0];
  const int*   pn          = (const int*)d_in[1];
  const int*   cn          = (const int*)d_in[2];
  const float* indP        = (const float*)d_in[3];
  const float* indC        = (const float*)d_in[4];
  const float* p_mask      = (const float*)d_in[5];
  const float* c_mask      = (const float*)d_in[6];
  const float* stok        = (const float*)d_in[7];
  const float* etok        = (const float*)d_in[8];
  const float* vW1 = (const float*)d_in[9],  *vb1 = (const float*)d_in[10];
  const float* vW2 = (const float*)d_in[11], *vb2 = (const float*)d_in[12];
  const float* eW1 = (const float*)d_in[13], *eb1 = (const float*)d_in[14];
  const float* eW2 = (const float*)d_in[15], *eb2 = (const float*)d_in[16];
  const float* pW1 = (const float*)d_in[17], *pb1 = (const float*)d_in[18];
  const float* pW2 = (const float*)d_in[19], *pb2 = (const float*)d_in[20];
  const float* cW1 = (const float*)d_in[21], *cb1 = (const float*)d_in[22];
  const float* cW2 = (const float*)d_in[23], *cb2 = (const float*)d_in[24];
  const float* aW1 = (const float*)d_in[25], *ab1 = (const float*)d_in[26];
  const float* aW2 = (const float*)d_in[27], *ab2 = (const float*)d_in[28];

  char* w = (char*)d_ws;
  auto alloc = [&](size_t bytes) -> char* {
    char* p = w;
    w += (bytes + 255) & ~(size_t)255;
    return p;
  };
  // total ~109 MB (proven budget is >=257 MB)
  float* Sp    = (float*)alloc((size_t)N_NODES * 128 * 4);     // 25.6MB
  float* Sc    = (float*)alloc((size_t)N_NODES * 128 * 4);     // 25.6MB
  float* rcp_p = (float*)alloc((size_t)N_NODES * 4);
  float* rcp_c = (float*)alloc((size_t)N_NODES * 4);
  unsigned short* Zall   = (unsigned short*)alloc((size_t)N_NODES * 512 * 2);  // 51.2MB
  unsigned short* fsamp  = (unsigned short*)alloc((size_t)4160 * 128 * 2);     // 1.1MB
  unsigned short* Tp     = (unsigned short*)alloc((size_t)4160 * 256 * 2);     // 2.1MB
  unsigned short* Tc     = (unsigned short*)alloc((size_t)4160 * 256 * 2);     // 2.1MB
  float*          xsamp  = (float*)alloc((size_t)4160 * 4);
  unsigned short* Wbig_p = (unsigned short*)alloc((size_t)2 * 256 * 128 * 2);
  unsigned short* Wbig_c = (unsigned short*)alloc((size_t)2 * 256 * 128 * 2);
  unsigned short* W1csw_p = (unsigned short*)alloc(256 * 128 * 2);
  unsigned short* W1csw_c = (unsigned short*)alloc(256 * 128 * 2);
  unsigned short* W1stg_a = (unsigned short*)alloc(12 * 8192 * 2);
  unsigned short* W2stg_p = (unsigned short*)alloc(8 * 4096 * 2);
  unsigned short* W2stg_c = (unsigned short*)alloc(8 * 4096 * 2);
  unsigned short* W2stg_a = (unsigned short*)alloc(8 * 4096 * 2);
  unsigned short* W1t_v   = (unsigned short*)alloc(256 * 128 * 2);
  unsigned short* W2t_v   = (unsigned short*)alloc(128 * 256 * 2);
  unsigned short* W2sw_e  = (unsigned short*)alloc(128 * 256 * 2);

  float* hidden = (float*)d_out;

  const int EB = N_EDGES / 64;          // 6250
  const int NB = (N_NODES + 63) / 64;   // 782

  // counts -> reciprocals
  hipMemsetAsync(rcp_p, 0, (size_t)N_NODES * 4, stream);
  hipMemsetAsync(rcp_c, 0, (size_t)N_NODES * 4, stream);
  count_kernel<<<(N_EDGES + 255) / 256, 256, 0, stream>>>(pn, cn, rcp_p, rcp_c);
  rcp_kernel<<<(N_NODES + 255) / 256, 256, 0, stream>>>(rcp_p, rcp_c);

  // weight prep
  transpose_w<<<(128 * 256 + 255) / 256, 256, 0, stream>>>(vW1, W1t_v, 128, 256);
  transpose_w<<<(256 * 128 + 255) / 256, 256, 0, stream>>>(vW2, W2t_v, 256, 128);
  build_w2sw<<<(128 * 256 + 255) / 256, 256, 0, stream>>>(eW2, W2sw_e);
  build_w1stg<<<(384 * 256 + 255) / 256, 256, 0, stream>>>(aW1, W1stg_a);
  build_w2stg<<<(256 * 128 + 255) / 256, 256, 0, stream>>>(pW2, W2stg_p);
  build_w2stg<<<(256 * 128 + 255) / 256, 256, 0, stream>>>(cW2, W2stg_c);
  build_w2stg<<<(256 * 128 + 255) / 256, 256, 0, stream>>>(aW2, W2stg_a);
  const int SWB = (256 * 128 + 255) / 256;
  build_w128_sw<<<SWB, 256, 0, stream>>>(pW1, 0,   Wbig_p + 0 * 256 * 128);
  build_w128_sw<<<SWB, 256, 0, stream>>>(pW1, 128, Wbig_p + 1 * 256 * 128);
  build_w128_sw<<<SWB, 256, 0, stream>>>(cW1, 0,   Wbig_c + 0 * 256 * 128);
  build_w128_sw<<<SWB, 256, 0, stream>>>(cW1, 128, Wbig_c + 1 * 256 * 128);
  build_w128_sw<<<SWB, 256, 0, stream>>>(pW1, 256, W1csw_p);
  build_w128_sw<<<SWB, 256, 0, stream>>>(cW1, 256, W1csw_c);

  // edge-scalar tables: T*(x) = mlp_e(x) @ W1c + b1 at 4097 sample points
  make_samples<<<(4160 + 255) / 256, 256, 0, stream>>>(xsamp);
  edge_feat_kernel<<<65, 256, 0, stream>>>(xsamp, eW1, eb1, W2sw_e, eb2, fsamp, 65);
  tab_gemm_kernel<<<65, 256, 0, stream>>>(fsamp, W1csw_p, pb1, Tp);
  tab_gemm_kernel<<<65, 256, 0, stream>>>(fsamp, W1csw_c, cb1, Tc);

  // initial hidden
  v_mlp_kernel<<<NB, 256, 0, stream>>>(batch_token, W1t_v, vb1, W2t_v, vb2, hidden);

  for (int hop = 0; hop < 3; ++hop) {
    hipMemsetAsync(Sp, 0, (size_t)N_NODES * 128 * 4, stream);
    hipMemsetAsync(Sc, 0, (size_t)N_NODES * 128 * 4, stream);
    // p-dir: A=[hc|hp|ep]; Z g0 = hid@pW1[0:128] (idx cn), g1 = hid@pW1[128:256] (idx pn)
    z_gemm_kernel<<<dim3(256, 2), 256, 0, stream>>>(hidden, Wbig_p, Zall);
    edge_msg3_kernel<<<EB, 256, 0, stream>>>(Zall, indP, cn, pn, Tp,
                                             W2stg_p, pb2, Sp, rcp_p);
    // c-dir: A=[hp|hc|ec]
    z_gemm_kernel<<<dim3(256, 2), 256, 0, stream>>>(hidden, Wbig_c, Zall);
    edge_msg3_kernel<<<EB, 256, 0, stream>>>(Zall, indC, pn, cn, Tc,
                                             W2stg_c, cb2, Sc, rcp_c);
    aggr_kernel<<<NB, 256, 0, stream>>>(hidden, Sp, Sc, p_mask, c_mask,
                                        stok, etok, W1stg_a, ab1, W2stg_a, ab2);
  }
  (void)in_sizes; (void)n_in; (void)out_size; (void)ws_size;
}

// Round 7
// 1703.069 us; speedup vs baseline: 3.7924x; 1.1723x over previous
//
#include <hip/hip_runtime.h>
#include <stdint.h>

#define N_NODES 50000
#define N_EDGES 400000
#define M_TAB 4096          // lerp intervals; samples 0..4096, alloc 4160 rows

typedef short s8v __attribute__((ext_vector_type(8)));
typedef float f4v __attribute__((ext_vector_type(4)));

static __device__ __forceinline__ unsigned short f2bf(float f) {
  union { float f; uint32_t u; } v; v.f = f;
  return (unsigned short)((v.u + 0x7FFFu + ((v.u >> 16) & 1u)) >> 16);
}
static __device__ __forceinline__ ushort4 f2bf4(float4 v) {
  ushort4 o; o.x = f2bf(v.x); o.y = f2bf(v.y); o.z = f2bf(v.z); o.w = f2bf(v.w);
  return o;
}
static __device__ __forceinline__ void bf2(uint32_t u, float& a, float& b) {
  union { uint32_t x; float f; } lo, hi;
  lo.x = u << 16; hi.x = u & 0xffff0000u;
  a = lo.f; b = hi.f;
}
static __device__ __forceinline__ f4v mfma16(s8v a, s8v b, f4v c) {
  return __builtin_amdgcn_mfma_f32_16x16x32_bf16(a, b, c, 0, 0, 0);
}
// async global->LDS, 16B/lane; LDS dest = wave-uniform base + lane*16
static __device__ __forceinline__ void gload_lds16(const void* g, void* l) {
  __builtin_amdgcn_global_load_lds(
      (const __attribute__((address_space(1))) uint32_t*)g,
      (__attribute__((address_space(3))) uint32_t*)l, 16, 0, 0);
}

// =====================================================================
// Z-GEMM (proven v6)
// =====================================================================
__global__ __launch_bounds__(256) void z_gemm_kernel(
    const float* __restrict__ hid, const unsigned short* __restrict__ Wsw,
    unsigned short* __restrict__ Z)
{
  __shared__ __align__(16) unsigned short B[256 * 128];
  const int tid = threadIdx.x, lane = tid & 63, wv = tid >> 6;
  const int g = blockIdx.y;
  const unsigned short* src = Wsw + (size_t)g * 256 * 128;
#pragma unroll
  for (int it = 0; it < 16; ++it) {
    int q = it * 4 + wv;
    gload_lds16(src + (size_t)q * 512 + lane * 8, &B[q * 512]);
  }
  __syncthreads();
  const int l15 = lane & 15, kg = lane >> 4;
  const f4v vz = {0.f, 0.f, 0.f, 0.f};
  for (int c0 = blockIdx.x; c0 < (N_NODES + 63) / 64; c0 += gridDim.x) {
    const int base = c0 * 64;
    const int row = base + wv * 16 + l15;
    s8v af[4];
#pragma unroll
    for (int k = 0; k < 4; ++k) {
      float4 u0 = {0.f,0.f,0.f,0.f}, u1 = {0.f,0.f,0.f,0.f};
      if (row < N_NODES) {
        u0 = *(const float4*)(hid + (size_t)row * 128 + k * 32 + kg * 8);
        u1 = *(const float4*)(hid + (size_t)row * 128 + k * 32 + kg * 8 + 4);
      }
      s8v a;
      a[0] = (short)f2bf(u0.x); a[1] = (short)f2bf(u0.y);
      a[2] = (short)f2bf(u0.z); a[3] = (short)f2bf(u0.w);
      a[4] = (short)f2bf(u1.x); a[5] = (short)f2bf(u1.y);
      a[6] = (short)f2bf(u1.z); a[7] = (short)f2bf(u1.w);
      af[k] = a;
    }
    f4v acc[16];
#pragma unroll
    for (int t = 0; t < 16; ++t) acc[t] = vz;
#pragma unroll
    for (int k = 0; k < 4; ++k) {
#pragma unroll
      for (int t = 0; t < 16; ++t) {
        int j = t * 16 + l15;
        s8v b = *(const s8v*)(&B[j * 128 + (((k * 4 + kg) ^ (j & 7)) * 8)]);
        acc[t] = mfma16(af[k], b, acc[t]);
      }
    }
#pragma unroll
    for (int t = 0; t < 16; ++t) {
      int c = t * 16 + l15;
#pragma unroll
      for (int j = 0; j < 4; ++j) {
        int ro = base + wv * 16 + kg * 4 + j;
        if (ro < N_NODES) Z[(size_t)ro * 512 + g * 256 + c] = f2bf(acc[t][j]);
      }
    }
  }
}

// =====================================================================
// Table GEMM (proven v6)
// =====================================================================
__global__ __launch_bounds__(256) void tab_gemm_kernel(
    const unsigned short* __restrict__ feat,
    const unsigned short* __restrict__ Wsw,
    const float* __restrict__ b1, unsigned short* __restrict__ T)
{
  __shared__ __align__(16) unsigned short B[256 * 128];
  const int tid = threadIdx.x, lane = tid & 63, wv = tid >> 6;
#pragma unroll
  for (int it = 0; it < 16; ++it) {
    int q = it * 4 + wv;
    gload_lds16(Wsw + (size_t)q * 512 + lane * 8, &B[q * 512]);
  }
  __syncthreads();
  const int l15 = lane & 15, kg = lane >> 4;
  const int base = blockIdx.x * 64;
  const int row = base + wv * 16 + l15;
  s8v af[4];
#pragma unroll
  for (int k = 0; k < 4; ++k)
    af[k] = *(const s8v*)(feat + (size_t)row * 128 + k * 32 + kg * 8);
  const f4v vz = {0.f, 0.f, 0.f, 0.f};
  f4v acc[16];
#pragma unroll
  for (int t = 0; t < 16; ++t) acc[t] = vz;
#pragma unroll
  for (int k = 0; k < 4; ++k) {
#pragma unroll
    for (int t = 0; t < 16; ++t) {
      int j = t * 16 + l15;
      s8v b = *(const s8v*)(&B[j * 128 + (((k * 4 + kg) ^ (j & 7)) * 8)]);
      acc[t] = mfma16(af[k], b, acc[t]);
    }
  }
#pragma unroll
  for (int t = 0; t < 16; ++t) {
    int c = t * 16 + l15;
    float bb = b1[c];
#pragma unroll
    for (int j = 0; j < 4; ++j) {
      int ro = base + wv * 16 + kg * 4 + j;
      T[(size_t)ro * 256 + c] = f2bf(acc[t][j] + bb);
    }
  }
}

// =====================================================================
// Edge message, SORTED (edges pre-sorted by target node):
//   H1 = relu(Z[sn0][0:256] + Z[sn1][256:512] + lerp(T, sx))
//   out = relu(H1 @ W2 + b2)  -> LDS f32 -> run-reduce over equal sn1
//   -> atomicAdd(Sacc[n], run_sum * rcp[n])
// =====================================================================
__global__ __launch_bounds__(256) void edge_msg4_kernel(
    const unsigned short* __restrict__ Z,   // [N][512]
    const int* __restrict__ sn0, const int* __restrict__ sn1,
    const float* __restrict__ sx,
    const unsigned short* __restrict__ T,   // [4097][256]
    const unsigned short* __restrict__ W2stg, const float* __restrict__ b2,
    float* __restrict__ Sacc, const float* __restrict__ rcpv)
{
  __shared__ __align__(16) unsigned short H1[64 * 256];  // 32KB; reused as f32 OUT
  __shared__ __align__(16) unsigned short Wb[2][4096];   // 16KB
  __shared__ int n0s[64], n1s[64], tix[64];
  __shared__ float tfr[64], tsc[64];
  const int tid = threadIdx.x, lane = tid & 63, wv = tid >> 6;
  const int l15 = lane & 15, kg = lane >> 4;
  const int base = blockIdx.x * 64;  // E % 64 == 0
  if (tid < 64) {
    int e = base + tid;
    int a0 = sn0[e], a1 = sn1[e];
    n0s[tid] = a0; n1s[tid] = a1; tsc[tid] = rcpv[a1];
    float x = sx[e];
    float xs = x * (float)M_TAB;
    int idx = (int)xs;
    idx = idx < 0 ? 0 : (idx > M_TAB - 1 ? M_TAB - 1 : idx);
    tix[tid] = idx;
    tfr[tid] = xs - (float)idx;
  }
  // stage W2 slice 0
#pragma unroll
  for (int i = 0; i < 2; ++i) {
    int q = wv * 2 + i;
    gload_lds16(W2stg + (size_t)q * 512 + lane * 8, &Wb[0][q * 512]);
  }
  __syncthreads();
  // build H1 = relu(Za + Zb + lerp) (swizzled 16B units)
#pragma unroll
  for (int it = 0; it < 8; ++it) {
    int i = tid + it * 256;
    int r = i >> 5, c8 = i & 31;
    const uint4 za = *(const uint4*)(Z + (size_t)n0s[r] * 512 + c8 * 8);
    const uint4 zb = *(const uint4*)(Z + (size_t)n1s[r] * 512 + 256 + c8 * 8);
    const uint4 t0 = *(const uint4*)(T + (size_t)tix[r] * 256 + c8 * 8);
    const uint4 t1 = *(const uint4*)(T + (size_t)(tix[r] + 1) * 256 + c8 * 8);
    const float f = tfr[r];
    uint32_t ua[4] = {za.x, za.y, za.z, za.w};
    uint32_t ub[4] = {zb.x, zb.y, zb.z, zb.w};
    uint32_t u0[4] = {t0.x, t0.y, t0.z, t0.w};
    uint32_t u1[4] = {t1.x, t1.y, t1.z, t1.w};
    uint32_t uo[4];
#pragma unroll
    for (int q = 0; q < 4; ++q) {
      float a0, a1, b0, b1f, p0, p1, q0, q1;
      bf2(ua[q], a0, a1); bf2(ub[q], b0, b1f);
      bf2(u0[q], p0, p1); bf2(u1[q], q0, q1);
      float s0 = fmaxf(a0 + b0 + p0 + f * (q0 - p0), 0.f);
      float s1 = fmaxf(a1 + b1f + p1 + f * (q1 - p1), 0.f);
      uo[q] = (uint32_t)f2bf(s0) | ((uint32_t)f2bf(s1) << 16);
    }
    uint4 pk; pk.x = uo[0]; pk.y = uo[1]; pk.z = uo[2]; pk.w = uo[3];
    *(uint4*)(H1 + r * 256 + ((c8 ^ (r & 7)) * 8)) = pk;
  }
  __syncthreads();
  // layer 2: [64,256] @ W2 -> [64,128], 8 staged K-phases
  const int rr = wv * 16 + l15;
  s8v af2[8];
#pragma unroll
  for (int k = 0; k < 8; ++k)
    af2[k] = *(const s8v*)(H1 + rr * 256 + (((k * 4 + kg) ^ (l15 & 7)) * 8));
  const f4v vz = {0.f, 0.f, 0.f, 0.f};
  f4v acc2[8];
#pragma unroll
  for (int t = 0; t < 8; ++t) acc2[t] = vz;
#pragma unroll
  for (int s = 0; s < 8; ++s) {
    if (s < 7) {
#pragma unroll
      for (int i = 0; i < 2; ++i) {
        int q = wv * 2 + i;
        gload_lds16(W2stg + (size_t)(s + 1) * 4096 + q * 512 + lane * 8,
                    &Wb[(s + 1) & 1][q * 512]);
      }
    }
#pragma unroll
    for (int t = 0; t < 8; ++t) {
      s8v b = *(const s8v*)(&Wb[s & 1][kg * 1024 + (t * 16 + l15) * 8]);
      acc2[t] = mfma16(af2[s], b, acc2[t]);
    }
    __syncthreads();
  }
  // per-edge out (bias+relu) -> f32 LDS (aliases H1; af2 long consumed)
  float* OUT = (float*)H1;
#pragma unroll
  for (int t = 0; t < 8; ++t) {
    int c = t * 16 + l15;
    float bb = b2[c];
#pragma unroll
    for (int j = 0; j < 4; ++j) {
      int r = wv * 16 + kg * 4 + j;
      OUT[r * 128 + c] = fmaxf(acc2[t][j] + bb, 0.f);
    }
  }
  __syncthreads();
  // run-reduction over equal targets (sorted): thread = (col, half)
  {
    const int c = tid & 127, h = tid >> 7;
    const int r0 = h * 32;
    float acc = 0.f;
    int cur = n1s[r0];
    float curs = tsc[r0];
    for (int r = r0; r < r0 + 32; ++r) {
      int nn = n1s[r];
      if (nn != cur) {
        atomicAdd(Sacc + (size_t)cur * 128 + c, acc * curs);
        acc = 0.f; cur = nn; curs = tsc[r];
      }
      acc += OUT[r * 128 + c];
    }
    atomicAdd(Sacc + (size_t)cur * 128 + c, acc * curs);
  }
}

// =====================================================================
// Aggr MLP (proven v4/v5/v6)
// =====================================================================
__global__ __launch_bounds__(256, 2) void aggr_kernel(
    float* __restrict__ hid,
    const float* __restrict__ Sp, const float* __restrict__ Sc,
    const float* __restrict__ pm, const float* __restrict__ cm,
    const float* __restrict__ st, const float* __restrict__ et,
    const unsigned short* __restrict__ W1stg, const float* __restrict__ b1,
    const unsigned short* __restrict__ W2stg, const float* __restrict__ b2)
{
  __shared__ __align__(16) unsigned short ABUF[64 * 384];
  __shared__ __align__(16) unsigned short Wb[2][8192];
  const int tid = threadIdx.x, lane = tid & 63, wv = tid >> 6;
  const int l15 = lane & 15, kg = lane >> 4;
  const int base = blockIdx.x * 64;
#pragma unroll
  for (int i = 0; i < 4; ++i) {
    int q = wv * 4 + i;
    gload_lds16(W1stg + (size_t)q * 512 + lane * 8, &Wb[0][q * 512]);
  }
#pragma unroll
  for (int it = 0; it < 24; ++it) {
    int i = tid + it * 256;
    int r = i / 96, q = i - r * 96;
    int seg = q >> 5, c4 = q & 31;
    int n = base + r;
    float4 v = {0.f, 0.f, 0.f, 0.f};
    if (n < N_NODES) {
      if (seg == 0) {
        v = *(const float4*)(hid + (size_t)n * 128 + c4 * 4);
      } else if (seg == 1) {
        v = *(const float4*)(Sp + (size_t)n * 128 + c4 * 4);
        float m = pm[n]; const float4 t = *(const float4*)(st + c4 * 4);
        v.x = fmaf(m, t.x, v.x); v.y = fmaf(m, t.y, v.y);
        v.z = fmaf(m, t.z, v.z); v.w = fmaf(m, t.w, v.w);
      } else {
        v = *(const float4*)(Sc + (size_t)n * 128 + c4 * 4);
        float m = cm[n]; const float4 t = *(const float4*)(et + c4 * 4);
        v.x = fmaf(m, t.x, v.x); v.y = fmaf(m, t.y, v.y);
        v.z = fmaf(m, t.z, v.z); v.w = fmaf(m, t.w, v.w);
      }
    }
    int unit = seg * 16 + (c4 >> 1);
    *(ushort4*)(ABUF + r * 384 + ((unit ^ (r & 7)) * 8) + (c4 & 1) * 4) = f2bf4(v);
  }
  __syncthreads();
  const int rr = wv * 16 + l15;
  s8v af1[12];
#pragma unroll
  for (int k = 0; k < 12; ++k)
    af1[k] = *(const s8v*)(ABUF + rr * 384 + (((k * 4 + kg) ^ (rr & 7)) * 8));
  const f4v vz = {0.f, 0.f, 0.f, 0.f};
  f4v acc1[16];
#pragma unroll
  for (int t = 0; t < 16; ++t) acc1[t] = vz;
#pragma unroll
  for (int s = 0; s < 12; ++s) {
    if (s < 11) {
#pragma unroll
      for (int i = 0; i < 4; ++i) {
        int q = wv * 4 + i;
        gload_lds16(W1stg + (size_t)(s + 1) * 8192 + q * 512 + lane * 8,
                    &Wb[(s + 1) & 1][q * 512]);
      }
    } else {
#pragma unroll
      for (int i = 0; i < 2; ++i) {
        int q = wv * 2 + i;
        gload_lds16(W2stg + (size_t)q * 512 + lane * 8, &Wb[0][q * 512]);
      }
    }
#pragma unroll
    for (int t = 0; t < 16; ++t) {
      s8v b = *(const s8v*)(&Wb[s & 1][kg * 2048 + (t * 16 + l15) * 8]);
      acc1[t] = mfma16(af1[s], b, acc1[t]);
    }
    __syncthreads();
  }
#pragma unroll
  for (int t = 0; t < 16; ++t) {
    int c = t * 16 + l15;
    float bb = b1[c];
#pragma unroll
    for (int j = 0; j < 4; ++j) {
      int r = wv * 16 + kg * 4 + j;
      ABUF[r * 256 + (((c >> 3) ^ (r & 7)) * 8) + (c & 7)] =
          f2bf(fmaxf(acc1[t][j] + bb, 0.f));
    }
  }
  __syncthreads();
  s8v af2[8];
#pragma unroll
  for (int k = 0; k < 8; ++k)
    af2[k] = *(const s8v*)(ABUF + rr * 256 + (((k * 4 + kg) ^ (l15 & 7)) * 8));
  f4v acc2[8];
#pragma unroll
  for (int t = 0; t < 8; ++t) acc2[t] = vz;
#pragma unroll
  for (int s = 0; s < 8; ++s) {
    if (s < 7) {
#pragma unroll
      for (int i = 0; i < 2; ++i) {
        int q = wv * 2 + i;
        gload_lds16(W2stg + (size_t)(s + 1) * 4096 + q * 512 + lane * 8,
                    &Wb[(s + 1) & 1][q * 512]);
      }
    }
#pragma unroll
    for (int t = 0; t < 8; ++t) {
      s8v b = *(const s8v*)(&Wb[s & 1][kg * 1024 + (t * 16 + l15) * 8]);
      acc2[t] = mfma16(af2[s], b, acc2[t]);
    }
    __syncthreads();
  }
#pragma unroll
  for (int t = 0; t < 8; ++t) {
    int c = t * 16 + l15;
    float bb = b2[c];
#pragma unroll
    for (int j = 0; j < 4; ++j) {
      int ro = base + wv * 16 + kg * 4 + j;
      if (ro < N_NODES) hid[(size_t)ro * 128 + c] += fmaxf(acc2[t][j] + bb, 0.f);
    }
  }
}

// =====================================================================
// edge-scalar MLP with resident W2 (proven v6) — used for table samples
// =====================================================================
__global__ __launch_bounds__(256) void edge_feat_kernel(
    const float* __restrict__ ind, const float* __restrict__ W1,
    const float* __restrict__ b1,
    const unsigned short* __restrict__ W2sw,
    const float* __restrict__ b2, unsigned short* __restrict__ feat,
    int ntiles)
{
  __shared__ __align__(16) unsigned short B[128 * 256];  // 64KB
  __shared__ unsigned short H1[64 * 264];
  __shared__ float xs[64];
  const int tid = threadIdx.x, lane = tid & 63, wv = tid >> 6;
  const int l15 = lane & 15, kg = lane >> 4;
#pragma unroll
  for (int it = 0; it < 16; ++it) {
    int q = it * 4 + wv;
    gload_lds16(W2sw + (size_t)q * 512 + lane * 8, &B[q * 512]);
  }
  const float w = W1[tid], bb1 = b1[tid];
  const f4v vz = {0.f, 0.f, 0.f, 0.f};
  for (int tile = blockIdx.x; tile < ntiles; tile += gridDim.x) {
    const int base = tile * 64;
    if (tid < 64) xs[tid] = ind[base + tid];
    __syncthreads();
    for (int r = 0; r < 64; ++r)
      H1[r * 264 + tid] = f2bf(fmaxf(fmaf(xs[r], w, bb1), 0.f));
    __syncthreads();
    const unsigned short* Hrow = H1 + (size_t)(wv * 16 + l15) * 264;
    s8v af2[8];
#pragma unroll
    for (int k = 0; k < 8; ++k) af2[k] = *(const s8v*)(Hrow + k * 32 + kg * 8);
    f4v acc2[8];
#pragma unroll
    for (int t = 0; t < 8; ++t) acc2[t] = vz;
#pragma unroll
    for (int k = 0; k < 8; ++k) {
#pragma unroll
      for (int t = 0; t < 8; ++t) {
        int j = t * 16 + l15;
        s8v b = *(const s8v*)(&B[j * 256 + (((k * 4 + kg) ^ (j & 7)) * 8)]);
        acc2[t] = mfma16(af2[k], b, acc2[t]);
      }
    }
#pragma unroll
    for (int t = 0; t < 8; ++t) {
      int c = t * 16 + l15;
      float b2c = b2[c];
#pragma unroll
      for (int j = 0; j < 4; ++j) {
        int e = base + wv * 16 + kg * 4 + j;
        feat[(size_t)e * 128 + c] = f2bf(fmaxf(acc2[t][j] + b2c, 0.f));
      }
    }
    __syncthreads();
  }
}

// =====================================================================
// one-time v MLP (proven)
// =====================================================================
template <int KST1>
static __device__ __forceinline__ void mlp_core(
    unsigned short* __restrict__ BUF,
    const unsigned short* __restrict__ W1t, const float* __restrict__ b1,
    const unsigned short* __restrict__ W2t,
    int l15, int kg, int wr0, f4v* __restrict__ acc2)
{
  const int ldA = KST1 * 32 + 8;
  const f4v vzero = {0.f, 0.f, 0.f, 0.f};
  const unsigned short* Arow = BUF + (size_t)(wr0 + l15) * ldA;
  s8v af1[KST1];
#pragma unroll
  for (int k = 0; k < KST1; ++k) af1[k] = *(const s8v*)(Arow + k * 32 + kg * 8);
  __syncthreads();
  f4v acc1[16];
#pragma unroll
  for (int t = 0; t < 16; ++t) acc1[t] = vzero;
#pragma unroll
  for (int k = 0; k < KST1; ++k) {
#pragma unroll
    for (int t = 0; t < 16; ++t) {
      s8v b = *(const s8v*)(W1t + (size_t)(t * 16 + l15) * (KST1 * 32) + k * 32 + kg * 8);
      acc1[t] = mfma16(af1[k], b, acc1[t]);
    }
  }
#pragma unroll
  for (int t = 0; t < 16; ++t) {
    int c = t * 16 + l15;
    float bb = b1[c];
#pragma unroll
    for (int j = 0; j < 4; ++j) {
      BUF[(size_t)(wr0 + kg * 4 + j) * 264 + c] = f2bf(fmaxf(acc1[t][j] + bb, 0.f));
    }
  }
  const unsigned short* Hrow = BUF + (size_t)(wr0 + l15) * 264;
  s8v af2[8];
#pragma unroll
  for (int k = 0; k < 8; ++k) af2[k] = *(const s8v*)(Hrow + k * 32 + kg * 8);
#pragma unroll
  for (int t = 0; t < 8; ++t) acc2[t] = vzero;
#pragma unroll
  for (int k = 0; k < 8; ++k) {
#pragma unroll
    for (int t = 0; t < 8; ++t) {
      s8v b = *(const s8v*)(W2t + (size_t)(t * 16 + l15) * 256 + k * 32 + kg * 8);
      acc2[t] = mfma16(af2[k], b, acc2[t]);
    }
  }
}

__global__ __launch_bounds__(256, 2) void v_mlp_kernel(
    const float* __restrict__ x,
    const unsigned short* __restrict__ W1t, const float* __restrict__ b1,
    const unsigned short* __restrict__ W2t, const float* __restrict__ b2,
    float* __restrict__ hid)
{
  __shared__ unsigned short BUF[64 * 264];
  const int tid = threadIdx.x;
  const int base = blockIdx.x * 64;
#pragma unroll
  for (int it = 0; it < 8; ++it) {
    int i = tid + it * 256;
    int r = i >> 5, c4 = i & 31, n = base + r;
    float4 v = {0.f, 0.f, 0.f, 0.f};
    if (n < N_NODES) v = *(const float4*)(x + (size_t)n * 128 + c4 * 4);
    *(ushort4*)(BUF + r * 136 + c4 * 4) = f2bf4(v);
  }
  __syncthreads();
  const int lane = tid & 63, wv = tid >> 6;
  const int l15 = lane & 15, kg = lane >> 4, wr0 = wv * 16;
  f4v acc2[8];
  mlp_core<4>(BUF, W1t, b1, W2t, l15, kg, wr0, acc2);
#pragma unroll
  for (int t = 0; t < 8; ++t) {
    int c = t * 16 + l15;
    float bb = b2[c];
#pragma unroll
    for (int j = 0; j < 4; ++j) {
      int n = base + wr0 + kg * 4 + j;
      if (n < N_NODES) hid[(size_t)n * 128 + c] = fmaxf(acc2[t][j] + bb, 0.f);
    }
  }
}

// ---------------- sorting + prep kernels ----------------
__global__ void counti_kernel(const int* __restrict__ pn, const int* __restrict__ cn,
                              int* __restrict__ cp, int* __restrict__ cc) {
  int i = blockIdx.x * 256 + threadIdx.x;
  if (i < N_EDGES) {
    atomicAdd(cp + pn[i], 1);
    atomicAdd(cc + cn[i], 1);
  }
}

__global__ void rcpi_kernel(const int* __restrict__ cp, const int* __restrict__ cc,
                            float* __restrict__ rp, float* __restrict__ rc) {
  int i = blockIdx.x * 256 + threadIdx.x;
  if (i < N_NODES) {
    rp[i] = 1.f / fmaxf((float)cp[i], 1.f);
    rc[i] = 1.f / fmaxf((float)cc[i], 1.f);
  }
}

// single-block exclusive scan of cnt[N_NODES] -> cur (chunked, 1024 threads)
__global__ void scan_kernel(const int* __restrict__ cnt, int* __restrict__ cur) {
  __shared__ int part[1024];
  const int t = threadIdx.x;
  const int CH = (N_NODES + 1023) / 1024;  // 49
  int s = 0;
#pragma unroll 1
  for (int i = 0; i < CH; ++i) {
    int idx = t * CH + i;
    if (idx < N_NODES) s += cnt[idx];
  }
  part[t] = s;
  __syncthreads();
  for (int d = 1; d < 1024; d <<= 1) {
    int v = (t >= d) ? part[t - d] : 0;
    __syncthreads();
    part[t] += v;
    __syncthreads();
  }
  int run = part[t] - s;  // exclusive base of this chunk
#pragma unroll 1
  for (int i = 0; i < CH; ++i) {
    int idx = t * CH + i;
    if (idx < N_NODES) { cur[idx] = run; run += cnt[idx]; }
  }
}

// scatter edges into target-sorted gathered arrays
__global__ void scatter_kernel(const int* __restrict__ tgt, const int* __restrict__ oth,
                               const float* __restrict__ x, int* __restrict__ cursor,
                               int* __restrict__ sn0, int* __restrict__ sn1,
                               float* __restrict__ sx) {
  int e = blockIdx.x * 256 + threadIdx.x;
  if (e < N_EDGES) {
    int tN = tgt[e];
    int pos = atomicAdd(cursor + tN, 1);
    sn0[pos] = oth[e];
    sn1[pos] = tN;
    sx[pos] = x[e];
  }
}

__global__ void transpose_w(const float* __restrict__ W, unsigned short* __restrict__ Wt,
                            int K, int NH) {
  int i = blockIdx.x * 256 + threadIdx.x;
  if (i < K * NH) {
    int k = i / NH, n = i - k * NH;
    Wt[(size_t)n * K + k] = f2bf(W[i]);
  }
}

__global__ void build_w1stg(const float* __restrict__ W, unsigned short* __restrict__ stg) {
  int i = blockIdx.x * 256 + threadIdx.x;
  if (i < 384 * 256) {
    int k = i >> 8, out = i & 255;
    int s = k >> 5, kc = (k >> 3) & 3, j = k & 7;
    stg[(size_t)s * 8192 + kc * 2048 + out * 8 + j] = f2bf(W[i]);
  }
}

__global__ void build_w2stg(const float* __restrict__ W, unsigned short* __restrict__ stg) {
  int i = blockIdx.x * 256 + threadIdx.x;
  if (i < 256 * 128) {
    int k = i >> 7, out = i & 127;
    int s = k >> 5, kc = (k >> 3) & 3, j = k & 7;
    stg[(size_t)s * 4096 + kc * 1024 + out * 8 + j] = f2bf(W[i]);
  }
}

__global__ void build_w128_sw(const float* __restrict__ W, int k_off,
                              unsigned short* __restrict__ dst) {
  int i = blockIdx.x * 256 + threadIdx.x;
  if (i < 256 * 128) {
    int j = i >> 7, e = i & 127;
    int unit = (e >> 3) ^ (j & 7);
    dst[(size_t)j * 128 + unit * 8 + (e & 7)] = f2bf(W[(size_t)(k_off + e) * 256 + j]);
  }
}

__global__ void build_w2sw(const float* __restrict__ W, unsigned short* __restrict__ dst) {
  int i = blockIdx.x * 256 + threadIdx.x;
  if (i < 128 * 256) {
    int j = i >> 8, k = i & 255;
    dst[(size_t)j * 256 + (((k >> 3) ^ (j & 7)) * 8) + (k & 7)] =
        f2bf(W[(size_t)k * 128 + j]);
  }
}

__global__ void make_samples(float* __restrict__ xs) {
  int i = blockIdx.x * 256 + threadIdx.x;
  if (i < 4160) {
    int s = i < M_TAB ? i : M_TAB;
    xs[i] = (float)s * (1.f / (float)M_TAB);
  }
}

extern "C" void kernel_launch(void* const* d_in, const int* in_sizes, int n_in,
                              void* d_out, int out_size, void* d_ws, size_t ws_size,
                              hipStream_t stream) {
  const float* batch_token = (const float*)d_in[0];
  const int*   pn          = (const int*)d_in[1];
  const int*   cn          = (const int*)d_in[2];
  const float* indP        = (const float*)d_in[3];
  const float* indC        = (const float*)d_in[4];
  const float* p_mask      = (const float*)d_in[5];
  const float* c_mask      = (const float*)d_in[6];
  const float* stok        = (const float*)d_in[7];
  const float* etok        = (const float*)d_in[8];
  const float* vW1 = (const float*)d_in[9],  *vb1 = (const float*)d_in[10];
  const float* vW2 = (const float*)d_in[11], *vb2 = (const float*)d_in[12];
  const float* eW1 = (const float*)d_in[13], *eb1 = (const float*)d_in[14];
  const float* eW2 = (const float*)d_in[15], *eb2 = (const float*)d_in[16];
  const float* pW1 = (const float*)d_in[17], *pb1 = (const float*)d_in[18];
  const float* pW2 = (const float*)d_in[19], *pb2 = (const float*)d_in[20];
  const float* cW1 = (const float*)d_in[21], *cb1 = (const float*)d_in[22];
  const float* cW2 = (const float*)d_in[23], *cb2 = (const float*)d_in[24];
  const float* aW1 = (const float*)d_in[25], *ab1 = (const float*)d_in[26];
  const float* aW2 = (const float*)d_in[27], *ab2 = (const float*)d_in[28];

  char* w = (char*)d_ws;
  auto alloc = [&](size_t bytes) -> char* {
    char* p = w;
    w += (bytes + 255) & ~(size_t)255;
    return p;
  };
  // total ~121 MB (proven budget >=257 MB)
  float* Sp    = (float*)alloc((size_t)N_NODES * 128 * 4);
  float* Sc    = (float*)alloc((size_t)N_NODES * 128 * 4);
  float* rcp_p = (float*)alloc((size_t)N_NODES * 4);
  float* rcp_c = (float*)alloc((size_t)N_NODES * 4);
  int*   cnt_p = (int*)alloc((size_t)N_NODES * 4);
  int*   cnt_c = (int*)alloc((size_t)N_NODES * 4);
  int*   cur_p = (int*)alloc((size_t)N_NODES * 4);
  int*   cur_c = (int*)alloc((size_t)N_NODES * 4);
  int*   sn0_p = (int*)alloc((size_t)N_EDGES * 4);
  int*   sn1_p = (int*)alloc((size_t)N_EDGES * 4);
  float* sx_p  = (float*)alloc((size_t)N_EDGES * 4);
  int*   sn0_c = (int*)alloc((size_t)N_EDGES * 4);
  int*   sn1_c = (int*)alloc((size_t)N_EDGES * 4);
  float* sx_c  = (float*)alloc((size_t)N_EDGES * 4);
  unsigned short* Zall   = (unsigned short*)alloc((size_t)N_NODES * 512 * 2);
  unsigned short* fsamp  = (unsigned short*)alloc((size_t)4160 * 128 * 2);
  unsigned short* Tp     = (unsigned short*)alloc((size_t)4160 * 256 * 2);
  unsigned short* Tc     = (unsigned short*)alloc((size_t)4160 * 256 * 2);
  float*          xsamp  = (float*)alloc((size_t)4160 * 4);
  unsigned short* Wbig_p = (unsigned short*)alloc((size_t)2 * 256 * 128 * 2);
  unsigned short* Wbig_c = (unsigned short*)alloc((size_t)2 * 256 * 128 * 2);
  unsigned short* W1csw_p = (unsigned short*)alloc(256 * 128 * 2);
  unsigned short* W1csw_c = (unsigned short*)alloc(256 * 128 * 2);
  unsigned short* W1stg_a = (unsigned short*)alloc(12 * 8192 * 2);
  unsigned short* W2stg_p = (unsigned short*)alloc(8 * 4096 * 2);
  unsigned short* W2stg_c = (unsigned short*)alloc(8 * 4096 * 2);
  unsigned short* W2stg_a = (unsigned short*)alloc(8 * 4096 * 2);
  unsigned short* W1t_v   = (unsigned short*)alloc(256 * 128 * 2);
  unsigned short* W2t_v   = (unsigned short*)alloc(128 * 256 * 2);
  unsigned short* W2sw_e  = (unsigned short*)alloc(128 * 256 * 2);

  float* hidden = (float*)d_out;

  const int EB = N_EDGES / 64;          // 6250
  const int NB = (N_NODES + 63) / 64;   // 782

  // counts -> rcp; exclusive-scan -> cursors; scatter to sorted arrays
  hipMemsetAsync(cnt_p, 0, (size_t)N_NODES * 4, stream);
  hipMemsetAsync(cnt_c, 0, (size_t)N_NODES * 4, stream);
  counti_kernel<<<(N_EDGES + 255) / 256, 256, 0, stream>>>(pn, cn, cnt_p, cnt_c);
  rcpi_kernel<<<(N_NODES + 255) / 256, 256, 0, stream>>>(cnt_p, cnt_c, rcp_p, rcp_c);
  scan_kernel<<<1, 1024, 0, stream>>>(cnt_p, cur_p);
  scan_kernel<<<1, 1024, 0, stream>>>(cnt_c, cur_c);
  scatter_kernel<<<(N_EDGES + 255) / 256, 256, 0, stream>>>(pn, cn, indP, cur_p,
                                                            sn0_p, sn1_p, sx_p);
  scatter_kernel<<<(N_EDGES + 255) / 256, 256, 0, stream>>>(cn, pn, indC, cur_c,
                                                            sn0_c, sn1_c, sx_c);

  // weight prep
  transpose_w<<<(128 * 256 + 255) / 256, 256, 0, stream>>>(vW1, W1t_v, 128, 256);
  transpose_w<<<(256 * 128 + 255) / 256, 256, 0, stream>>>(vW2, W2t_v, 256, 128);
  build_w2sw<<<(128 * 256 + 255) / 256, 256, 0, stream>>>(eW2, W2sw_e);
  build_w1stg<<<(384 * 256 + 255) / 256, 256, 0, stream>>>(aW1, W1stg_a);
  build_w2stg<<<(256 * 128 + 255) / 256, 256, 0, stream>>>(pW2, W2stg_p);
  build_w2stg<<<(256 * 128 + 255) / 256, 256, 0, stream>>>(cW2, W2stg_c);
  build_w2stg<<<(256 * 128 + 255) / 256, 256, 0, stream>>>(aW2, W2stg_a);
  const int SWB = (256 * 128 + 255) / 256;
  build_w128_sw<<<SWB, 256, 0, stream>>>(pW1, 0,   Wbig_p + 0 * 256 * 128);
  build_w128_sw<<<SWB, 256, 0, stream>>>(pW1, 128, Wbig_p + 1 * 256 * 128);
  build_w128_sw<<<SWB, 256, 0, stream>>>(cW1, 0,   Wbig_c + 0 * 256 * 128);
  build_w128_sw<<<SWB, 256, 0, stream>>>(cW1, 128, Wbig_c + 1 * 256 * 128);
  build_w128_sw<<<SWB, 256, 0, stream>>>(pW1, 256, W1csw_p);
  build_w128_sw<<<SWB, 256, 0, stream>>>(cW1, 256, W1csw_c);

  // edge-scalar tables
  make_samples<<<(4160 + 255) / 256, 256, 0, stream>>>(xsamp);
  edge_feat_kernel<<<65, 256, 0, stream>>>(xsamp, eW1, eb1, W2sw_e, eb2, fsamp, 65);
  tab_gemm_kernel<<<65, 256, 0, stream>>>(fsamp, W1csw_p, pb1, Tp);
  tab_gemm_kernel<<<65, 256, 0, stream>>>(fsamp, W1csw_c, cb1, Tc);

  // initial hidden
  v_mlp_kernel<<<NB, 256, 0, stream>>>(batch_token, W1t_v, vb1, W2t_v, vb2, hidden);

  for (int hop = 0; hop < 3; ++hop) {
    hipMemsetAsync(Sp, 0, (size_t)N_NODES * 128 * 4, stream);
    hipMemsetAsync(Sc, 0, (size_t)N_NODES * 128 * 4, stream);
    // p-dir: A=[hc|hp|ep]; n0=cn (pW1 k0..127), n1=pn (k128..255); target pn
    z_gemm_kernel<<<dim3(256, 2), 256, 0, stream>>>(hidden, Wbig_p, Zall);
    edge_msg4_kernel<<<EB, 256, 0, stream>>>(Zall, sn0_p, sn1_p, sx_p, Tp,
                                             W2stg_p, pb2, Sp, rcp_p);
    // c-dir: A=[hp|hc|ec]; target cn
    z_gemm_kernel<<<dim3(256, 2), 256, 0, stream>>>(hidden, Wbig_c, Zall);
    edge_msg4_kernel<<<EB, 256, 0, stream>>>(Zall, sn0_c, sn1_c, sx_c, Tc,
                                             W2stg_c, cb2, Sc, rcp_c);
    aggr_kernel<<<NB, 256, 0, stream>>>(hidden, Sp, Sc, p_mask, c_mask,
                                        stok, etok, W1stg_a, ab1, W2stg_a, ab2);
  }
  (void)in_sizes; (void)n_in; (void)out_size; (void)ws_size;
}

// Round 8
// 1602.499 us; speedup vs baseline: 4.0304x; 1.0628x over previous
//
#include <hip/hip_runtime.h>
#include <stdint.h>

#define N_NODES 50000
#define N_EDGES 400000
#define M_TAB 4096          // table intervals; rows 0..4096 (nearest sample)

typedef short s8v __attribute__((ext_vector_type(8)));
typedef float f4v __attribute__((ext_vector_type(4)));

static __device__ __forceinline__ unsigned short f2bf(float f) {
  union { float f; uint32_t u; } v; v.f = f;
  return (unsigned short)((v.u + 0x7FFFu + ((v.u >> 16) & 1u)) >> 16);
}
static __device__ __forceinline__ ushort4 f2bf4(float4 v) {
  ushort4 o; o.x = f2bf(v.x); o.y = f2bf(v.y); o.z = f2bf(v.z); o.w = f2bf(v.w);
  return o;
}
static __device__ __forceinline__ void bf2(uint32_t u, float& a, float& b) {
  union { uint32_t x; float f; } lo, hi;
  lo.x = u << 16; hi.x = u & 0xffff0000u;
  a = lo.f; b = hi.f;
}
static __device__ __forceinline__ f4v mfma16(s8v a, s8v b, f4v c) {
  return __builtin_amdgcn_mfma_f32_16x16x32_bf16(a, b, c, 0, 0, 0);
}
// async global->LDS, 16B/lane; LDS dest = wave-uniform base + lane*16
static __device__ __forceinline__ void gload_lds16(const void* g, void* l) {
  __builtin_amdgcn_global_load_lds(
      (const __attribute__((address_space(1))) uint32_t*)g,
      (__attribute__((address_space(3))) uint32_t*)l, 16, 0, 0);
}

// =====================================================================
// Z-GEMM, 4 groups fused: Z[n][g*256+c] = sum_k bf16(hid[n][k]) * Wg[k][c]
// groups: 0=pW1[0:128], 1=pW1[128:256], 2=cW1[0:128], 3=cW1[128:256]
// =====================================================================
__global__ __launch_bounds__(256) void z_gemm_kernel(
    const float* __restrict__ hid, const unsigned short* __restrict__ Wsw,
    unsigned short* __restrict__ Z)
{
  __shared__ __align__(16) unsigned short B[256 * 128];
  const int tid = threadIdx.x, lane = tid & 63, wv = tid >> 6;
  const int g = blockIdx.y;
  const unsigned short* src = Wsw + (size_t)g * 256 * 128;
#pragma unroll
  for (int it = 0; it < 16; ++it) {
    int q = it * 4 + wv;
    gload_lds16(src + (size_t)q * 512 + lane * 8, &B[q * 512]);
  }
  __syncthreads();
  const int l15 = lane & 15, kg = lane >> 4;
  const f4v vz = {0.f, 0.f, 0.f, 0.f};
  for (int c0 = blockIdx.x; c0 < (N_NODES + 63) / 64; c0 += gridDim.x) {
    const int base = c0 * 64;
    const int row = base + wv * 16 + l15;
    s8v af[4];
#pragma unroll
    for (int k = 0; k < 4; ++k) {
      float4 u0 = {0.f,0.f,0.f,0.f}, u1 = {0.f,0.f,0.f,0.f};
      if (row < N_NODES) {
        u0 = *(const float4*)(hid + (size_t)row * 128 + k * 32 + kg * 8);
        u1 = *(const float4*)(hid + (size_t)row * 128 + k * 32 + kg * 8 + 4);
      }
      s8v a;
      a[0] = (short)f2bf(u0.x); a[1] = (short)f2bf(u0.y);
      a[2] = (short)f2bf(u0.z); a[3] = (short)f2bf(u0.w);
      a[4] = (short)f2bf(u1.x); a[5] = (short)f2bf(u1.y);
      a[6] = (short)f2bf(u1.z); a[7] = (short)f2bf(u1.w);
      af[k] = a;
    }
    f4v acc[16];
#pragma unroll
    for (int t = 0; t < 16; ++t) acc[t] = vz;
#pragma unroll
    for (int k = 0; k < 4; ++k) {
#pragma unroll
      for (int t = 0; t < 16; ++t) {
        int j = t * 16 + l15;
        s8v b = *(const s8v*)(&B[j * 128 + (((k * 4 + kg) ^ (j & 7)) * 8)]);
        acc[t] = mfma16(af[k], b, acc[t]);
      }
    }
#pragma unroll
    for (int t = 0; t < 16; ++t) {
      int c = t * 16 + l15;
#pragma unroll
      for (int j = 0; j < 4; ++j) {
        int ro = base + wv * 16 + kg * 4 + j;
        if (ro < N_NODES) Z[(size_t)ro * 1024 + g * 256 + c] = f2bf(acc[t][j]);
      }
    }
  }
}

// =====================================================================
// Table GEMM (proven v6/v7)
// =====================================================================
__global__ __launch_bounds__(256) void tab_gemm_kernel(
    const unsigned short* __restrict__ feat,
    const unsigned short* __restrict__ Wsw,
    const float* __restrict__ b1, unsigned short* __restrict__ T)
{
  __shared__ __align__(16) unsigned short B[256 * 128];
  const int tid = threadIdx.x, lane = tid & 63, wv = tid >> 6;
#pragma unroll
  for (int it = 0; it < 16; ++it) {
    int q = it * 4 + wv;
    gload_lds16(Wsw + (size_t)q * 512 + lane * 8, &B[q * 512]);
  }
  __syncthreads();
  const int l15 = lane & 15, kg = lane >> 4;
  const int base = blockIdx.x * 64;
  const int row = base + wv * 16 + l15;
  s8v af[4];
#pragma unroll
  for (int k = 0; k < 4; ++k)
    af[k] = *(const s8v*)(feat + (size_t)row * 128 + k * 32 + kg * 8);
  const f4v vz = {0.f, 0.f, 0.f, 0.f};
  f4v acc[16];
#pragma unroll
  for (int t = 0; t < 16; ++t) acc[t] = vz;
#pragma unroll
  for (int k = 0; k < 4; ++k) {
#pragma unroll
    for (int t = 0; t < 16; ++t) {
      int j = t * 16 + l15;
      s8v b = *(const s8v*)(&B[j * 128 + (((k * 4 + kg) ^ (j & 7)) * 8)]);
      acc[t] = mfma16(af[k], b, acc[t]);
    }
  }
#pragma unroll
  for (int t = 0; t < 16; ++t) {
    int c = t * 16 + l15;
    float bb = b1[c];
#pragma unroll
    for (int j = 0; j < 4; ++j) {
      int ro = base + wv * 16 + kg * 4 + j;
      T[(size_t)ro * 256 + c] = f2bf(acc[t][j] + bb);
    }
  }
}

// =====================================================================
// Edge message, SORTED, nearest-sample table:
//   H1 = relu(Z[sn0][off0..] + Z[sn1][off1..] + T[round(x*M)])
//   out = relu(H1 @ W2 + b2) -> LDS f32 -> run-reduce over equal sn1
//   -> atomicAdd(Sacc[n], run_sum * rcp[n])
// =====================================================================
__global__ __launch_bounds__(256) void edge_msg5_kernel(
    const unsigned short* __restrict__ Z,   // [N][1024]
    const int* __restrict__ sn0, const int* __restrict__ sn1,
    const float* __restrict__ sx,
    const unsigned short* __restrict__ T,   // [4097][256]
    int off0, int off1,
    const unsigned short* __restrict__ W2stg, const float* __restrict__ b2,
    float* __restrict__ Sacc, const float* __restrict__ rcpv)
{
  __shared__ __align__(16) unsigned short H1[64 * 256];  // 32KB; reused as f32 OUT
  __shared__ __align__(16) unsigned short Wb[2][4096];   // 16KB
  __shared__ int n0s[64], n1s[64], tix[64];
  __shared__ float tsc[64];
  const int tid = threadIdx.x, lane = tid & 63, wv = tid >> 6;
  const int l15 = lane & 15, kg = lane >> 4;
  const int base = blockIdx.x * 64;  // E % 64 == 0
  if (tid < 64) {
    int e = base + tid;
    int a0 = sn0[e], a1 = sn1[e];
    n0s[tid] = a0; n1s[tid] = a1; tsc[tid] = rcpv[a1];
    float x = sx[e];
    int idx = (int)(x * (float)M_TAB + 0.5f);
    tix[tid] = idx < 0 ? 0 : (idx > M_TAB ? M_TAB : idx);
  }
  // stage W2 slice 0
#pragma unroll
  for (int i = 0; i < 2; ++i) {
    int q = wv * 2 + i;
    gload_lds16(W2stg + (size_t)q * 512 + lane * 8, &Wb[0][q * 512]);
  }
  __syncthreads();
  // build H1 = relu(Za + Zb + T) (swizzled 16B units)
#pragma unroll
  for (int it = 0; it < 8; ++it) {
    int i = tid + it * 256;
    int r = i >> 5, c8 = i & 31;
    const uint4 za = *(const uint4*)(Z + (size_t)n0s[r] * 1024 + off0 + c8 * 8);
    const uint4 zb = *(const uint4*)(Z + (size_t)n1s[r] * 1024 + off1 + c8 * 8);
    const uint4 t0 = *(const uint4*)(T + (size_t)tix[r] * 256 + c8 * 8);
    uint32_t ua[4] = {za.x, za.y, za.z, za.w};
    uint32_t ub[4] = {zb.x, zb.y, zb.z, zb.w};
    uint32_t u0[4] = {t0.x, t0.y, t0.z, t0.w};
    uint32_t uo[4];
#pragma unroll
    for (int q = 0; q < 4; ++q) {
      float a0, a1, b0, b1f, p0, p1;
      bf2(ua[q], a0, a1); bf2(ub[q], b0, b1f); bf2(u0[q], p0, p1);
      float s0 = fmaxf(a0 + b0 + p0, 0.f);
      float s1 = fmaxf(a1 + b1f + p1, 0.f);
      uo[q] = (uint32_t)f2bf(s0) | ((uint32_t)f2bf(s1) << 16);
    }
    uint4 pk; pk.x = uo[0]; pk.y = uo[1]; pk.z = uo[2]; pk.w = uo[3];
    *(uint4*)(H1 + r * 256 + ((c8 ^ (r & 7)) * 8)) = pk;
  }
  __syncthreads();
  // layer 2: [64,256] @ W2 -> [64,128], 8 staged K-phases
  const int rr = wv * 16 + l15;
  s8v af2[8];
#pragma unroll
  for (int k = 0; k < 8; ++k)
    af2[k] = *(const s8v*)(H1 + rr * 256 + (((k * 4 + kg) ^ (l15 & 7)) * 8));
  const f4v vz = {0.f, 0.f, 0.f, 0.f};
  f4v acc2[8];
#pragma unroll
  for (int t = 0; t < 8; ++t) acc2[t] = vz;
#pragma unroll
  for (int s = 0; s < 8; ++s) {
    if (s < 7) {
#pragma unroll
      for (int i = 0; i < 2; ++i) {
        int q = wv * 2 + i;
        gload_lds16(W2stg + (size_t)(s + 1) * 4096 + q * 512 + lane * 8,
                    &Wb[(s + 1) & 1][q * 512]);
      }
    }
#pragma unroll
    for (int t = 0; t < 8; ++t) {
      s8v b = *(const s8v*)(&Wb[s & 1][kg * 1024 + (t * 16 + l15) * 8]);
      acc2[t] = mfma16(af2[s], b, acc2[t]);
    }
    __syncthreads();
  }
  // per-edge out (bias+relu) -> f32 LDS (aliases H1)
  float* OUT = (float*)H1;
#pragma unroll
  for (int t = 0; t < 8; ++t) {
    int c = t * 16 + l15;
    float bb = b2[c];
#pragma unroll
    for (int j = 0; j < 4; ++j) {
      int r = wv * 16 + kg * 4 + j;
      OUT[r * 128 + c] = fmaxf(acc2[t][j] + bb, 0.f);
    }
  }
  __syncthreads();
  // run-reduction over equal targets (sorted): thread = (col, half)
  {
    const int c = tid & 127, h = tid >> 7;
    const int r0 = h * 32;
    float acc = 0.f;
    int cur = n1s[r0];
    float curs = tsc[r0];
    for (int r = r0; r < r0 + 32; ++r) {
      int nn = n1s[r];
      if (nn != cur) {
        atomicAdd(Sacc + (size_t)cur * 128 + c, acc * curs);
        acc = 0.f; cur = nn; curs = tsc[r];
      }
      acc += OUT[r * 128 + c];
    }
    atomicAdd(Sacc + (size_t)cur * 128 + c, acc * curs);
  }
}

// =====================================================================
// Aggr MLP (proven v4..v7)
// =====================================================================
__global__ __launch_bounds__(256, 2) void aggr_kernel(
    float* __restrict__ hid,
    const float* __restrict__ Sp, const float* __restrict__ Sc,
    const float* __restrict__ pm, const float* __restrict__ cm,
    const float* __restrict__ st, const float* __restrict__ et,
    const unsigned short* __restrict__ W1stg, const float* __restrict__ b1,
    const unsigned short* __restrict__ W2stg, const float* __restrict__ b2)
{
  __shared__ __align__(16) unsigned short ABUF[64 * 384];
  __shared__ __align__(16) unsigned short Wb[2][8192];
  const int tid = threadIdx.x, lane = tid & 63, wv = tid >> 6;
  const int l15 = lane & 15, kg = lane >> 4;
  const int base = blockIdx.x * 64;
#pragma unroll
  for (int i = 0; i < 4; ++i) {
    int q = wv * 4 + i;
    gload_lds16(W1stg + (size_t)q * 512 + lane * 8, &Wb[0][q * 512]);
  }
#pragma unroll
  for (int it = 0; it < 24; ++it) {
    int i = tid + it * 256;
    int r = i / 96, q = i - r * 96;
    int seg = q >> 5, c4 = q & 31;
    int n = base + r;
    float4 v = {0.f, 0.f, 0.f, 0.f};
    if (n < N_NODES) {
      if (seg == 0) {
        v = *(const float4*)(hid + (size_t)n * 128 + c4 * 4);
      } else if (seg == 1) {
        v = *(const float4*)(Sp + (size_t)n * 128 + c4 * 4);
        float m = pm[n]; const float4 t = *(const float4*)(st + c4 * 4);
        v.x = fmaf(m, t.x, v.x); v.y = fmaf(m, t.y, v.y);
        v.z = fmaf(m, t.z, v.z); v.w = fmaf(m, t.w, v.w);
      } else {
        v = *(const float4*)(Sc + (size_t)n * 128 + c4 * 4);
        float m = cm[n]; const float4 t = *(const float4*)(et + c4 * 4);
        v.x = fmaf(m, t.x, v.x); v.y = fmaf(m, t.y, v.y);
        v.z = fmaf(m, t.z, v.z); v.w = fmaf(m, t.w, v.w);
      }
    }
    int unit = seg * 16 + (c4 >> 1);
    *(ushort4*)(ABUF + r * 384 + ((unit ^ (r & 7)) * 8) + (c4 & 1) * 4) = f2bf4(v);
  }
  __syncthreads();
  const int rr = wv * 16 + l15;
  s8v af1[12];
#pragma unroll
  for (int k = 0; k < 12; ++k)
    af1[k] = *(const s8v*)(ABUF + rr * 384 + (((k * 4 + kg) ^ (rr & 7)) * 8));
  const f4v vz = {0.f, 0.f, 0.f, 0.f};
  f4v acc1[16];
#pragma unroll
  for (int t = 0; t < 16; ++t) acc1[t] = vz;
#pragma unroll
  for (int s = 0; s < 12; ++s) {
    if (s < 11) {
#pragma unroll
      for (int i = 0; i < 4; ++i) {
        int q = wv * 4 + i;
        gload_lds16(W1stg + (size_t)(s + 1) * 8192 + q * 512 + lane * 8,
                    &Wb[(s + 1) & 1][q * 512]);
      }
    } else {
#pragma unroll
      for (int i = 0; i < 2; ++i) {
        int q = wv * 2 + i;
        gload_lds16(W2stg + (size_t)q * 512 + lane * 8, &Wb[0][q * 512]);
      }
    }
#pragma unroll
    for (int t = 0; t < 16; ++t) {
      s8v b = *(const s8v*)(&Wb[s & 1][kg * 2048 + (t * 16 + l15) * 8]);
      acc1[t] = mfma16(af1[s], b, acc1[t]);
    }
    __syncthreads();
  }
#pragma unroll
  for (int t = 0; t < 16; ++t) {
    int c = t * 16 + l15;
    float bb = b1[c];
#pragma unroll
    for (int j = 0; j < 4; ++j) {
      int r = wv * 16 + kg * 4 + j;
      ABUF[r * 256 + (((c >> 3) ^ (r & 7)) * 8) + (c & 7)] =
          f2bf(fmaxf(acc1[t][j] + bb, 0.f));
    }
  }
  __syncthreads();
  s8v af2[8];
#pragma unroll
  for (int k = 0; k < 8; ++k)
    af2[k] = *(const s8v*)(ABUF + rr * 256 + (((k * 4 + kg) ^ (l15 & 7)) * 8));
  f4v acc2[8];
#pragma unroll
  for (int t = 0; t < 8; ++t) acc2[t] = vz;
#pragma unroll
  for (int s = 0; s < 8; ++s) {
    if (s < 7) {
#pragma unroll
      for (int i = 0; i < 2; ++i) {
        int q = wv * 2 + i;
        gload_lds16(W2stg + (size_t)(s + 1) * 4096 + q * 512 + lane * 8,
                    &Wb[(s + 1) & 1][q * 512]);
      }
    }
#pragma unroll
    for (int t = 0; t < 8; ++t) {
      s8v b = *(const s8v*)(&Wb[s & 1][kg * 1024 + (t * 16 + l15) * 8]);
      acc2[t] = mfma16(af2[s], b, acc2[t]);
    }
    __syncthreads();
  }
#pragma unroll
  for (int t = 0; t < 8; ++t) {
    int c = t * 16 + l15;
    float bb = b2[c];
#pragma unroll
    for (int j = 0; j < 4; ++j) {
      int ro = base + wv * 16 + kg * 4 + j;
      if (ro < N_NODES) hid[(size_t)ro * 128 + c] += fmaxf(acc2[t][j] + bb, 0.f);
    }
  }
}

// =====================================================================
// edge-scalar MLP (proven) — only for the 65 table-sample tiles
// =====================================================================
__global__ __launch_bounds__(256) void edge_feat_kernel(
    const float* __restrict__ ind, const float* __restrict__ W1,
    const float* __restrict__ b1,
    const unsigned short* __restrict__ W2sw,
    const float* __restrict__ b2, unsigned short* __restrict__ feat,
    int ntiles)
{
  __shared__ __align__(16) unsigned short B[128 * 256];  // 64KB
  __shared__ unsigned short H1[64 * 264];
  __shared__ float xs[64];
  const int tid = threadIdx.x, lane = tid & 63, wv = tid >> 6;
  const int l15 = lane & 15, kg = lane >> 4;
#pragma unroll
  for (int it = 0; it < 16; ++it) {
    int q = it * 4 + wv;
    gload_lds16(W2sw + (size_t)q * 512 + lane * 8, &B[q * 512]);
  }
  const float w = W1[tid], bb1 = b1[tid];
  const f4v vz = {0.f, 0.f, 0.f, 0.f};
  for (int tile = blockIdx.x; tile < ntiles; tile += gridDim.x) {
    const int base = tile * 64;
    if (tid < 64) xs[tid] = ind[base + tid];
    __syncthreads();
    for (int r = 0; r < 64; ++r)
      H1[r * 264 + tid] = f2bf(fmaxf(fmaf(xs[r], w, bb1), 0.f));
    __syncthreads();
    const unsigned short* Hrow = H1 + (size_t)(wv * 16 + l15) * 264;
    s8v af2[8];
#pragma unroll
    for (int k = 0; k < 8; ++k) af2[k] = *(const s8v*)(Hrow + k * 32 + kg * 8);
    f4v acc2[8];
#pragma unroll
    for (int t = 0; t < 8; ++t) acc2[t] = vz;
#pragma unroll
    for (int k = 0; k < 8; ++k) {
#pragma unroll
      for (int t = 0; t < 8; ++t) {
        int j = t * 16 + l15;
        s8v b = *(const s8v*)(&B[j * 256 + (((k * 4 + kg) ^ (j & 7)) * 8)]);
        acc2[t] = mfma16(af2[k], b, acc2[t]);
      }
    }
#pragma unroll
    for (int t = 0; t < 8; ++t) {
      int c = t * 16 + l15;
      float b2c = b2[c];
#pragma unroll
      for (int j = 0; j < 4; ++j) {
        int e = base + wv * 16 + kg * 4 + j;
        feat[(size_t)e * 128 + c] = f2bf(fmaxf(acc2[t][j] + b2c, 0.f));
      }
    }
    __syncthreads();
  }
}

// =====================================================================
// one-time v MLP (proven)
// =====================================================================
template <int KST1>
static __device__ __forceinline__ void mlp_core(
    unsigned short* __restrict__ BUF,
    const unsigned short* __restrict__ W1t, const float* __restrict__ b1,
    const unsigned short* __restrict__ W2t,
    int l15, int kg, int wr0, f4v* __restrict__ acc2)
{
  const int ldA = KST1 * 32 + 8;
  const f4v vzero = {0.f, 0.f, 0.f, 0.f};
  const unsigned short* Arow = BUF + (size_t)(wr0 + l15) * ldA;
  s8v af1[KST1];
#pragma unroll
  for (int k = 0; k < KST1; ++k) af1[k] = *(const s8v*)(Arow + k * 32 + kg * 8);
  __syncthreads();
  f4v acc1[16];
#pragma unroll
  for (int t = 0; t < 16; ++t) acc1[t] = vzero;
#pragma unroll
  for (int k = 0; k < KST1; ++k) {
#pragma unroll
    for (int t = 0; t < 16; ++t) {
      s8v b = *(const s8v*)(W1t + (size_t)(t * 16 + l15) * (KST1 * 32) + k * 32 + kg * 8);
      acc1[t] = mfma16(af1[k], b, acc1[t]);
    }
  }
#pragma unroll
  for (int t = 0; t < 16; ++t) {
    int c = t * 16 + l15;
    float bb = b1[c];
#pragma unroll
    for (int j = 0; j < 4; ++j) {
      BUF[(size_t)(wr0 + kg * 4 + j) * 264 + c] = f2bf(fmaxf(acc1[t][j] + bb, 0.f));
    }
  }
  const unsigned short* Hrow = BUF + (size_t)(wr0 + l15) * 264;
  s8v af2[8];
#pragma unroll
  for (int k = 0; k < 8; ++k) af2[k] = *(const s8v*)(Hrow + k * 32 + kg * 8);
#pragma unroll
  for (int t = 0; t < 8; ++t) acc2[t] = vzero;
#pragma unroll
  for (int k = 0; k < 8; ++k) {
#pragma unroll
    for (int t = 0; t < 8; ++t) {
      s8v b = *(const s8v*)(W2t + (size_t)(t * 16 + l15) * 256 + k * 32 + kg * 8);
      acc2[t] = mfma16(af2[k], b, acc2[t]);
    }
  }
}

__global__ __launch_bounds__(256, 2) void v_mlp_kernel(
    const float* __restrict__ x,
    const unsigned short* __restrict__ W1t, const float* __restrict__ b1,
    const unsigned short* __restrict__ W2t, const float* __restrict__ b2,
    float* __restrict__ hid)
{
  __shared__ unsigned short BUF[64 * 264];
  const int tid = threadIdx.x;
  const int base = blockIdx.x * 64;
#pragma unroll
  for (int it = 0; it < 8; ++it) {
    int i = tid + it * 256;
    int r = i >> 5, c4 = i & 31, n = base + r;
    float4 v = {0.f, 0.f, 0.f, 0.f};
    if (n < N_NODES) v = *(const float4*)(x + (size_t)n * 128 + c4 * 4);
    *(ushort4*)(BUF + r * 136 + c4 * 4) = f2bf4(v);
  }
  __syncthreads();
  const int lane = tid & 63, wv = tid >> 6;
  const int l15 = lane & 15, kg = lane >> 4, wr0 = wv * 16;
  f4v acc2[8];
  mlp_core<4>(BUF, W1t, b1, W2t, l15, kg, wr0, acc2);
#pragma unroll
  for (int t = 0; t < 8; ++t) {
    int c = t * 16 + l15;
    float bb = b2[c];
#pragma unroll
    for (int j = 0; j < 4; ++j) {
      int n = base + wr0 + kg * 4 + j;
      if (n < N_NODES) hid[(size_t)n * 128 + c] = fmaxf(acc2[t][j] + bb, 0.f);
    }
  }
}

// ---------------- sorting + prep kernels (proven v7) ----------------
__global__ void counti_kernel(const int* __restrict__ pn, const int* __restrict__ cn,
                              int* __restrict__ cp, int* __restrict__ cc) {
  int i = blockIdx.x * 256 + threadIdx.x;
  if (i < N_EDGES) {
    atomicAdd(cp + pn[i], 1);
    atomicAdd(cc + cn[i], 1);
  }
}

__global__ void rcpi_kernel(const int* __restrict__ cp, const int* __restrict__ cc,
                            float* __restrict__ rp, float* __restrict__ rc) {
  int i = blockIdx.x * 256 + threadIdx.x;
  if (i < N_NODES) {
    rp[i] = 1.f / fmaxf((float)cp[i], 1.f);
    rc[i] = 1.f / fmaxf((float)cc[i], 1.f);
  }
}

__global__ void scan_kernel(const int* __restrict__ cnt, int* __restrict__ cur) {
  __shared__ int part[1024];
  const int t = threadIdx.x;
  const int CH = (N_NODES + 1023) / 1024;  // 49
  int s = 0;
#pragma unroll 1
  for (int i = 0; i < CH; ++i) {
    int idx = t * CH + i;
    if (idx < N_NODES) s += cnt[idx];
  }
  part[t] = s;
  __syncthreads();
  for (int d = 1; d < 1024; d <<= 1) {
    int v = (t >= d) ? part[t - d] : 0;
    __syncthreads();
    part[t] += v;
    __syncthreads();
  }
  int run = part[t] - s;
#pragma unroll 1
  for (int i = 0; i < CH; ++i) {
    int idx = t * CH + i;
    if (idx < N_NODES) { cur[idx] = run; run += cnt[idx]; }
  }
}

__global__ void scatter_kernel(const int* __restrict__ tgt, const int* __restrict__ oth,
                               const float* __restrict__ x, int* __restrict__ cursor,
                               int* __restrict__ sn0, int* __restrict__ sn1,
                               float* __restrict__ sx) {
  int e = blockIdx.x * 256 + threadIdx.x;
  if (e < N_EDGES) {
    int tN = tgt[e];
    int pos = atomicAdd(cursor + tN, 1);
    sn0[pos] = oth[e];
    sn1[pos] = tN;
    sx[pos] = x[e];
  }
}

__global__ void transpose_w(const float* __restrict__ W, unsigned short* __restrict__ Wt,
                            int K, int NH) {
  int i = blockIdx.x * 256 + threadIdx.x;
  if (i < K * NH) {
    int k = i / NH, n = i - k * NH;
    Wt[(size_t)n * K + k] = f2bf(W[i]);
  }
}

__global__ void build_w1stg(const float* __restrict__ W, unsigned short* __restrict__ stg) {
  int i = blockIdx.x * 256 + threadIdx.x;
  if (i < 384 * 256) {
    int k = i >> 8, out = i & 255;
    int s = k >> 5, kc = (k >> 3) & 3, j = k & 7;
    stg[(size_t)s * 8192 + kc * 2048 + out * 8 + j] = f2bf(W[i]);
  }
}

__global__ void build_w2stg(const float* __restrict__ W, unsigned short* __restrict__ stg) {
  int i = blockIdx.x * 256 + threadIdx.x;
  if (i < 256 * 128) {
    int k = i >> 7, out = i & 127;
    int s = k >> 5, kc = (k >> 3) & 3, j = k & 7;
    stg[(size_t)s * 4096 + kc * 1024 + out * 8 + j] = f2bf(W[i]);
  }
}

__global__ void build_w128_sw(const float* __restrict__ W, int k_off,
                              unsigned short* __restrict__ dst) {
  int i = blockIdx.x * 256 + threadIdx.x;
  if (i < 256 * 128) {
    int j = i >> 7, e = i & 127;
    int unit = (e >> 3) ^ (j & 7);
    dst[(size_t)j * 128 + unit * 8 + (e & 7)] = f2bf(W[(size_t)(k_off + e) * 256 + j]);
  }
}

__global__ void build_w2sw(const float* __restrict__ W, unsigned short* __restrict__ dst) {
  int i = blockIdx.x * 256 + threadIdx.x;
  if (i < 128 * 256) {
    int j = i >> 8, k = i & 255;
    dst[(size_t)j * 256 + (((k >> 3) ^ (j & 7)) * 8) + (k & 7)] =
        f2bf(W[(size_t)k * 128 + j]);
  }
}

__global__ void make_samples(float* __restrict__ xs) {
  int i = blockIdx.x * 256 + threadIdx.x;
  if (i < 4160) {
    int s = i < M_TAB ? i : M_TAB;
    xs[i] = (float)s * (1.f / (float)M_TAB);
  }
}

extern "C" void kernel_launch(void* const* d_in, const int* in_sizes, int n_in,
                              void* d_out, int out_size, void* d_ws, size_t ws_size,
                              hipStream_t stream) {
  const float* batch_token = (const float*)d_in[0];
  const int*   pn          = (const int*)d_in[1];
  const int*   cn          = (const int*)d_in[2];
  const float* indP        = (const float*)d_in[3];
  const float* indC        = (const float*)d_in[4];
  const float* p_mask      = (const float*)d_in[5];
  const float* c_mask      = (const float*)d_in[6];
  const float* stok        = (const float*)d_in[7];
  const float* etok        = (const float*)d_in[8];
  const float* vW1 = (const float*)d_in[9],  *vb1 = (const float*)d_in[10];
  const float* vW2 = (const float*)d_in[11], *vb2 = (const float*)d_in[12];
  const float* eW1 = (const float*)d_in[13], *eb1 = (const float*)d_in[14];
  const float* eW2 = (const float*)d_in[15], *eb2 = (const float*)d_in[16];
  const float* pW1 = (const float*)d_in[17], *pb1 = (const float*)d_in[18];
  const float* pW2 = (const float*)d_in[19], *pb2 = (const float*)d_in[20];
  const float* cW1 = (const float*)d_in[21], *cb1 = (const float*)d_in[22];
  const float* cW2 = (const float*)d_in[23], *cb2 = (const float*)d_in[24];
  const float* aW1 = (const float*)d_in[25], *ab1 = (const float*)d_in[26];
  const float* aW2 = (const float*)d_in[27], *ab2 = (const float*)d_in[28];

  char* w = (char*)d_ws;
  auto alloc = [&](size_t bytes) -> char* {
    char* p = w;
    w += (bytes + 255) & ~(size_t)255;
    return p;
  };
  // total ~172 MB (proven budget >=257 MB)
  float* Sp    = (float*)alloc((size_t)N_NODES * 128 * 4);
  float* Sc    = (float*)alloc((size_t)N_NODES * 128 * 4);
  float* rcp_p = (float*)alloc((size_t)N_NODES * 4);
  float* rcp_c = (float*)alloc((size_t)N_NODES * 4);
  int*   cnt_p = (int*)alloc((size_t)N_NODES * 4);
  int*   cnt_c = (int*)alloc((size_t)N_NODES * 4);
  int*   cur_p = (int*)alloc((size_t)N_NODES * 4);
  int*   cur_c = (int*)alloc((size_t)N_NODES * 4);
  int*   sn0_p = (int*)alloc((size_t)N_EDGES * 4);
  int*   sn1_p = (int*)alloc((size_t)N_EDGES * 4);
  float* sx_p  = (float*)alloc((size_t)N_EDGES * 4);
  int*   sn0_c = (int*)alloc((size_t)N_EDGES * 4);
  int*   sn1_c = (int*)alloc((size_t)N_EDGES * 4);
  float* sx_c  = (float*)alloc((size_t)N_EDGES * 4);
  unsigned short* Zall   = (unsigned short*)alloc((size_t)N_NODES * 1024 * 2); // 102.4MB
  unsigned short* fsamp  = (unsigned short*)alloc((size_t)4160 * 128 * 2);
  unsigned short* Tp     = (unsigned short*)alloc((size_t)4160 * 256 * 2);
  unsigned short* Tc     = (unsigned short*)alloc((size_t)4160 * 256 * 2);
  float*          xsamp  = (float*)alloc((size_t)4160 * 4);
  unsigned short* Wbig   = (unsigned short*)alloc((size_t)4 * 256 * 128 * 2);
  unsigned short* W1csw_p = (unsigned short*)alloc(256 * 128 * 2);
  unsigned short* W1csw_c = (unsigned short*)alloc(256 * 128 * 2);
  unsigned short* W1stg_a = (unsigned short*)alloc(12 * 8192 * 2);
  unsigned short* W2stg_p = (unsigned short*)alloc(8 * 4096 * 2);
  unsigned short* W2stg_c = (unsigned short*)alloc(8 * 4096 * 2);
  unsigned short* W2stg_a = (unsigned short*)alloc(8 * 4096 * 2);
  unsigned short* W1t_v   = (unsigned short*)alloc(256 * 128 * 2);
  unsigned short* W2t_v   = (unsigned short*)alloc(128 * 256 * 2);
  unsigned short* W2sw_e  = (unsigned short*)alloc(128 * 256 * 2);

  float* hidden = (float*)d_out;

  const int EB = N_EDGES / 64;          // 6250
  const int NB = (N_NODES + 63) / 64;   // 782

  // counts -> rcp; exclusive-scan -> cursors; scatter to sorted arrays
  hipMemsetAsync(cnt_p, 0, (size_t)N_NODES * 4, stream);
  hipMemsetAsync(cnt_c, 0, (size_t)N_NODES * 4, stream);
  counti_kernel<<<(N_EDGES + 255) / 256, 256, 0, stream>>>(pn, cn, cnt_p, cnt_c);
  rcpi_kernel<<<(N_NODES + 255) / 256, 256, 0, stream>>>(cnt_p, cnt_c, rcp_p, rcp_c);
  scan_kernel<<<1, 1024, 0, stream>>>(cnt_p, cur_p);
  scan_kernel<<<1, 1024, 0, stream>>>(cnt_c, cur_c);
  scatter_kernel<<<(N_EDGES + 255) / 256, 256, 0, stream>>>(pn, cn, indP, cur_p,
                                                            sn0_p, sn1_p, sx_p);
  scatter_kernel<<<(N_EDGES + 255) / 256, 256, 0, stream>>>(cn, pn, indC, cur_c,
                                                            sn0_c, sn1_c, sx_c);

  // weight prep
  transpose_w<<<(128 * 256 + 255) / 256, 256, 0, stream>>>(vW1, W1t_v, 128, 256);
  transpose_w<<<(256 * 128 + 255) / 256, 256, 0, stream>>>(vW2, W2t_v, 256, 128);
  build_w2sw<<<(128 * 256 + 255) / 256, 256, 0, stream>>>(eW2, W2sw_e);
  build_w1stg<<<(384 * 256 + 255) / 256, 256, 0, stream>>>(aW1, W1stg_a);
  build_w2stg<<<(256 * 128 + 255) / 256, 256, 0, stream>>>(pW2, W2stg_p);
  build_w2stg<<<(256 * 128 + 255) / 256, 256, 0, stream>>>(cW2, W2stg_c);
  build_w2stg<<<(256 * 128 + 255) / 256, 256, 0, stream>>>(aW2, W2stg_a);
  const int SWB = (256 * 128 + 255) / 256;
  build_w128_sw<<<SWB, 256, 0, stream>>>(pW1, 0,   Wbig + 0 * 256 * 128);
  build_w128_sw<<<SWB, 256, 0, stream>>>(pW1, 128, Wbig + 1 * 256 * 128);
  build_w128_sw<<<SWB, 256, 0, stream>>>(cW1, 0,   Wbig + 2 * 256 * 128);
  build_w128_sw<<<SWB, 256, 0, stream>>>(cW1, 128, Wbig + 3 * 256 * 128);
  build_w128_sw<<<SWB, 256, 0, stream>>>(pW1, 256, W1csw_p);
  build_w128_sw<<<SWB, 256, 0, stream>>>(cW1, 256, W1csw_c);

  // edge-scalar tables: T*(s/M) = mlp_e(s/M) @ W1c + b1
  make_samples<<<(4160 + 255) / 256, 256, 0, stream>>>(xsamp);
  edge_feat_kernel<<<65, 256, 0, stream>>>(xsamp, eW1, eb1, W2sw_e, eb2, fsamp, 65);
  tab_gemm_kernel<<<65, 256, 0, stream>>>(fsamp, W1csw_p, pb1, Tp);
  tab_gemm_kernel<<<65, 256, 0, stream>>>(fsamp, W1csw_c, cb1, Tc);

  // initial hidden
  v_mlp_kernel<<<NB, 256, 0, stream>>>(batch_token, W1t_v, vb1, W2t_v, vb2, hidden);

  for (int hop = 0; hop < 3; ++hop) {
    hipMemsetAsync(Sp, 0, (size_t)N_NODES * 128 * 4, stream);
    hipMemsetAsync(Sc, 0, (size_t)N_NODES * 128 * 4, stream);
    // one fused Z-GEMM: groups {p:hc, p:hp, c:hp, c:hc} -> Zall[N][1024]
    z_gemm_kernel<<<dim3(256, 4), 256, 0, stream>>>(hidden, Wbig, Zall);
    // p-dir: n0=cn -> cols[0:256), n1=pn -> cols[256:512); target pn
    edge_msg5_kernel<<<EB, 256, 0, stream>>>(Zall, sn0_p, sn1_p, sx_p, Tp,
                                             0, 256, W2stg_p, pb2, Sp, rcp_p);
    // c-dir: n0=pn -> cols[512:768), n1=cn -> cols[768:1024); target cn
    edge_msg5_kernel<<<EB, 256, 0, stream>>>(Zall, sn0_c, sn1_c, sx_c, Tc,
                                             512, 768, W2stg_c, cb2, Sc, rcp_c);
    aggr_kernel<<<NB, 256, 0, stream>>>(hidden, Sp, Sc, p_mask, c_mask,
                                        stok, etok, W1stg_a, ab1, W2stg_a, ab2);
  }
  (void)in_sizes; (void)n_in; (void)out_size; (void)ws_size;
}

// Round 9
// 1598.866 us; speedup vs baseline: 4.0396x; 1.0023x over previous
//
#include <hip/hip_runtime.h>
#include <stdint.h>

#define N_NODES 50000
#define N_EDGES 400000
#define M_TAB 4096          // table intervals; rows 0..4096 (nearest sample)
#define EB_T 6250           // edge tiles per direction (E/64)

typedef short s8v __attribute__((ext_vector_type(8)));
typedef float f4v __attribute__((ext_vector_type(4)));

static __device__ __forceinline__ unsigned short f2bf(float f) {
  union { float f; uint32_t u; } v; v.f = f;
  return (unsigned short)((v.u + 0x7FFFu + ((v.u >> 16) & 1u)) >> 16);
}
static __device__ __forceinline__ ushort4 f2bf4(float4 v) {
  ushort4 o; o.x = f2bf(v.x); o.y = f2bf(v.y); o.z = f2bf(v.z); o.w = f2bf(v.w);
  return o;
}
static __device__ __forceinline__ void bf2(uint32_t u, float& a, float& b) {
  union { uint32_t x; float f; } lo, hi;
  lo.x = u << 16; hi.x = u & 0xffff0000u;
  a = lo.f; b = hi.f;
}
static __device__ __forceinline__ f4v mfma16(s8v a, s8v b, f4v c) {
  return __builtin_amdgcn_mfma_f32_16x16x32_bf16(a, b, c, 0, 0, 0);
}
// async global->LDS, 16B/lane; LDS dest = wave-uniform base + lane*16
static __device__ __forceinline__ void gload_lds16(const void* g, void* l) {
  __builtin_amdgcn_global_load_lds(
      (const __attribute__((address_space(1))) uint32_t*)g,
      (__attribute__((address_space(3))) uint32_t*)l, 16, 0, 0);
}

// =====================================================================
// Z-GEMM, 4 groups fused, bf16 A input (hidb):
//   Z[n][g*256+c] = sum_k hidb[n][k] * Wg[k][c]
// groups: 0=pW1[0:128], 1=pW1[128:256], 2=cW1[0:128], 3=cW1[128:256]
// =====================================================================
__global__ __launch_bounds__(256) void z_gemm_kernel(
    const unsigned short* __restrict__ hidb, const unsigned short* __restrict__ Wsw,
    unsigned short* __restrict__ Z)
{
  __shared__ __align__(16) unsigned short B[256 * 128];
  const int tid = threadIdx.x, lane = tid & 63, wv = tid >> 6;
  const int g = blockIdx.y;
  const unsigned short* src = Wsw + (size_t)g * 256 * 128;
#pragma unroll
  for (int it = 0; it < 16; ++it) {
    int q = it * 4 + wv;
    gload_lds16(src + (size_t)q * 512 + lane * 8, &B[q * 512]);
  }
  __syncthreads();
  const int l15 = lane & 15, kg = lane >> 4;
  const f4v vz = {0.f, 0.f, 0.f, 0.f};
  const s8v zz = {0, 0, 0, 0, 0, 0, 0, 0};
  for (int c0 = blockIdx.x; c0 < (N_NODES + 63) / 64; c0 += gridDim.x) {
    const int base = c0 * 64;
    const int row = base + wv * 16 + l15;
    s8v af[4];
    if (row < N_NODES) {
#pragma unroll
      for (int k = 0; k < 4; ++k)
        af[k] = *(const s8v*)(hidb + (size_t)row * 128 + k * 32 + kg * 8);
    } else {
#pragma unroll
      for (int k = 0; k < 4; ++k) af[k] = zz;
    }
    f4v acc[16];
#pragma unroll
    for (int t = 0; t < 16; ++t) acc[t] = vz;
#pragma unroll
    for (int k = 0; k < 4; ++k) {
#pragma unroll
      for (int t = 0; t < 16; ++t) {
        int j = t * 16 + l15;
        s8v b = *(const s8v*)(&B[j * 128 + (((k * 4 + kg) ^ (j & 7)) * 8)]);
        acc[t] = mfma16(af[k], b, acc[t]);
      }
    }
#pragma unroll
    for (int t = 0; t < 16; ++t) {
      int c = t * 16 + l15;
#pragma unroll
      for (int j = 0; j < 4; ++j) {
        int ro = base + wv * 16 + kg * 4 + j;
        if (ro < N_NODES) Z[(size_t)ro * 1024 + g * 256 + c] = f2bf(acc[t][j]);
      }
    }
  }
}

// =====================================================================
// Table GEMM (proven)
// =====================================================================
__global__ __launch_bounds__(256) void tab_gemm_kernel(
    const unsigned short* __restrict__ feat,
    const unsigned short* __restrict__ Wsw,
    const float* __restrict__ b1, unsigned short* __restrict__ T)
{
  __shared__ __align__(16) unsigned short B[256 * 128];
  const int tid = threadIdx.x, lane = tid & 63, wv = tid >> 6;
#pragma unroll
  for (int it = 0; it < 16; ++it) {
    int q = it * 4 + wv;
    gload_lds16(Wsw + (size_t)q * 512 + lane * 8, &B[q * 512]);
  }
  __syncthreads();
  const int l15 = lane & 15, kg = lane >> 4;
  const int base = blockIdx.x * 64;
  const int row = base + wv * 16 + l15;
  s8v af[4];
#pragma unroll
  for (int k = 0; k < 4; ++k)
    af[k] = *(const s8v*)(feat + (size_t)row * 128 + k * 32 + kg * 8);
  const f4v vz = {0.f, 0.f, 0.f, 0.f};
  f4v acc[16];
#pragma unroll
  for (int t = 0; t < 16; ++t) acc[t] = vz;
#pragma unroll
  for (int k = 0; k < 4; ++k) {
#pragma unroll
    for (int t = 0; t < 16; ++t) {
      int j = t * 16 + l15;
      s8v b = *(const s8v*)(&B[j * 128 + (((k * 4 + kg) ^ (j & 7)) * 8)]);
      acc[t] = mfma16(af[k], b, acc[t]);
    }
  }
#pragma unroll
  for (int t = 0; t < 16; ++t) {
    int c = t * 16 + l15;
    float bb = b1[c];
#pragma unroll
    for (int j = 0; j < 4; ++j) {
      int ro = base + wv * 16 + kg * 4 + j;
      T[(size_t)ro * 256 + c] = f2bf(acc[t][j] + bb);
    }
  }
}

// =====================================================================
// Edge message, SORTED, fragment-direct H1, both directions in one grid:
//   af2[k] = bf16(relu(Za + Zb + T))   computed straight into registers
//   out = relu(af2 @ W2 + b2) -> LDS f32 -> run-reduce -> atomicAdd
// =====================================================================
__global__ __launch_bounds__(256) void edge_msg6_kernel(
    const unsigned short* __restrict__ Z,   // [N][1024]
    const int* __restrict__ sn0p, const int* __restrict__ sn1p,
    const float* __restrict__ sxp, const unsigned short* __restrict__ Tp,
    const unsigned short* __restrict__ W2p, const float* __restrict__ b2p,
    float* __restrict__ Sp, const float* __restrict__ rcpp,
    const int* __restrict__ sn0c, const int* __restrict__ sn1c,
    const float* __restrict__ sxc, const unsigned short* __restrict__ Tc,
    const unsigned short* __restrict__ W2c, const float* __restrict__ b2c,
    float* __restrict__ Sc, const float* __restrict__ rcpc)
{
  __shared__ __align__(16) float OUT[64 * 128];          // 32KB
  __shared__ __align__(16) unsigned short Wb[2][4096];   // 16KB
  __shared__ int n0s[64], n1s[64], tix[64];
  __shared__ float tsc[64];
  const int tid = threadIdx.x, lane = tid & 63, wv = tid >> 6;
  const int l15 = lane & 15, kg = lane >> 4;
  const int xb = blockIdx.x;
  const bool isP = xb < EB_T;
  const int base = (isP ? xb : xb - EB_T) * 64;
  const int* __restrict__ sn0 = isP ? sn0p : sn0c;
  const int* __restrict__ sn1 = isP ? sn1p : sn1c;
  const float* __restrict__ sx = isP ? sxp : sxc;
  const unsigned short* __restrict__ T = isP ? Tp : Tc;
  const unsigned short* __restrict__ W2stg = isP ? W2p : W2c;
  const float* __restrict__ b2 = isP ? b2p : b2c;
  float* __restrict__ Sacc = isP ? Sp : Sc;
  const float* __restrict__ rcpv = isP ? rcpp : rcpc;
  const int off0 = isP ? 0 : 512, off1 = isP ? 256 : 768;

  if (tid < 64) {
    int e = base + tid;
    int a0 = sn0[e], a1 = sn1[e];
    n0s[tid] = a0; n1s[tid] = a1; tsc[tid] = rcpv[a1];
    float x = sx[e];
    int idx = (int)(x * (float)M_TAB + 0.5f);
    tix[tid] = idx < 0 ? 0 : (idx > M_TAB ? M_TAB : idx);
  }
  // stage W2 slice 0
#pragma unroll
  for (int i = 0; i < 2; ++i) {
    int q = wv * 2 + i;
    gload_lds16(W2stg + (size_t)q * 512 + lane * 8, &Wb[0][q * 512]);
  }
  __syncthreads();  // idx visible + W2 s0 staged
  // fragment-direct H1: compute af2[k] straight from Za/Zb/T
  const int rr = wv * 16 + l15;
  const unsigned short* za = Z + (size_t)n0s[rr] * 1024 + off0 + kg * 8;
  const unsigned short* zb = Z + (size_t)n1s[rr] * 1024 + off1 + kg * 8;
  const unsigned short* tt = T + (size_t)tix[rr] * 256 + kg * 8;
  s8v af2[8];
#pragma unroll
  for (int k = 0; k < 8; ++k) {
    const uint4 a = *(const uint4*)(za + k * 32);
    const uint4 b = *(const uint4*)(zb + k * 32);
    const uint4 t = *(const uint4*)(tt + k * 32);
    uint32_t ua[4] = {a.x, a.y, a.z, a.w};
    uint32_t ub[4] = {b.x, b.y, b.z, b.w};
    uint32_t ut[4] = {t.x, t.y, t.z, t.w};
    uint32_t uo[4];
#pragma unroll
    for (int q = 0; q < 4; ++q) {
      float a0, a1, b0, b1f, p0, p1;
      bf2(ua[q], a0, a1); bf2(ub[q], b0, b1f); bf2(ut[q], p0, p1);
      float s0 = fmaxf(a0 + b0 + p0, 0.f);
      float s1 = fmaxf(a1 + b1f + p1, 0.f);
      uo[q] = (uint32_t)f2bf(s0) | ((uint32_t)f2bf(s1) << 16);
    }
    union { uint4 u; s8v s; } cv;
    cv.u.x = uo[0]; cv.u.y = uo[1]; cv.u.z = uo[2]; cv.u.w = uo[3];
    af2[k] = cv.s;
  }
  // layer 2: 8 staged K-phases
  const f4v vz = {0.f, 0.f, 0.f, 0.f};
  f4v acc2[8];
#pragma unroll
  for (int t = 0; t < 8; ++t) acc2[t] = vz;
#pragma unroll
  for (int s = 0; s < 8; ++s) {
    if (s < 7) {
#pragma unroll
      for (int i = 0; i < 2; ++i) {
        int q = wv * 2 + i;
        gload_lds16(W2stg + (size_t)(s + 1) * 4096 + q * 512 + lane * 8,
                    &Wb[(s + 1) & 1][q * 512]);
      }
    }
#pragma unroll
    for (int t = 0; t < 8; ++t) {
      s8v b = *(const s8v*)(&Wb[s & 1][kg * 1024 + (t * 16 + l15) * 8]);
      acc2[t] = mfma16(af2[s], b, acc2[t]);
    }
    __syncthreads();
  }
  // per-edge out (bias+relu) -> f32 LDS
#pragma unroll
  for (int t = 0; t < 8; ++t) {
    int c = t * 16 + l15;
    float bb = b2[c];
#pragma unroll
    for (int j = 0; j < 4; ++j) {
      int r = wv * 16 + kg * 4 + j;
      OUT[r * 128 + c] = fmaxf(acc2[t][j] + bb, 0.f);
    }
  }
  __syncthreads();
  // run-reduction over equal targets (sorted): thread = (col, half)
  {
    const int c = tid & 127, h = tid >> 7;
    const int r0 = h * 32;
    float acc = 0.f;
    int cur = n1s[r0];
    float curs = tsc[r0];
    for (int r = r0; r < r0 + 32; ++r) {
      int nn = n1s[r];
      if (nn != cur) {
        atomicAdd(Sacc + (size_t)cur * 128 + c, acc * curs);
        acc = 0.f; cur = nn; curs = tsc[r];
      }
      acc += OUT[r * 128 + c];
    }
    atomicAdd(Sacc + (size_t)cur * 128 + c, acc * curs);
  }
}

// =====================================================================
// Aggr MLP: seg0 from hidb (16B copies); epilogue maintains hid + hidb
// =====================================================================
__global__ __launch_bounds__(256, 2) void aggr_kernel(
    float* __restrict__ hid, unsigned short* __restrict__ hidb,
    const float* __restrict__ Sp, const float* __restrict__ Sc,
    const float* __restrict__ pm, const float* __restrict__ cm,
    const float* __restrict__ st, const float* __restrict__ et,
    const unsigned short* __restrict__ W1stg, const float* __restrict__ b1,
    const unsigned short* __restrict__ W2stg, const float* __restrict__ b2)
{
  __shared__ __align__(16) unsigned short ABUF[64 * 384];
  __shared__ __align__(16) unsigned short Wb[2][8192];
  const int tid = threadIdx.x, lane = tid & 63, wv = tid >> 6;
  const int l15 = lane & 15, kg = lane >> 4;
  const int base = blockIdx.x * 64;
#pragma unroll
  for (int i = 0; i < 4; ++i) {
    int q = wv * 4 + i;
    gload_lds16(W1stg + (size_t)q * 512 + lane * 8, &Wb[0][q * 512]);
  }
  // seg0: copy hidb rows (16B units)
#pragma unroll
  for (int it = 0; it < 4; ++it) {
    int i = tid + it * 256;
    int r = i >> 4, u = i & 15, n = base + r;
    uint4 f = {0u, 0u, 0u, 0u};
    if (n < N_NODES) f = *(const uint4*)(hidb + (size_t)n * 128 + u * 8);
    *(uint4*)(ABUF + r * 384 + ((u ^ (r & 7)) * 8)) = f;
  }
  // seg1/2: Sp,Sc f32 + mask-token fma -> bf16
#pragma unroll
  for (int it = 0; it < 16; ++it) {
    int i = tid + it * 256;
    int r = i >> 6, q = i & 63;
    int seg = 1 + (q >> 5), c4 = q & 31, n = base + r;
    float4 v = {0.f, 0.f, 0.f, 0.f};
    if (n < N_NODES) {
      if (seg == 1) {
        v = *(const float4*)(Sp + (size_t)n * 128 + c4 * 4);
        float m = pm[n]; const float4 t = *(const float4*)(st + c4 * 4);
        v.x = fmaf(m, t.x, v.x); v.y = fmaf(m, t.y, v.y);
        v.z = fmaf(m, t.z, v.z); v.w = fmaf(m, t.w, v.w);
      } else {
        v = *(const float4*)(Sc + (size_t)n * 128 + c4 * 4);
        float m = cm[n]; const float4 t = *(const float4*)(et + c4 * 4);
        v.x = fmaf(m, t.x, v.x); v.y = fmaf(m, t.y, v.y);
        v.z = fmaf(m, t.z, v.z); v.w = fmaf(m, t.w, v.w);
      }
    }
    int unit = seg * 16 + (c4 >> 1);
    *(ushort4*)(ABUF + r * 384 + ((unit ^ (r & 7)) * 8) + (c4 & 1) * 4) = f2bf4(v);
  }
  __syncthreads();
  const int rr = wv * 16 + l15;
  s8v af1[12];
#pragma unroll
  for (int k = 0; k < 12; ++k)
    af1[k] = *(const s8v*)(ABUF + rr * 384 + (((k * 4 + kg) ^ (rr & 7)) * 8));
  const f4v vz = {0.f, 0.f, 0.f, 0.f};
  f4v acc1[16];
#pragma unroll
  for (int t = 0; t < 16; ++t) acc1[t] = vz;
#pragma unroll
  for (int s = 0; s < 12; ++s) {
    if (s < 11) {
#pragma unroll
      for (int i = 0; i < 4; ++i) {
        int q = wv * 4 + i;
        gload_lds16(W1stg + (size_t)(s + 1) * 8192 + q * 512 + lane * 8,
                    &Wb[(s + 1) & 1][q * 512]);
      }
    } else {
#pragma unroll
      for (int i = 0; i < 2; ++i) {
        int q = wv * 2 + i;
        gload_lds16(W2stg + (size_t)q * 512 + lane * 8, &Wb[0][q * 512]);
      }
    }
#pragma unroll
    for (int t = 0; t < 16; ++t) {
      s8v b = *(const s8v*)(&Wb[s & 1][kg * 2048 + (t * 16 + l15) * 8]);
      acc1[t] = mfma16(af1[s], b, acc1[t]);
    }
    __syncthreads();
  }
#pragma unroll
  for (int t = 0; t < 16; ++t) {
    int c = t * 16 + l15;
    float bb = b1[c];
#pragma unroll
    for (int j = 0; j < 4; ++j) {
      int r = wv * 16 + kg * 4 + j;
      ABUF[r * 256 + (((c >> 3) ^ (r & 7)) * 8) + (c & 7)] =
          f2bf(fmaxf(acc1[t][j] + bb, 0.f));
    }
  }
  __syncthreads();
  s8v af2[8];
#pragma unroll
  for (int k = 0; k < 8; ++k)
    af2[k] = *(const s8v*)(ABUF + rr * 256 + (((k * 4 + kg) ^ (l15 & 7)) * 8));
  f4v acc2[8];
#pragma unroll
  for (int t = 0; t < 8; ++t) acc2[t] = vz;
#pragma unroll
  for (int s = 0; s < 8; ++s) {
    if (s < 7) {
#pragma unroll
      for (int i = 0; i < 2; ++i) {
        int q = wv * 2 + i;
        gload_lds16(W2stg + (size_t)(s + 1) * 4096 + q * 512 + lane * 8,
                    &Wb[(s + 1) & 1][q * 512]);
      }
    }
#pragma unroll
    for (int t = 0; t < 8; ++t) {
      s8v b = *(const s8v*)(&Wb[s & 1][kg * 1024 + (t * 16 + l15) * 8]);
      acc2[t] = mfma16(af2[s], b, acc2[t]);
    }
    __syncthreads();
  }
#pragma unroll
  for (int t = 0; t < 8; ++t) {
    int c = t * 16 + l15;
    float bb = b2[c];
#pragma unroll
    for (int j = 0; j < 4; ++j) {
      int ro = base + wv * 16 + kg * 4 + j;
      if (ro < N_NODES) {
        float nv = hid[(size_t)ro * 128 + c] + fmaxf(acc2[t][j] + bb, 0.f);
        hid[(size_t)ro * 128 + c] = nv;
        hidb[(size_t)ro * 128 + c] = f2bf(nv);
      }
    }
  }
}

// =====================================================================
// edge-scalar MLP (proven) — only for the 65 table-sample tiles
// =====================================================================
__global__ __launch_bounds__(256) void edge_feat_kernel(
    const float* __restrict__ ind, const float* __restrict__ W1,
    const float* __restrict__ b1,
    const unsigned short* __restrict__ W2sw,
    const float* __restrict__ b2, unsigned short* __restrict__ feat,
    int ntiles)
{
  __shared__ __align__(16) unsigned short B[128 * 256];  // 64KB
  __shared__ unsigned short H1[64 * 264];
  __shared__ float xs[64];
  const int tid = threadIdx.x, lane = tid & 63, wv = tid >> 6;
  const int l15 = lane & 15, kg = lane >> 4;
#pragma unroll
  for (int it = 0; it < 16; ++it) {
    int q = it * 4 + wv;
    gload_lds16(W2sw + (size_t)q * 512 + lane * 8, &B[q * 512]);
  }
  const float w = W1[tid], bb1 = b1[tid];
  const f4v vz = {0.f, 0.f, 0.f, 0.f};
  for (int tile = blockIdx.x; tile < ntiles; tile += gridDim.x) {
    const int base = tile * 64;
    if (tid < 64) xs[tid] = ind[base + tid];
    __syncthreads();
    for (int r = 0; r < 64; ++r)
      H1[r * 264 + tid] = f2bf(fmaxf(fmaf(xs[r], w, bb1), 0.f));
    __syncthreads();
    const unsigned short* Hrow = H1 + (size_t)(wv * 16 + l15) * 264;
    s8v af2[8];
#pragma unroll
    for (int k = 0; k < 8; ++k) af2[k] = *(const s8v*)(Hrow + k * 32 + kg * 8);
    f4v acc2[8];
#pragma unroll
    for (int t = 0; t < 8; ++t) acc2[t] = vz;
#pragma unroll
    for (int k = 0; k < 8; ++k) {
#pragma unroll
      for (int t = 0; t < 8; ++t) {
        int j = t * 16 + l15;
        s8v b = *(const s8v*)(&B[j * 256 + (((k * 4 + kg) ^ (j & 7)) * 8)]);
        acc2[t] = mfma16(af2[k], b, acc2[t]);
      }
    }
#pragma unroll
    for (int t = 0; t < 8; ++t) {
      int c = t * 16 + l15;
      float b2c = b2[c];
#pragma unroll
      for (int j = 0; j < 4; ++j) {
        int e = base + wv * 16 + kg * 4 + j;
        feat[(size_t)e * 128 + c] = f2bf(fmaxf(acc2[t][j] + b2c, 0.f));
      }
    }
    __syncthreads();
  }
}

// =====================================================================
// one-time v MLP (proven) — now also writes hidb
// =====================================================================
template <int KST1>
static __device__ __forceinline__ void mlp_core(
    unsigned short* __restrict__ BUF,
    const unsigned short* __restrict__ W1t, const float* __restrict__ b1,
    const unsigned short* __restrict__ W2t,
    int l15, int kg, int wr0, f4v* __restrict__ acc2)
{
  const int ldA = KST1 * 32 + 8;
  const f4v vzero = {0.f, 0.f, 0.f, 0.f};
  const unsigned short* Arow = BUF + (size_t)(wr0 + l15) * ldA;
  s8v af1[KST1];
#pragma unroll
  for (int k = 0; k < KST1; ++k) af1[k] = *(const s8v*)(Arow + k * 32 + kg * 8);
  __syncthreads();
  f4v acc1[16];
#pragma unroll
  for (int t = 0; t < 16; ++t) acc1[t] = vzero;
#pragma unroll
  for (int k = 0; k < KST1; ++k) {
#pragma unroll
    for (int t = 0; t < 16; ++t) {
      s8v b = *(const s8v*)(W1t + (size_t)(t * 16 + l15) * (KST1 * 32) + k * 32 + kg * 8);
      acc1[t] = mfma16(af1[k], b, acc1[t]);
    }
  }
#pragma unroll
  for (int t = 0; t < 16; ++t) {
    int c = t * 16 + l15;
    float bb = b1[c];
#pragma unroll
    for (int j = 0; j < 4; ++j) {
      BUF[(size_t)(wr0 + kg * 4 + j) * 264 + c] = f2bf(fmaxf(acc1[t][j] + bb, 0.f));
    }
  }
  const unsigned short* Hrow = BUF + (size_t)(wr0 + l15) * 264;
  s8v af2[8];
#pragma unroll
  for (int k = 0; k < 8; ++k) af2[k] = *(const s8v*)(Hrow + k * 32 + kg * 8);
#pragma unroll
  for (int t = 0; t < 8; ++t) acc2[t] = vzero;
#pragma unroll
  for (int k = 0; k < 8; ++k) {
#pragma unroll
    for (int t = 0; t < 8; ++t) {
      s8v b = *(const s8v*)(W2t + (size_t)(t * 16 + l15) * 256 + k * 32 + kg * 8);
      acc2[t] = mfma16(af2[k], b, acc2[t]);
    }
  }
}

__global__ __launch_bounds__(256, 2) void v_mlp_kernel(
    const float* __restrict__ x,
    const unsigned short* __restrict__ W1t, const float* __restrict__ b1,
    const unsigned short* __restrict__ W2t, const float* __restrict__ b2,
    float* __restrict__ hid, unsigned short* __restrict__ hidb)
{
  __shared__ unsigned short BUF[64 * 264];
  const int tid = threadIdx.x;
  const int base = blockIdx.x * 64;
#pragma unroll
  for (int it = 0; it < 8; ++it) {
    int i = tid + it * 256;
    int r = i >> 5, c4 = i & 31, n = base + r;
    float4 v = {0.f, 0.f, 0.f, 0.f};
    if (n < N_NODES) v = *(const float4*)(x + (size_t)n * 128 + c4 * 4);
    *(ushort4*)(BUF + r * 136 + c4 * 4) = f2bf4(v);
  }
  __syncthreads();
  const int lane = tid & 63, wv = tid >> 6;
  const int l15 = lane & 15, kg = lane >> 4, wr0 = wv * 16;
  f4v acc2[8];
  mlp_core<4>(BUF, W1t, b1, W2t, l15, kg, wr0, acc2);
#pragma unroll
  for (int t = 0; t < 8; ++t) {
    int c = t * 16 + l15;
    float bb = b2[c];
#pragma unroll
    for (int j = 0; j < 4; ++j) {
      int n = base + wr0 + kg * 4 + j;
      if (n < N_NODES) {
        float v = fmaxf(acc2[t][j] + bb, 0.f);
        hid[(size_t)n * 128 + c] = v;
        hidb[(size_t)n * 128 + c] = f2bf(v);
      }
    }
  }
}

// ---------------- sorting + prep kernels (proven) ----------------
__global__ void counti_kernel(const int* __restrict__ pn, const int* __restrict__ cn,
                              int* __restrict__ cp, int* __restrict__ cc) {
  int i = blockIdx.x * 256 + threadIdx.x;
  if (i < N_EDGES) {
    atomicAdd(cp + pn[i], 1);
    atomicAdd(cc + cn[i], 1);
  }
}

__global__ void rcpi_kernel(const int* __restrict__ cp, const int* __restrict__ cc,
                            float* __restrict__ rp, float* __restrict__ rc) {
  int i = blockIdx.x * 256 + threadIdx.x;
  if (i < N_NODES) {
    rp[i] = 1.f / fmaxf((float)cp[i], 1.f);
    rc[i] = 1.f / fmaxf((float)cc[i], 1.f);
  }
}

__global__ void scan_kernel(const int* __restrict__ cnt, int* __restrict__ cur) {
  __shared__ int part[1024];
  const int t = threadIdx.x;
  const int CH = (N_NODES + 1023) / 1024;  // 49
  int s = 0;
#pragma unroll 1
  for (int i = 0; i < CH; ++i) {
    int idx = t * CH + i;
    if (idx < N_NODES) s += cnt[idx];
  }
  part[t] = s;
  __syncthreads();
  for (int d = 1; d < 1024; d <<= 1) {
    int v = (t >= d) ? part[t - d] : 0;
    __syncthreads();
    part[t] += v;
    __syncthreads();
  }
  int run = part[t] - s;
#pragma unroll 1
  for (int i = 0; i < CH; ++i) {
    int idx = t * CH + i;
    if (idx < N_NODES) { cur[idx] = run; run += cnt[idx]; }
  }
}

__global__ void scatter_kernel(const int* __restrict__ tgt, const int* __restrict__ oth,
                               const float* __restrict__ x, int* __restrict__ cursor,
                               int* __restrict__ sn0, int* __restrict__ sn1,
                               float* __restrict__ sx) {
  int e = blockIdx.x * 256 + threadIdx.x;
  if (e < N_EDGES) {
    int tN = tgt[e];
    int pos = atomicAdd(cursor + tN, 1);
    sn0[pos] = oth[e];
    sn1[pos] = tN;
    sx[pos] = x[e];
  }
}

__global__ void transpose_w(const float* __restrict__ W, unsigned short* __restrict__ Wt,
                            int K, int NH) {
  int i = blockIdx.x * 256 + threadIdx.x;
  if (i < K * NH) {
    int k = i / NH, n = i - k * NH;
    Wt[(size_t)n * K + k] = f2bf(W[i]);
  }
}

__global__ void build_w1stg(const float* __restrict__ W, unsigned short* __restrict__ stg) {
  int i = blockIdx.x * 256 + threadIdx.x;
  if (i < 384 * 256) {
    int k = i >> 8, out = i & 255;
    int s = k >> 5, kc = (k >> 3) & 3, j = k & 7;
    stg[(size_t)s * 8192 + kc * 2048 + out * 8 + j] = f2bf(W[i]);
  }
}

__global__ void build_w2stg(const float* __restrict__ W, unsigned short* __restrict__ stg) {
  int i = blockIdx.x * 256 + threadIdx.x;
  if (i < 256 * 128) {
    int k = i >> 7, out = i & 127;
    int s = k >> 5, kc = (k >> 3) & 3, j = k & 7;
    stg[(size_t)s * 4096 + kc * 1024 + out * 8 + j] = f2bf(W[i]);
  }
}

__global__ void build_w128_sw(const float* __restrict__ W, int k_off,
                              unsigned short* __restrict__ dst) {
  int i = blockIdx.x * 256 + threadIdx.x;
  if (i < 256 * 128) {
    int j = i >> 7, e = i & 127;
    int unit = (e >> 3) ^ (j & 7);
    dst[(size_t)j * 128 + unit * 8 + (e & 7)] = f2bf(W[(size_t)(k_off + e) * 256 + j]);
  }
}

__global__ void build_w2sw(const float* __restrict__ W, unsigned short* __restrict__ dst) {
  int i = blockIdx.x * 256 + threadIdx.x;
  if (i < 128 * 256) {
    int j = i >> 8, k = i & 255;
    dst[(size_t)j * 256 + (((k >> 3) ^ (j & 7)) * 8) + (k & 7)] =
        f2bf(W[(size_t)k * 128 + j]);
  }
}

__global__ void make_samples(float* __restrict__ xs) {
  int i = blockIdx.x * 256 + threadIdx.x;
  if (i < 4160) {
    int s = i < M_TAB ? i : M_TAB;
    xs[i] = (float)s * (1.f / (float)M_TAB);
  }
}

extern "C" void kernel_launch(void* const* d_in, const int* in_sizes, int n_in,
                              void* d_out, int out_size, void* d_ws, size_t ws_size,
                              hipStream_t stream) {
  const float* batch_token = (const float*)d_in[0];
  const int*   pn          = (const int*)d_in[1];
  const int*   cn          = (const int*)d_in[2];
  const float* indP        = (const float*)d_in[3];
  const float* indC        = (const float*)d_in[4];
  const float* p_mask      = (const float*)d_in[5];
  const float* c_mask      = (const float*)d_in[6];
  const float* stok        = (const float*)d_in[7];
  const float* etok        = (const float*)d_in[8];
  const float* vW1 = (const float*)d_in[9],  *vb1 = (const float*)d_in[10];
  const float* vW2 = (const float*)d_in[11], *vb2 = (const float*)d_in[12];
  const float* eW1 = (const float*)d_in[13], *eb1 = (const float*)d_in[14];
  const float* eW2 = (const float*)d_in[15], *eb2 = (const float*)d_in[16];
  const float* pW1 = (const float*)d_in[17], *pb1 = (const float*)d_in[18];
  const float* pW2 = (const float*)d_in[19], *pb2 = (const float*)d_in[20];
  const float* cW1 = (const float*)d_in[21], *cb1 = (const float*)d_in[22];
  const float* cW2 = (const float*)d_in[23], *cb2 = (const float*)d_in[24];
  const float* aW1 = (const float*)d_in[25], *ab1 = (const float*)d_in[26];
  const float* aW2 = (const float*)d_in[27], *ab2 = (const float*)d_in[28];

  char* w = (char*)d_ws;
  auto alloc = [&](size_t bytes) -> char* {
    char* p = w;
    w += (bytes + 255) & ~(size_t)255;
    return p;
  };
  // total ~185 MB (proven budget >=257 MB). Sp,Sc contiguous (one memset).
  float* Sp    = (float*)alloc((size_t)N_NODES * 128 * 4);
  float* Sc    = (float*)alloc((size_t)N_NODES * 128 * 4);
  float* rcp_p = (float*)alloc((size_t)N_NODES * 4);
  float* rcp_c = (float*)alloc((size_t)N_NODES * 4);
  int*   cnt_p = (int*)alloc((size_t)N_NODES * 4);
  int*   cnt_c = (int*)alloc((size_t)N_NODES * 4);
  int*   cur_p = (int*)alloc((size_t)N_NODES * 4);
  int*   cur_c = (int*)alloc((size_t)N_NODES * 4);
  int*   sn0_p = (int*)alloc((size_t)N_EDGES * 4);
  int*   sn1_p = (int*)alloc((size_t)N_EDGES * 4);
  float* sx_p  = (float*)alloc((size_t)N_EDGES * 4);
  int*   sn0_c = (int*)alloc((size_t)N_EDGES * 4);
  int*   sn1_c = (int*)alloc((size_t)N_EDGES * 4);
  float* sx_c  = (float*)alloc((size_t)N_EDGES * 4);
  unsigned short* Zall   = (unsigned short*)alloc((size_t)N_NODES * 1024 * 2); // 102.4MB
  unsigned short* hidb   = (unsigned short*)alloc((size_t)N_NODES * 128 * 2);  // 12.8MB
  unsigned short* fsamp  = (unsigned short*)alloc((size_t)4160 * 128 * 2);
  unsigned short* Tp     = (unsigned short*)alloc((size_t)4160 * 256 * 2);
  unsigned short* Tc     = (unsigned short*)alloc((size_t)4160 * 256 * 2);
  float*          xsamp  = (float*)alloc((size_t)4160 * 4);
  unsigned short* Wbig   = (unsigned short*)alloc((size_t)4 * 256 * 128 * 2);
  unsigned short* W1csw_p = (unsigned short*)alloc(256 * 128 * 2);
  unsigned short* W1csw_c = (unsigned short*)alloc(256 * 128 * 2);
  unsigned short* W1stg_a = (unsigned short*)alloc(12 * 8192 * 2);
  unsigned short* W2stg_p = (unsigned short*)alloc(8 * 4096 * 2);
  unsigned short* W2stg_c = (unsigned short*)alloc(8 * 4096 * 2);
  unsigned short* W2stg_a = (unsigned short*)alloc(8 * 4096 * 2);
  unsigned short* W1t_v   = (unsigned short*)alloc(256 * 128 * 2);
  unsigned short* W2t_v   = (unsigned short*)alloc(128 * 256 * 2);
  unsigned short* W2sw_e  = (unsigned short*)alloc(128 * 256 * 2);

  float* hidden = (float*)d_out;

  const int NB = (N_NODES + 63) / 64;   // 782

  // counts -> rcp; exclusive-scan -> cursors; scatter to sorted arrays
  hipMemsetAsync(cnt_p, 0, (size_t)N_NODES * 4, stream);
  hipMemsetAsync(cnt_c, 0, (size_t)N_NODES * 4, stream);
  counti_kernel<<<(N_EDGES + 255) / 256, 256, 0, stream>>>(pn, cn, cnt_p, cnt_c);
  rcpi_kernel<<<(N_NODES + 255) / 256, 256, 0, stream>>>(cnt_p, cnt_c, rcp_p, rcp_c);
  scan_kernel<<<1, 1024, 0, stream>>>(cnt_p, cur_p);
  scan_kernel<<<1, 1024, 0, stream>>>(cnt_c, cur_c);
  scatter_kernel<<<(N_EDGES + 255) / 256, 256, 0, stream>>>(pn, cn, indP, cur_p,
                                                            sn0_p, sn1_p, sx_p);
  scatter_kernel<<<(N_EDGES + 255) / 256, 256, 0, stream>>>(cn, pn, indC, cur_c,
                                                            sn0_c, sn1_c, sx_c);

  // weight prep
  transpose_w<<<(128 * 256 + 255) / 256, 256, 0, stream>>>(vW1, W1t_v, 128, 256);
  transpose_w<<<(256 * 128 + 255) / 256, 256, 0, stream>>>(vW2, W2t_v, 256, 128);
  build_w2sw<<<(128 * 256 + 255) / 256, 256, 0, stream>>>(eW2, W2sw_e);
  build_w1stg<<<(384 * 256 + 255) / 256, 256, 0, stream>>>(aW1, W1stg_a);
  build_w2stg<<<(256 * 128 + 255) / 256, 256, 0, stream>>>(pW2, W2stg_p);
  build_w2stg<<<(256 * 128 + 255) / 256, 256, 0, stream>>>(cW2, W2stg_c);
  build_w2stg<<<(256 * 128 + 255) / 256, 256, 0, stream>>>(aW2, W2stg_a);
  const int SWB = (256 * 128 + 255) / 256;
  build_w128_sw<<<SWB, 256, 0, stream>>>(pW1, 0,   Wbig + 0 * 256 * 128);
  build_w128_sw<<<SWB, 256, 0, stream>>>(pW1, 128, Wbig + 1 * 256 * 128);
  build_w128_sw<<<SWB, 256, 0, stream>>>(cW1, 0,   Wbig + 2 * 256 * 128);
  build_w128_sw<<<SWB, 256, 0, stream>>>(cW1, 128, Wbig + 3 * 256 * 128);
  build_w128_sw<<<SWB, 256, 0, stream>>>(pW1, 256, W1csw_p);
  build_w128_sw<<<SWB, 256, 0, stream>>>(cW1, 256, W1csw_c);

  // edge-scalar tables: T*(s/M) = mlp_e(s/M) @ W1c + b1
  make_samples<<<(4160 + 255) / 256, 256, 0, stream>>>(xsamp);
  edge_feat_kernel<<<65, 256, 0, stream>>>(xsamp, eW1, eb1, W2sw_e, eb2, fsamp, 65);
  tab_gemm_kernel<<<65, 256, 0, stream>>>(fsamp, W1csw_p, pb1, Tp);
  tab_gemm_kernel<<<65, 256, 0, stream>>>(fsamp, W1csw_c, cb1, Tc);

  // initial hidden (f32 + bf16 shadow)
  v_mlp_kernel<<<NB, 256, 0, stream>>>(batch_token, W1t_v, vb1, W2t_v, vb2,
                                       hidden, hidb);

  for (int hop = 0; hop < 3; ++hop) {
    // Sp and Sc are contiguous: one memset
    hipMemsetAsync(Sp, 0, (size_t)N_NODES * 128 * 4 * 2, stream);
    // fused Z-GEMM: groups {p:hc, p:hp, c:hp, c:hc} -> Zall[N][1024]
    z_gemm_kernel<<<dim3(256, 4), 256, 0, stream>>>(hidb, Wbig, Zall);
    // both directions in one launch (p: blocks [0,EB), c: blocks [EB,2EB))
    edge_msg6_kernel<<<2 * EB_T, 256, 0, stream>>>(
        Zall,
        sn0_p, sn1_p, sx_p, Tp, W2stg_p, pb2, Sp, rcp_p,
        sn0_c, sn1_c, sx_c, Tc, W2stg_c, cb2, Sc, rcp_c);
    aggr_kernel<<<NB, 256, 0, stream>>>(hidden, hidb, Sp, Sc, p_mask, c_mask,
                                        stok, etok, W1stg_a, ab1, W2stg_a, ab2);
  }
  (void)in_sizes; (void)n_in; (void)out_size; (void)ws_size;
}